// Round 3
// baseline (515.462 us; speedup 1.0000x reference)
//
#include <hip/hip_runtime.h>
#include <math.h>

typedef __bf16 bf16;
typedef __bf16 bfrag __attribute__((ext_vector_type(8)));
typedef __bf16 bf4 __attribute__((ext_vector_type(4)));
typedef float f4 __attribute__((ext_vector_type(4)));

#define DEV static __device__ __forceinline__

DEV f4 MFMA(bfrag a, bfrag b, f4 c) {
  return __builtin_amdgcn_mfma_f32_16x16x32_bf16(a, b, c, 0, 0, 0);
}

// ---------------- fp32 -> bf16 convert (x4 vectorized) ----------------
__global__ void cvt_bf16(const float* __restrict__ in, bf16* __restrict__ out, int n4) {
  int i = blockIdx.x * blockDim.x + threadIdx.x;
  if (i >= n4) return;
  float4 v = reinterpret_cast<const float4*>(in)[i];
  bf4 o;
  o[0] = (bf16)v.x; o[1] = (bf16)v.y; o[2] = (bf16)v.z; o[3] = (bf16)v.w;
  reinterpret_cast<bf4*>(out)[i] = o;
}

// ---------------- mask -> additive bias ----------------
__global__ void maskbias_k(const int* __restrict__ mask, float* __restrict__ mb, int n) {
  int i = blockIdx.x * blockDim.x + threadIdx.x;
  if (i < n) mb[i] = (mask[i] > 0) ? 0.f : -1e9f;
}

// ---------------- GEMM: C[M,N] = act(A[M,K] @ W[N,K]^T + bias) ----------------
template<int OUTF32, int RELU>
__global__ __launch_bounds__(256) void gemm_nt(
    const bf16* __restrict__ A, int lda,
    const bf16* __restrict__ W, int ldw,
    const float* __restrict__ bias,
    void* __restrict__ C, int ldc,
    int N64, int K) {
  int lane = threadIdx.x & 63;
  int w = threadIdx.x >> 6;
  int lrow = lane & 15, lgrp = lane >> 4;
  int tn = blockIdx.x % N64, tm = blockIdx.x / N64;
  int m0 = tm * 64 + (w >> 1) * 32;
  int n0 = tn * 64 + (w & 1) * 32;
  const bf16* Ab = A + (size_t)m0 * lda + lgrp * 8;
  const bf16* Wb = W + (size_t)n0 * ldw + lgrp * 8;
  f4 acc[2][2] = {};
  for (int k0 = 0; k0 < K; k0 += 32) {
    bfrag a0 = *(const bfrag*)(Ab + (size_t)lrow * lda + k0);
    bfrag a1 = *(const bfrag*)(Ab + (size_t)(lrow + 16) * lda + k0);
    bfrag b0 = *(const bfrag*)(Wb + (size_t)lrow * ldw + k0);
    bfrag b1 = *(const bfrag*)(Wb + (size_t)(lrow + 16) * ldw + k0);
    acc[0][0] = MFMA(a0, b0, acc[0][0]);
    acc[0][1] = MFMA(a0, b1, acc[0][1]);
    acc[1][0] = MFMA(a1, b0, acc[1][0]);
    acc[1][1] = MFMA(a1, b1, acc[1][1]);
  }
#pragma unroll
  for (int mi = 0; mi < 2; mi++)
#pragma unroll
    for (int nj = 0; nj < 2; nj++) {
      int col = n0 + nj * 16 + lrow;
      float bv = bias[col];
      int rowb = m0 + mi * 16 + lgrp * 4;
#pragma unroll
      for (int i = 0; i < 4; i++) {
        float v = acc[mi][nj][i] + bv;
        if (RELU) v = fmaxf(v, 0.f);
        if (OUTF32)
          ((float*)C)[(size_t)(rowb + i) * ldc + col] = v;
        else
          ((bf16*)C)[(size_t)(rowb + i) * ldc + col] = (bf16)v;
      }
    }
}

// ---------------- V transpose: Vt[b][h][d][s] = V[b][s][coff + h*64 + d] ----------------
__global__ __launch_bounds__(256) void vtrans(const bf16* __restrict__ V, int rs, int coff,
                                              bf16* __restrict__ Vt, int H, int S) {
  int nst = S / 64;
  int st = blockIdx.x % nst;
  int h = (blockIdx.x / nst) % H;
  int b = blockIdx.x / (nst * H);
  __shared__ bf16 tile[64][72];
  int t = threadIdx.x;
  int r = t >> 2, c = t & 3;
  const bf16* src = V + ((size_t)b * S + st * 64 + r) * rs + coff + h * 64 + c * 16;
  bfrag v0 = *(const bfrag*)(src);
  bfrag v1 = *(const bfrag*)(src + 8);
  *(bfrag*)&tile[r][c * 16] = v0;
  *(bfrag*)&tile[r][c * 16 + 8] = v1;
  __syncthreads();
  bf16* dst = Vt + (((size_t)b * H + h) * 64 + r) * S + st * 64 + c * 16;
  bfrag o0, o1;
#pragma unroll
  for (int j = 0; j < 8; j++) {
    o0[j] = tile[c * 16 + j][r];
    o1[j] = tile[c * 16 + 8 + j][r];
  }
  *(bfrag*)dst = o0;
  *(bfrag*)(dst + 8) = o1;
}

// ---------------- flash attention v2: swapped operands, lane-local softmax ----------------
// QK^T computed as mfma(K,Q): score[key][q], q = lane&15 -> softmax is lane-local.
// PV computed as mfma(V,P): out[d][q], q = lane&15 -> no rescale shuffles.
// SPLIT>1: keys partitioned; unnormalized f32 partials + (m,l) written for combine.
template<int SPLIT, int PARTIAL>
__global__ __launch_bounds__(256) void flash2_k(
    const bf16* __restrict__ Q, const bf16* __restrict__ Kp, int rs,
    const bf16* __restrict__ Vt, const float* __restrict__ bias,
    bf16* __restrict__ O, int ors,
    float* __restrict__ Opart, float2* __restrict__ MLpart,
    int H, int S, float scale, int Bc) {
  int nqt = S / 64;
  int bid = blockIdx.x;
  int qt = bid % nqt;
  int h = (bid / nqt) % H;
  int b = (bid / (nqt * H)) % Bc;
  int sp = bid / (nqt * H * Bc);
  int lane = threadIdx.x & 63, w = threadIdx.x >> 6;
  int lrow = lane & 15, lgrp = lane >> 4;
  int q0 = qt * 64 + w * 16;
  const int kchunk = S / SPLIT;
  int k_beg = sp * kchunk;

  const bf16* Qb = Q + ((size_t)b * S + q0 + lrow) * rs + h * 64 + lgrp * 8;
  bfrag qf0 = *(const bfrag*)(Qb);
  bfrag qf1 = *(const bfrag*)(Qb + 32);
  const bf16* Kb = Kp + (size_t)b * S * rs + h * 64 + lgrp * 8;
  const bf16* Vb = Vt + ((size_t)b * H + h) * 64 * (size_t)S + lgrp * 8;
  const float* biasb = bias + (size_t)b * S;

  __shared__ bf16 P[4][16][72];
  f4 acc[4] = {};
  float mrun = -3.0e38f, lrun = 0.f;

  // prologue prefetch: K tile 0, V tile 0
  bfrag kf[8], vf[8];
#pragma unroll
  for (int cf = 0; cf < 4; cf++) {
    const bf16* kr = Kb + (size_t)(k_beg + cf * 16 + lrow) * rs;
    kf[cf * 2] = *(const bfrag*)(kr);
    kf[cf * 2 + 1] = *(const bfrag*)(kr + 32);
  }
#pragma unroll
  for (int df = 0; df < 4; df++) {
    const bf16* vr = Vb + (size_t)(df * 16 + lrow) * S + k_beg;
    vf[df] = *(const bfrag*)(vr);
    vf[4 + df] = *(const bfrag*)(vr + 32);
  }

  for (int kt = k_beg; kt < k_beg + kchunk; kt += 64) {
    // bias for this tile: key = kt + cf*16 + lgrp*4 + i
    f4 bv[4];
#pragma unroll
    for (int cf = 0; cf < 4; cf++)
      bv[cf] = *(const f4*)(biasb + kt + cf * 16 + lgrp * 4);

    // QK^T swapped: s[cf][i] = score(key = kt+cf*16+lgrp*4+i, q = lrow)
    f4 s[4];
#pragma unroll
    for (int cf = 0; cf < 4; cf++) {
      f4 z = {0.f, 0.f, 0.f, 0.f};
      z = MFMA(kf[cf * 2], qf0, z);
      z = MFMA(kf[cf * 2 + 1], qf1, z);
      s[cf] = z;
    }

    // prefetch next K tile (kf consumed by the QK above)
    int ktn = (kt + 64 < k_beg + kchunk) ? kt + 64 : kt;
#pragma unroll
    for (int cf = 0; cf < 4; cf++) {
      const bf16* kr = Kb + (size_t)(ktn + cf * 16 + lrow) * rs;
      kf[cf * 2] = *(const bfrag*)(kr);
      kf[cf * 2 + 1] = *(const bfrag*)(kr + 32);
    }

    // scale + bias
#pragma unroll
    for (int cf = 0; cf < 4; cf++)
#pragma unroll
      for (int i = 0; i < 4; i++) s[cf][i] = s[cf][i] * scale + bv[cf][i];

    // lane-local tree max over 16, then 2 shuffles across lgrp
    f4 t0, t1;
#pragma unroll
    for (int i = 0; i < 4; i++) {
      t0[i] = fmaxf(s[0][i], s[1][i]);
      t1[i] = fmaxf(s[2][i], s[3][i]);
    }
    float mx = fmaxf(fmaxf(fmaxf(t0[0], t0[1]), fmaxf(t0[2], t0[3])),
                     fmaxf(fmaxf(t1[0], t1[1]), fmaxf(t1[2], t1[3])));
    mx = fmaxf(mx, __shfl_xor(mx, 16));
    mx = fmaxf(mx, __shfl_xor(mx, 32));
    float mn = fmaxf(mrun, mx);
    float sc0 = __expf(mrun - mn);
    mrun = mn;

    // exp in place + tree sum
#pragma unroll
    for (int cf = 0; cf < 4; cf++)
#pragma unroll
      for (int i = 0; i < 4; i++) s[cf][i] = __expf(s[cf][i] - mn);
    f4 u0, u1;
#pragma unroll
    for (int i = 0; i < 4; i++) {
      u0[i] = s[0][i] + s[1][i];
      u1[i] = s[2][i] + s[3][i];
    }
    float rsum = ((u0[0] + u0[1]) + (u0[2] + u0[3])) + ((u1[0] + u1[1]) + (u1[2] + u1[3]));
    rsum += __shfl_xor(rsum, 16);
    rsum += __shfl_xor(rsum, 32);
    lrun = lrun * sc0 + rsum;
#pragma unroll
    for (int df = 0; df < 4; df++)
#pragma unroll
      for (int i = 0; i < 4; i++) acc[df][i] *= sc0;

    // P -> LDS: row q=lrow, keys cf*16+lgrp*4..+3 contiguous (b64 writes)
#pragma unroll
    for (int cf = 0; cf < 4; cf++) {
      bf4 pb;
#pragma unroll
      for (int i = 0; i < 4; i++) pb[i] = (bf16)s[cf][i];
      *(bf4*)&P[w][lrow][cf * 16 + lgrp * 4] = pb;
    }

    // PV swapped: acc[df][i] += V^T rows (d) x P rows (q) -> out[d][q=lrow]
#pragma unroll
    for (int ks = 0; ks < 2; ks++) {
      bfrag pa = *(const bfrag*)&P[w][lrow][ks * 32 + lgrp * 8];
#pragma unroll
      for (int df = 0; df < 4; df++)
        acc[df] = MFMA(vf[ks * 4 + df], pa, acc[df]);
    }

    // prefetch next V tile (vf consumed by the PV above)
#pragma unroll
    for (int df = 0; df < 4; df++) {
      const bf16* vr = Vb + (size_t)(df * 16 + lrow) * S + ktn;
      vf[df] = *(const bfrag*)(vr);
      vf[4 + df] = *(const bfrag*)(vr + 32);
    }
  }

  int q = q0 + lrow;
  if (PARTIAL) {
    float* op = Opart + ((((size_t)sp * Bc + b) * H + h) * S + q) * 64 + lgrp * 4;
#pragma unroll
    for (int df = 0; df < 4; df++) *(f4*)(op + df * 16) = acc[df];
    if (lgrp == 0) {
      float2 ml; ml.x = mrun; ml.y = lrun;
      MLpart[(((size_t)sp * Bc + b) * H + h) * S + q] = ml;
    }
  } else {
    float inv = 1.f / lrun;
    bf16* Ob = O + ((size_t)b * S + q) * ors + h * 64 + lgrp * 4;
#pragma unroll
    for (int df = 0; df < 4; df++) {
      bf4 ob;
#pragma unroll
      for (int i = 0; i < 4; i++) ob[i] = (bf16)(acc[df][i] * inv);
      *(bf4*)(Ob + df * 16) = ob;
    }
  }
}

// ---------------- combine split-K flash partials ----------------
__global__ __launch_bounds__(256) void flash_comb(
    const float* __restrict__ Opart, const float2* __restrict__ ML,
    bf16* __restrict__ O, int ors, int Hh, int S, int Bc, int nsplit) {
  int idx = blockIdx.x * 256 + threadIdx.x;
  int d4 = idx & 15;
  int q = (idx >> 4) % S;
  int hh = ((idx >> 4) / S) % Hh;
  int b = (idx >> 4) / (S * Hh);
  size_t rowstride = (size_t)Bc * Hh * S;
  size_t rbase = ((size_t)b * Hh + hh) * S + q;
  float m = -3.0e38f;
  for (int sp = 0; sp < nsplit; sp++) m = fmaxf(m, ML[sp * rowstride + rbase].x);
  float lsum = 0.f;
  f4 o = {0.f, 0.f, 0.f, 0.f};
  for (int sp = 0; sp < nsplit; sp++) {
    float2 ml = ML[sp * rowstride + rbase];
    float wgt = __expf(ml.x - m);
    lsum += ml.y * wgt;
    f4 a = *(const f4*)(Opart + (sp * rowstride + rbase) * 64 + d4 * 4);
#pragma unroll
    for (int i = 0; i < 4; i++) o[i] += a[i] * wgt;
  }
  float inv = 1.f / lsum;
  bf4 ob;
#pragma unroll
  for (int i = 0; i < 4; i++) ob[i] = (bf16)(o[i] * inv);
  *(bf4*)(O + ((size_t)b * S + q) * ors + hh * 64 + d4 * 4) = ob;
}

// ---------------- survival epilogue ----------------
__global__ __launch_bounds__(256) void surv_k(
    const bf16* __restrict__ hid,
    const float* __restrict__ nw2, const float* __restrict__ nb2,
    const float* __restrict__ mw2, const float* __restrict__ mb2,
    const float* __restrict__ dw2, const float* __restrict__ db2,
    const float* __restrict__ maskBias, float* __restrict__ biasMain) {
  int w = threadIdx.x >> 6, lane = threadIdx.x & 63;
  int row = blockIdx.x * 4 + w;
  const bf16* hr = hid + (size_t)row * 384;
  const float* W2[3] = {nw2, mw2, dw2};
  float outs[3];
#pragma unroll
  for (int t = 0; t < 3; t++) {
    float acc = (float)hr[t * 128 + lane] * W2[t][lane] +
                (float)hr[t * 128 + 64 + lane] * W2[t][64 + lane];
    for (int msk = 1; msk < 64; msk <<= 1) acc += __shfl_xor(acc, msk);
    outs[t] = acc;
  }
  if (lane == 0) {
    float xn = outs[0] + nb2[0];
    float n = (xn > 20.f) ? xn : log1pf(__expf(xn));
    float mu = 1.f / (1.f + __expf(-(outs[1] + mb2[0])));
    float delta = fmaxf(outs[2] + db2[0], 0.f);
    float surv = logf(n + 1e-8f) + logf(mu + 1e-8f) - delta;
    biasMain[row] = 0.1f * surv + maskBias[row];
  }
}

extern "C" void kernel_launch(void* const* d_in, const int* in_sizes, int n_in,
                              void* d_out, int out_size, void* d_ws, size_t ws_size,
                              hipStream_t stream) {
  const int B = 2, S = 2048, H = 768, I = 256;
  const int NH = 12, SNH = 4;
  const int M = B * S;  // 4096

  const float* x = (const float*)d_in[0];
  const int* mask = (const int*)d_in[1];
  const float* qw = (const float*)d_in[2];
  const float* qb = (const float*)d_in[3];
  const float* kw = (const float*)d_in[4];
  const float* kb = (const float*)d_in[5];
  const float* vw = (const float*)d_in[6];
  const float* vb = (const float*)d_in[7];
  const float* ow = (const float*)d_in[8];
  const float* ob = (const float*)d_in[9];
  const float* sp_w = (const float*)d_in[10];
  const float* sp_b = (const float*)d_in[11];
  const float* sa_in_w = (const float*)d_in[12];
  const float* sa_in_b = (const float*)d_in[13];
  const float* sa_out_w = (const float*)d_in[14];
  const float* sa_out_b = (const float*)d_in[15];
  const float* nw1 = (const float*)d_in[16];
  const float* nb1 = (const float*)d_in[17];
  const float* nw2 = (const float*)d_in[18];
  const float* nb2 = (const float*)d_in[19];
  const float* mw1 = (const float*)d_in[20];
  const float* mb1 = (const float*)d_in[21];
  const float* mw2 = (const float*)d_in[22];
  const float* mb2 = (const float*)d_in[23];
  const float* dw1 = (const float*)d_in[24];
  const float* db1 = (const float*)d_in[25];
  const float* dw2 = (const float*)d_in[26];
  const float* db2 = (const float*)d_in[27];

  char* ws = (char*)d_ws;
  size_t off = 0;
  auto alloc = [&](size_t bytes) -> void* {
    void* p = ws + off;
    off += (bytes + 255) & ~(size_t)255;
    return p;
  };

  // persistent
  bf16* xb = (bf16*)alloc((size_t)M * H * 2);
  bf16* wqkv = (bf16*)alloc((size_t)3 * H * H * 2);
  float* bqkv = (float*)alloc((size_t)3 * H * 4);
  bf16* wob = (bf16*)alloc((size_t)H * H * 2);
  bf16* spwb = (bf16*)alloc((size_t)I * H * 2);
  bf16* sainb = (bf16*)alloc((size_t)(3 * I) * I * 2);
  bf16* saoutb = (bf16*)alloc((size_t)I * I * 2);
  bf16* w1pack = (bf16*)alloc((size_t)384 * 256 * 2);
  float* b1pack = (float*)alloc((size_t)384 * 4);
  float* maskBias = (float*)alloc((size_t)M * 4);
  float* biasMain = (float*)alloc((size_t)M * 4);

  const int SPM = 2, SPS = 4;
  size_t offMark = off;
  // phase A (scorer)
  bf16* h0 = (bf16*)alloc((size_t)M * I * 2);
  bf16* qkv_s = (bf16*)alloc((size_t)M * (3 * I) * 2);
  bf16* vt_s = (bf16*)alloc((size_t)B * SNH * 64 * S * 2);
  bf16* attn_s = (bf16*)alloc((size_t)M * I * 2);
  bf16* h1 = (bf16*)alloc((size_t)M * I * 2);
  bf16* hid = (bf16*)alloc((size_t)M * 384 * 2);
  float* Opart_s = (float*)alloc((size_t)SPS * B * SNH * S * 64 * 4);
  float2* ML_s = (float2*)alloc((size_t)SPS * B * SNH * S * 8);
  size_t endA = off;
  // phase B (main) overlays phase A
  off = offMark;
  bf16* QKVm = (bf16*)alloc((size_t)M * 3 * H * 2);
  bf16* vt_m = (bf16*)alloc((size_t)B * NH * 64 * S * 2);
  bf16* attn_m = (bf16*)alloc((size_t)M * H * 2);
  float* Opart_m = (float*)alloc((size_t)SPM * B * NH * S * 64 * 4);
  float2* ML_m = (float2*)alloc((size_t)SPM * B * NH * S * 8);
  size_t endB = off;
  size_t need = endA > endB ? endA : endB;
  bool split_ok = ws_size >= need;
  (void)in_sizes; (void)n_in; (void)out_size;

  auto cdiv = [](int a, int b) { return (a + b - 1) / b; };

  // converts + weight packing
  cvt_bf16<<<cdiv(M * H / 4, 256), 256, 0, stream>>>(x, xb, M * H / 4);
  cvt_bf16<<<cdiv(H * H / 4, 256), 256, 0, stream>>>(qw, wqkv, H * H / 4);
  cvt_bf16<<<cdiv(H * H / 4, 256), 256, 0, stream>>>(kw, wqkv + H * H, H * H / 4);
  cvt_bf16<<<cdiv(H * H / 4, 256), 256, 0, stream>>>(vw, wqkv + 2 * H * H, H * H / 4);
  hipMemcpyAsync(bqkv, qb, H * 4, hipMemcpyDeviceToDevice, stream);
  hipMemcpyAsync(bqkv + H, kb, H * 4, hipMemcpyDeviceToDevice, stream);
  hipMemcpyAsync(bqkv + 2 * H, vb, H * 4, hipMemcpyDeviceToDevice, stream);
  cvt_bf16<<<cdiv(H * H / 4, 256), 256, 0, stream>>>(ow, wob, H * H / 4);
  cvt_bf16<<<cdiv(I * H / 4, 256), 256, 0, stream>>>(sp_w, spwb, I * H / 4);
  cvt_bf16<<<cdiv(3 * I * I / 4, 256), 256, 0, stream>>>(sa_in_w, sainb, 3 * I * I / 4);
  cvt_bf16<<<cdiv(I * I / 4, 256), 256, 0, stream>>>(sa_out_w, saoutb, I * I / 4);
  cvt_bf16<<<cdiv(128 * 256 / 4, 256), 256, 0, stream>>>(nw1, w1pack, 128 * 256 / 4);
  cvt_bf16<<<cdiv(128 * 256 / 4, 256), 256, 0, stream>>>(mw1, w1pack + 128 * 256, 128 * 256 / 4);
  cvt_bf16<<<cdiv(128 * 256 / 4, 256), 256, 0, stream>>>(dw1, w1pack + 2 * 128 * 256, 128 * 256 / 4);
  hipMemcpyAsync(b1pack, nb1, 128 * 4, hipMemcpyDeviceToDevice, stream);
  hipMemcpyAsync(b1pack + 128, mb1, 128 * 4, hipMemcpyDeviceToDevice, stream);
  hipMemcpyAsync(b1pack + 256, db1, 128 * 4, hipMemcpyDeviceToDevice, stream);
  maskbias_k<<<cdiv(M, 256), 256, 0, stream>>>(mask, maskBias, M);

  // ---- scorer branch ----
  gemm_nt<0, 0><<<(M / 64) * (I / 64), 256, 0, stream>>>(xb, H, spwb, H, sp_b, h0, I, I / 64, H);
  gemm_nt<0, 0><<<(M / 64) * ((3 * I) / 64), 256, 0, stream>>>(h0, I, sainb, I, sa_in_b, qkv_s,
                                                               3 * I, (3 * I) / 64, I);
  vtrans<<<B * SNH * (S / 64), 256, 0, stream>>>(qkv_s, 3 * I, 2 * I, vt_s, SNH, S);
  if (split_ok) {
    flash2_k<SPS, 1><<<SPS * B * SNH * (S / 64), 256, 0, stream>>>(
        qkv_s, qkv_s + I, 3 * I, vt_s, maskBias, nullptr, 0, Opart_s, ML_s, SNH, S, 0.125f, B);
    flash_comb<<<(B * SNH * S * 16) / 256, 256, 0, stream>>>(Opart_s, ML_s, attn_s, I, SNH, S,
                                                             B, SPS);
  } else {
    flash2_k<1, 0><<<B * SNH * (S / 64), 256, 0, stream>>>(
        qkv_s, qkv_s + I, 3 * I, vt_s, maskBias, attn_s, I, nullptr, nullptr, SNH, S, 0.125f, B);
  }
  gemm_nt<0, 0><<<(M / 64) * (I / 64), 256, 0, stream>>>(attn_s, I, saoutb, I, sa_out_b, h1, I,
                                                         I / 64, I);
  gemm_nt<0, 1><<<(M / 64) * (384 / 64), 256, 0, stream>>>(h1, I, w1pack, I, b1pack, hid, 384,
                                                           384 / 64, I);
  surv_k<<<M / 4, 256, 0, stream>>>(hid, nw2, nb2, mw2, mb2, dw2, db2, maskBias, biasMain);

  // ---- main branch ----
  gemm_nt<0, 0><<<(M / 64) * (3 * H / 64), 256, 0, stream>>>(xb, H, wqkv, H, bqkv, QKVm, 3 * H,
                                                             3 * H / 64, H);
  vtrans<<<B * NH * (S / 64), 256, 0, stream>>>(QKVm, 3 * H, 2 * H, vt_m, NH, S);
  if (split_ok) {
    flash2_k<SPM, 1><<<SPM * B * NH * (S / 64), 256, 0, stream>>>(
        QKVm, QKVm + H, 3 * H, vt_m, biasMain, nullptr, 0, Opart_m, ML_m, NH, S, 0.125f, B);
    flash_comb<<<(B * NH * S * 16) / 256, 256, 0, stream>>>(Opart_m, ML_m, attn_m, H, NH, S, B,
                                                            SPM);
  } else {
    flash2_k<1, 0><<<B * NH * (S / 64), 256, 0, stream>>>(
        QKVm, QKVm + H, 3 * H, vt_m, biasMain, attn_m, H, nullptr, nullptr, NH, S, 0.125f, B);
  }
  gemm_nt<1, 0><<<(M / 64) * (H / 64), 256, 0, stream>>>(attn_m, H, wob, H, ob, d_out, H,
                                                         H / 64, H);
}

// Round 4
// 380.811 us; speedup vs baseline: 1.3536x; 1.3536x over previous
//
#include <hip/hip_runtime.h>
#include <math.h>

typedef __bf16 bf16;
typedef __bf16 bfrag __attribute__((ext_vector_type(8)));
typedef __bf16 bf4 __attribute__((ext_vector_type(4)));
typedef float f4 __attribute__((ext_vector_type(4)));

#define DEV static __device__ __forceinline__

DEV f4 MFMA(bfrag a, bfrag b, f4 c) {
  return __builtin_amdgcn_mfma_f32_16x16x32_bf16(a, b, c, 0, 0, 0);
}

// ---------------- fused setup: all fp32->bf16 converts + bias packs + maskbias ----------------
// One launch replaces 11 cvt + 6 d2d copies + maskbias (launch overhead was ~25us).
__global__ __launch_bounds__(256) void pack_all(
    const float* __restrict__ x, const float* __restrict__ qw, const float* __restrict__ kw,
    const float* __restrict__ vw, const float* __restrict__ ow, const float* __restrict__ sp_w,
    const float* __restrict__ sa_in_w, const float* __restrict__ sa_out_w,
    const float* __restrict__ nw1, const float* __restrict__ mw1, const float* __restrict__ dw1,
    const float* __restrict__ qb, const float* __restrict__ kb, const float* __restrict__ vb,
    const float* __restrict__ nb1, const float* __restrict__ mb1, const float* __restrict__ db1,
    const int* __restrict__ mask,
    bf16* __restrict__ xb, bf16* __restrict__ wqkv, bf16* __restrict__ wob,
    bf16* __restrict__ spwb, bf16* __restrict__ sainb, bf16* __restrict__ saoutb,
    bf16* __restrict__ w1pack, float* __restrict__ bqkv, float* __restrict__ b1pack,
    float* __restrict__ maskBias) {
  int bid = blockIdx.x;
  int tid = threadIdx.x;
  const float* src = nullptr;
  bf16* dst = nullptr;
  int rel = 0;
  // segment table (blocks of 1024 f32 = 256 lanes x float4)
  if (bid < 3072)      { src = x;       dst = xb;                   rel = bid; }
  else if (bid < 3648) { src = qw;      dst = wqkv;                 rel = bid - 3072; }
  else if (bid < 4224) { src = kw;      dst = wqkv + 589824;        rel = bid - 3648; }
  else if (bid < 4800) { src = vw;      dst = wqkv + 2 * 589824;    rel = bid - 4224; }
  else if (bid < 5376) { src = ow;      dst = wob;                  rel = bid - 4800; }
  else if (bid < 5568) { src = sp_w;    dst = spwb;                 rel = bid - 5376; }
  else if (bid < 5760) { src = sa_in_w; dst = sainb;                rel = bid - 5568; }
  else if (bid < 5824) { src = sa_out_w;dst = saoutb;               rel = bid - 5760; }
  else if (bid < 5856) { src = nw1;     dst = w1pack;               rel = bid - 5824; }
  else if (bid < 5888) { src = mw1;     dst = w1pack + 32768;       rel = bid - 5856; }
  else if (bid < 5920) { src = dw1;     dst = w1pack + 2 * 32768;   rel = bid - 5888; }
  else if (bid == 5920) {
    // bqkv: 3 x 768 f32 = 576 float4
    if (tid < 576) {
      int which = tid / 192, j = tid % 192;
      const float* s = which == 0 ? qb : (which == 1 ? kb : vb);
      reinterpret_cast<float4*>(bqkv)[tid] = reinterpret_cast<const float4*>(s)[j];
    }
    return;
  } else if (bid == 5921) {
    // b1pack: 3 x 128 f32 = 96 float4
    if (tid < 96) {
      int which = tid / 32, j = tid % 32;
      const float* s = which == 0 ? nb1 : (which == 1 ? mb1 : db1);
      reinterpret_cast<float4*>(b1pack)[tid] = reinterpret_cast<const float4*>(s)[j];
    }
    return;
  } else {
    // maskBias: 4096 ints = 1024 int4, 4 blocks
    int idx = (bid - 5922) * 256 + tid;
    int4 m = reinterpret_cast<const int4*>(mask)[idx];
    float4 o;
    o.x = m.x > 0 ? 0.f : -1e9f;
    o.y = m.y > 0 ? 0.f : -1e9f;
    o.z = m.z > 0 ? 0.f : -1e9f;
    o.w = m.w > 0 ? 0.f : -1e9f;
    reinterpret_cast<float4*>(maskBias)[idx] = o;
    return;
  }
  int i = rel * 256 + tid;
  float4 v = reinterpret_cast<const float4*>(src)[i];
  bf4 o;
  o[0] = (bf16)v.x; o[1] = (bf16)v.y; o[2] = (bf16)v.z; o[3] = (bf16)v.w;
  reinterpret_cast<bf4*>(dst)[i] = o;
}

// ---------------- GEMM: C[M,N] = act(A[M,K] @ W[N,K]^T + bias) ----------------
template<int OUTF32, int RELU>
__global__ __launch_bounds__(256) void gemm_nt(
    const bf16* __restrict__ A, int lda,
    const bf16* __restrict__ W, int ldw,
    const float* __restrict__ bias,
    void* __restrict__ C, int ldc,
    int N64, int K) {
  int lane = threadIdx.x & 63;
  int w = threadIdx.x >> 6;
  int lrow = lane & 15, lgrp = lane >> 4;
  int tn = blockIdx.x % N64, tm = blockIdx.x / N64;
  int m0 = tm * 64 + (w >> 1) * 32;
  int n0 = tn * 64 + (w & 1) * 32;
  const bf16* Ab = A + (size_t)m0 * lda + lgrp * 8;
  const bf16* Wb = W + (size_t)n0 * ldw + lgrp * 8;
  f4 acc[2][2] = {};
  for (int k0 = 0; k0 < K; k0 += 32) {
    bfrag a0 = *(const bfrag*)(Ab + (size_t)lrow * lda + k0);
    bfrag a1 = *(const bfrag*)(Ab + (size_t)(lrow + 16) * lda + k0);
    bfrag b0 = *(const bfrag*)(Wb + (size_t)lrow * ldw + k0);
    bfrag b1 = *(const bfrag*)(Wb + (size_t)(lrow + 16) * ldw + k0);
    acc[0][0] = MFMA(a0, b0, acc[0][0]);
    acc[0][1] = MFMA(a0, b1, acc[0][1]);
    acc[1][0] = MFMA(a1, b0, acc[1][0]);
    acc[1][1] = MFMA(a1, b1, acc[1][1]);
  }
#pragma unroll
  for (int mi = 0; mi < 2; mi++)
#pragma unroll
    for (int nj = 0; nj < 2; nj++) {
      int col = n0 + nj * 16 + lrow;
      float bv = bias[col];
      int rowb = m0 + mi * 16 + lgrp * 4;
#pragma unroll
      for (int i = 0; i < 4; i++) {
        float v = acc[mi][nj][i] + bv;
        if (RELU) v = fmaxf(v, 0.f);
        if (OUTF32)
          ((float*)C)[(size_t)(rowb + i) * ldc + col] = v;
        else
          ((bf16*)C)[(size_t)(rowb + i) * ldc + col] = (bf16)v;
      }
    }
}

// ---------------- V transpose: Vt[b][h][d][s] = V[b][s][coff + h*64 + d] ----------------
__global__ __launch_bounds__(256) void vtrans(const bf16* __restrict__ V, int rs, int coff,
                                              bf16* __restrict__ Vt, int H, int S) {
  int nst = S / 64;
  int st = blockIdx.x % nst;
  int h = (blockIdx.x / nst) % H;
  int b = blockIdx.x / (nst * H);
  __shared__ bf16 tile[64][72];
  int t = threadIdx.x;
  int r = t >> 2, c = t & 3;
  const bf16* src = V + ((size_t)b * S + st * 64 + r) * rs + coff + h * 64 + c * 16;
  bfrag v0 = *(const bfrag*)(src);
  bfrag v1 = *(const bfrag*)(src + 8);
  *(bfrag*)&tile[r][c * 16] = v0;
  *(bfrag*)&tile[r][c * 16 + 8] = v1;
  __syncthreads();
  bf16* dst = Vt + (((size_t)b * H + h) * 64 + r) * S + st * 64 + c * 16;
  bfrag o0, o1;
#pragma unroll
  for (int j = 0; j < 8; j++) {
    o0[j] = tile[c * 16 + j][r];
    o1[j] = tile[c * 16 + 8 + j][r];
  }
  *(bfrag*)dst = o0;
  *(bfrag*)(dst + 8) = o1;
}

// ---------------- flash attention v3: 32 q/wave, swapped operands, defer-rescale ----------------
// QK^T as mfma(K,Q): score[key][q]; softmax lane-local (q = lane&15, 2 q-frags).
// PV as mfma(V,P): out[d][q]. K/V/bias loads amortized over 2 q-frags (32 MFMA/tile).
template<int SPLIT, int PARTIAL>
__global__ __launch_bounds__(256) void flash3_k(
    const bf16* __restrict__ Q, const bf16* __restrict__ Kp, int rs,
    const bf16* __restrict__ Vt, const float* __restrict__ bias,
    bf16* __restrict__ O, int ors,
    float* __restrict__ Opart, float2* __restrict__ MLpart,
    int H, int S, float scale, int Bc) {
  int nqt = S / 128;
  int bid = blockIdx.x;
  int qt = bid % nqt;
  int h = (bid / nqt) % H;
  int b = (bid / (nqt * H)) % Bc;
  int sp = bid / (nqt * H * Bc);
  int lane = threadIdx.x & 63, w = threadIdx.x >> 6;
  int lrow = lane & 15, lgrp = lane >> 4;
  int q0 = qt * 128 + w * 32;
  const int kchunk = S / SPLIT;
  int k_beg = sp * kchunk;

  // Q fragments: 2 q-tiles x 2 k-slices
  bfrag qf[4];
#pragma unroll
  for (int qi = 0; qi < 2; qi++) {
    const bf16* Qb = Q + ((size_t)b * S + q0 + qi * 16 + lrow) * rs + h * 64 + lgrp * 8;
    qf[qi * 2] = *(const bfrag*)(Qb);
    qf[qi * 2 + 1] = *(const bfrag*)(Qb + 32);
  }
  const bf16* Kb = Kp + (size_t)b * S * rs + h * 64 + lgrp * 8;
  const bf16* Vb = Vt + ((size_t)b * H + h) * 64 * (size_t)S + lgrp * 8;
  const float* biasb = bias + (size_t)b * S;

  __shared__ bf16 P[4][2][16][72];
  f4 acc[2][4] = {};
  float mrun[2], lrun[2];
#pragma unroll
  for (int qi = 0; qi < 2; qi++) { mrun[qi] = -3.0e38f; lrun[qi] = 0.f; }

  for (int kt = k_beg; kt < k_beg + kchunk; kt += 64) {
    // bias for this tile (key-indexed, shared across q-frags)
    f4 bv[4];
#pragma unroll
    for (int cf = 0; cf < 4; cf++)
      bv[cf] = *(const f4*)(biasb + kt + cf * 16 + lgrp * 4);

    // QK^T: each K pair feeds both q-frags
    f4 s[2][4];
#pragma unroll
    for (int cf = 0; cf < 4; cf++) {
      const bf16* kr = Kb + (size_t)(kt + cf * 16 + lrow) * rs;
      bfrag k0 = *(const bfrag*)(kr);
      bfrag k1 = *(const bfrag*)(kr + 32);
      f4 z0 = {0.f, 0.f, 0.f, 0.f};
      z0 = MFMA(k0, qf[0], z0);
      z0 = MFMA(k1, qf[1], z0);
      s[0][cf] = z0;
      f4 z1 = {0.f, 0.f, 0.f, 0.f};
      z1 = MFMA(k0, qf[2], z1);
      z1 = MFMA(k1, qf[3], z1);
      s[1][cf] = z1;
    }

    // softmax per q-frag (lane-local; keys spread over cf,i and lgrp)
#pragma unroll
    for (int qi = 0; qi < 2; qi++) {
#pragma unroll
      for (int cf = 0; cf < 4; cf++)
#pragma unroll
        for (int i = 0; i < 4; i++) s[qi][cf][i] = s[qi][cf][i] * scale + bv[cf][i];
      f4 t0, t1;
#pragma unroll
      for (int i = 0; i < 4; i++) {
        t0[i] = fmaxf(s[qi][0][i], s[qi][1][i]);
        t1[i] = fmaxf(s[qi][2][i], s[qi][3][i]);
      }
      float mx = fmaxf(fmaxf(fmaxf(t0[0], t0[1]), fmaxf(t0[2], t0[3])),
                       fmaxf(fmaxf(t1[0], t1[1]), fmaxf(t1[2], t1[3])));
      mx = fmaxf(mx, __shfl_xor(mx, 16));
      mx = fmaxf(mx, __shfl_xor(mx, 32));
      // T13 defer-rescale: skip rescale when tile max is within threshold
      if (!__all(mx <= mrun[qi] + 8.f)) {
        float mn = fmaxf(mrun[qi], mx);
        float sc0 = __expf(mrun[qi] - mn);
        mrun[qi] = mn;
        lrun[qi] *= sc0;
#pragma unroll
        for (int df = 0; df < 4; df++)
#pragma unroll
          for (int i = 0; i < 4; i++) acc[qi][df][i] *= sc0;
      }
      float mn = mrun[qi];
#pragma unroll
      for (int cf = 0; cf < 4; cf++)
#pragma unroll
        for (int i = 0; i < 4; i++) s[qi][cf][i] = __expf(s[qi][cf][i] - mn);
      f4 u0, u1;
#pragma unroll
      for (int i = 0; i < 4; i++) {
        u0[i] = s[qi][0][i] + s[qi][1][i];
        u1[i] = s[qi][2][i] + s[qi][3][i];
      }
      float rsum = ((u0[0] + u0[1]) + (u0[2] + u0[3])) + ((u1[0] + u1[1]) + (u1[2] + u1[3]));
      rsum += __shfl_xor(rsum, 16);
      rsum += __shfl_xor(rsum, 32);
      lrun[qi] += rsum;
      // P -> LDS (row q=lrow, contiguous 4 keys per write)
#pragma unroll
      for (int cf = 0; cf < 4; cf++) {
        bf4 pb;
#pragma unroll
        for (int i = 0; i < 4; i++) pb[i] = (bf16)s[qi][cf][i];
        *(bf4*)&P[w][qi][lrow][cf * 16 + lgrp * 4] = pb;
      }
    }

    // PV: each V load feeds both q-frags
#pragma unroll
    for (int ks = 0; ks < 2; ks++) {
      bfrag pa0 = *(const bfrag*)&P[w][0][lrow][ks * 32 + lgrp * 8];
      bfrag pa1 = *(const bfrag*)&P[w][1][lrow][ks * 32 + lgrp * 8];
#pragma unroll
      for (int df = 0; df < 4; df++) {
        bfrag vfr = *(const bfrag*)(Vb + (size_t)(df * 16 + lrow) * S + kt + ks * 32);
        acc[0][df] = MFMA(vfr, pa0, acc[0][df]);
        acc[1][df] = MFMA(vfr, pa1, acc[1][df]);
      }
    }
  }

#pragma unroll
  for (int qi = 0; qi < 2; qi++) {
    int q = q0 + qi * 16 + lrow;
    if (PARTIAL) {
      float* op = Opart + ((((size_t)sp * Bc + b) * H + h) * S + q) * 64 + lgrp * 4;
#pragma unroll
      for (int df = 0; df < 4; df++) *(f4*)(op + df * 16) = acc[qi][df];
      if (lgrp == 0) {
        float2 ml; ml.x = mrun[qi]; ml.y = lrun[qi];
        MLpart[(((size_t)sp * Bc + b) * H + h) * S + q] = ml;
      }
    } else {
      float inv = 1.f / lrun[qi];
      bf16* Ob = O + ((size_t)b * S + q) * ors + h * 64 + lgrp * 4;
#pragma unroll
      for (int df = 0; df < 4; df++) {
        bf4 obv;
#pragma unroll
        for (int i = 0; i < 4; i++) obv[i] = (bf16)(acc[qi][df][i] * inv);
        *(bf4*)(Ob + df * 16) = obv;
      }
    }
  }
}

// ---------------- combine split-K flash partials ----------------
__global__ __launch_bounds__(256) void flash_comb(
    const float* __restrict__ Opart, const float2* __restrict__ ML,
    bf16* __restrict__ O, int ors, int Hh, int S, int Bc, int nsplit) {
  int idx = blockIdx.x * 256 + threadIdx.x;
  int d4 = idx & 15;
  int q = (idx >> 4) % S;
  int hh = ((idx >> 4) / S) % Hh;
  int b = (idx >> 4) / (S * Hh);
  size_t rowstride = (size_t)Bc * Hh * S;
  size_t rbase = ((size_t)b * Hh + hh) * S + q;
  float m = -3.0e38f;
  for (int sp = 0; sp < nsplit; sp++) m = fmaxf(m, ML[sp * rowstride + rbase].x);
  float lsum = 0.f;
  f4 o = {0.f, 0.f, 0.f, 0.f};
  for (int sp = 0; sp < nsplit; sp++) {
    float2 ml = ML[sp * rowstride + rbase];
    float wgt = __expf(ml.x - m);
    lsum += ml.y * wgt;
    f4 a = *(const f4*)(Opart + (sp * rowstride + rbase) * 64 + d4 * 4);
#pragma unroll
    for (int i = 0; i < 4; i++) o[i] += a[i] * wgt;
  }
  float inv = 1.f / lsum;
  bf4 obv;
#pragma unroll
  for (int i = 0; i < 4; i++) obv[i] = (bf16)(o[i] * inv);
  *(bf4*)(O + ((size_t)b * S + q) * ors + hh * 64 + d4 * 4) = obv;
}

// ---------------- survival epilogue ----------------
__global__ __launch_bounds__(256) void surv_k(
    const bf16* __restrict__ hid,
    const float* __restrict__ nw2, const float* __restrict__ nb2,
    const float* __restrict__ mw2, const float* __restrict__ mb2,
    const float* __restrict__ dw2, const float* __restrict__ db2,
    const float* __restrict__ maskBias, float* __restrict__ biasMain) {
  int w = threadIdx.x >> 6, lane = threadIdx.x & 63;
  int row = blockIdx.x * 4 + w;
  const bf16* hr = hid + (size_t)row * 384;
  const float* W2[3] = {nw2, mw2, dw2};
  float outs[3];
#pragma unroll
  for (int t = 0; t < 3; t++) {
    float acc = (float)hr[t * 128 + lane] * W2[t][lane] +
                (float)hr[t * 128 + 64 + lane] * W2[t][64 + lane];
    for (int msk = 1; msk < 64; msk <<= 1) acc += __shfl_xor(acc, msk);
    outs[t] = acc;
  }
  if (lane == 0) {
    float xn = outs[0] + nb2[0];
    float n = (xn > 20.f) ? xn : log1pf(__expf(xn));
    float mu = 1.f / (1.f + __expf(-(outs[1] + mb2[0])));
    float delta = fmaxf(outs[2] + db2[0], 0.f);
    float surv = logf(n + 1e-8f) + logf(mu + 1e-8f) - delta;
    biasMain[row] = 0.1f * surv + maskBias[row];
  }
}

extern "C" void kernel_launch(void* const* d_in, const int* in_sizes, int n_in,
                              void* d_out, int out_size, void* d_ws, size_t ws_size,
                              hipStream_t stream) {
  const int B = 2, S = 2048, H = 768, I = 256;
  const int NH = 12, SNH = 4;
  const int M = B * S;  // 4096

  const float* x = (const float*)d_in[0];
  const int* mask = (const int*)d_in[1];
  const float* qw = (const float*)d_in[2];
  const float* qb = (const float*)d_in[3];
  const float* kw = (const float*)d_in[4];
  const float* kb = (const float*)d_in[5];
  const float* vw = (const float*)d_in[6];
  const float* vb = (const float*)d_in[7];
  const float* ow = (const float*)d_in[8];
  const float* ob = (const float*)d_in[9];
  const float* sp_w = (const float*)d_in[10];
  const float* sp_b = (const float*)d_in[11];
  const float* sa_in_w = (const float*)d_in[12];
  const float* sa_in_b = (const float*)d_in[13];
  const float* sa_out_w = (const float*)d_in[14];
  const float* sa_out_b = (const float*)d_in[15];
  const float* nw1 = (const float*)d_in[16];
  const float* nb1 = (const float*)d_in[17];
  const float* nw2 = (const float*)d_in[18];
  const float* nb2 = (const float*)d_in[19];
  const float* mw1 = (const float*)d_in[20];
  const float* mb1 = (const float*)d_in[21];
  const float* mw2 = (const float*)d_in[22];
  const float* mb2 = (const float*)d_in[23];
  const float* dw1 = (const float*)d_in[24];
  const float* db1 = (const float*)d_in[25];
  const float* dw2 = (const float*)d_in[26];
  const float* db2 = (const float*)d_in[27];

  char* ws = (char*)d_ws;
  size_t off = 0;
  auto alloc = [&](size_t bytes) -> void* {
    void* p = ws + off;
    off += (bytes + 255) & ~(size_t)255;
    return p;
  };

  // persistent
  bf16* xb = (bf16*)alloc((size_t)M * H * 2);
  bf16* wqkv = (bf16*)alloc((size_t)3 * H * H * 2);
  float* bqkv = (float*)alloc((size_t)3 * H * 4);
  bf16* wob = (bf16*)alloc((size_t)H * H * 2);
  bf16* spwb = (bf16*)alloc((size_t)I * H * 2);
  bf16* sainb = (bf16*)alloc((size_t)(3 * I) * I * 2);
  bf16* saoutb = (bf16*)alloc((size_t)I * I * 2);
  bf16* w1pack = (bf16*)alloc((size_t)384 * 256 * 2);
  float* b1pack = (float*)alloc((size_t)384 * 4);
  float* maskBias = (float*)alloc((size_t)M * 4);
  float* biasMain = (float*)alloc((size_t)M * 4);

  const int SPM = 4, SPS = 8;
  size_t offMark = off;
  // phase A (scorer)
  bf16* h0 = (bf16*)alloc((size_t)M * I * 2);
  bf16* qkv_s = (bf16*)alloc((size_t)M * (3 * I) * 2);
  bf16* vt_s = (bf16*)alloc((size_t)B * SNH * 64 * S * 2);
  bf16* attn_s = (bf16*)alloc((size_t)M * I * 2);
  bf16* h1 = (bf16*)alloc((size_t)M * I * 2);
  bf16* hid = (bf16*)alloc((size_t)M * 384 * 2);
  float* Opart_s = (float*)alloc((size_t)SPS * B * SNH * S * 64 * 4);
  float2* ML_s = (float2*)alloc((size_t)SPS * B * SNH * S * 8);
  size_t endA = off;
  // phase B (main) overlays phase A
  off = offMark;
  bf16* QKVm = (bf16*)alloc((size_t)M * 3 * H * 2);
  bf16* vt_m = (bf16*)alloc((size_t)B * NH * 64 * S * 2);
  bf16* attn_m = (bf16*)alloc((size_t)M * H * 2);
  float* Opart_m = (float*)alloc((size_t)SPM * B * NH * S * 64 * 4);
  float2* ML_m = (float2*)alloc((size_t)SPM * B * NH * S * 8);
  size_t endB = off;
  size_t need = endA > endB ? endA : endB;
  bool split_ok = ws_size >= need;
  (void)in_sizes; (void)n_in; (void)out_size;

  // fused setup (grid = 5926 per segment table in pack_all)
  pack_all<<<5926, 256, 0, stream>>>(x, qw, kw, vw, ow, sp_w, sa_in_w, sa_out_w, nw1, mw1, dw1,
                                     qb, kb, vb, nb1, mb1, db1, mask,
                                     xb, wqkv, wob, spwb, sainb, saoutb, w1pack, bqkv, b1pack,
                                     maskBias);

  // ---- scorer branch ----
  gemm_nt<0, 0><<<(M / 64) * (I / 64), 256, 0, stream>>>(xb, H, spwb, H, sp_b, h0, I, I / 64, H);
  gemm_nt<0, 0><<<(M / 64) * ((3 * I) / 64), 256, 0, stream>>>(h0, I, sainb, I, sa_in_b, qkv_s,
                                                               3 * I, (3 * I) / 64, I);
  vtrans<<<B * SNH * (S / 64), 256, 0, stream>>>(qkv_s, 3 * I, 2 * I, vt_s, SNH, S);
  if (split_ok) {
    flash3_k<SPS, 1><<<SPS * B * SNH * (S / 128), 256, 0, stream>>>(
        qkv_s, qkv_s + I, 3 * I, vt_s, maskBias, nullptr, 0, Opart_s, ML_s, SNH, S, 0.125f, B);
    flash_comb<<<(B * SNH * S * 16) / 256, 256, 0, stream>>>(Opart_s, ML_s, attn_s, I, SNH, S,
                                                             B, SPS);
  } else {
    flash3_k<1, 0><<<B * SNH * (S / 128), 256, 0, stream>>>(
        qkv_s, qkv_s + I, 3 * I, vt_s, maskBias, attn_s, I, nullptr, nullptr, SNH, S, 0.125f, B);
  }
  gemm_nt<0, 0><<<(M / 64) * (I / 64), 256, 0, stream>>>(attn_s, I, saoutb, I, sa_out_b, h1, I,
                                                         I / 64, I);
  gemm_nt<0, 1><<<(M / 64) * (384 / 64), 256, 0, stream>>>(h1, I, w1pack, I, b1pack, hid, 384,
                                                           384 / 64, I);
  surv_k<<<M / 4, 256, 0, stream>>>(hid, nw2, nb2, mw2, mb2, dw2, db2, maskBias, biasMain);

  // ---- main branch ----
  gemm_nt<0, 0><<<(M / 64) * (3 * H / 64), 256, 0, stream>>>(xb, H, wqkv, H, bqkv, QKVm, 3 * H,
                                                             3 * H / 64, H);
  vtrans<<<B * NH * (S / 64), 256, 0, stream>>>(QKVm, 3 * H, 2 * H, vt_m, NH, S);
  if (split_ok) {
    flash3_k<SPM, 1><<<SPM * B * NH * (S / 128), 256, 0, stream>>>(
        QKVm, QKVm + H, 3 * H, vt_m, biasMain, nullptr, 0, Opart_m, ML_m, NH, S, 0.125f, B);
    flash_comb<<<(B * NH * S * 16) / 256, 256, 0, stream>>>(Opart_m, ML_m, attn_m, H, NH, S, B,
                                                            SPM);
  } else {
    flash3_k<1, 0><<<B * NH * (S / 128), 256, 0, stream>>>(
        QKVm, QKVm + H, 3 * H, vt_m, biasMain, attn_m, H, nullptr, nullptr, NH, S, 0.125f, B);
  }
  gemm_nt<1, 0><<<(M / 64) * (H / 64), 256, 0, stream>>>(attn_m, H, wob, H, ob, d_out, H,
                                                         H / 64, H);
}

// Round 5
// 338.494 us; speedup vs baseline: 1.5228x; 1.1250x over previous
//
#include <hip/hip_runtime.h>
#include <math.h>

typedef __bf16 bf16;
typedef __bf16 bfrag __attribute__((ext_vector_type(8)));
typedef __bf16 bf4 __attribute__((ext_vector_type(4)));
typedef float f4 __attribute__((ext_vector_type(4)));
typedef float f16v __attribute__((ext_vector_type(16)));

#define DEV static __device__ __forceinline__

DEV f4 MFMA(bfrag a, bfrag b, f4 c) {
  return __builtin_amdgcn_mfma_f32_16x16x32_bf16(a, b, c, 0, 0, 0);
}
DEV f16v MFMA32(bfrag a, bfrag b, f16v c) {
  return __builtin_amdgcn_mfma_f32_32x32x16_bf16(a, b, c, 0, 0, 0);
}
DEV unsigned pkbf(float a, float b) {
  bf16 ha = (bf16)a, hb = (bf16)b;
  unsigned short ua = __builtin_bit_cast(unsigned short, ha);
  unsigned short ub = __builtin_bit_cast(unsigned short, hb);
  return (unsigned)ua | ((unsigned)ub << 16);
}

// ---------------- fused setup: all fp32->bf16 converts + bias packs + maskbias ----------------
__global__ __launch_bounds__(256) void pack_all(
    const float* __restrict__ x, const float* __restrict__ qw, const float* __restrict__ kw,
    const float* __restrict__ vw, const float* __restrict__ ow, const float* __restrict__ sp_w,
    const float* __restrict__ sa_in_w, const float* __restrict__ sa_out_w,
    const float* __restrict__ nw1, const float* __restrict__ mw1, const float* __restrict__ dw1,
    const float* __restrict__ qb, const float* __restrict__ kb, const float* __restrict__ vb,
    const float* __restrict__ nb1, const float* __restrict__ mb1, const float* __restrict__ db1,
    const int* __restrict__ mask,
    bf16* __restrict__ xb, bf16* __restrict__ wqkv, bf16* __restrict__ wob,
    bf16* __restrict__ spwb, bf16* __restrict__ sainb, bf16* __restrict__ saoutb,
    bf16* __restrict__ w1pack, float* __restrict__ bqkv, float* __restrict__ b1pack,
    float* __restrict__ maskBias) {
  int bid = blockIdx.x;
  int tid = threadIdx.x;
  const float* src = nullptr;
  bf16* dst = nullptr;
  int rel = 0;
  if (bid < 3072)      { src = x;       dst = xb;                   rel = bid; }
  else if (bid < 3648) { src = qw;      dst = wqkv;                 rel = bid - 3072; }
  else if (bid < 4224) { src = kw;      dst = wqkv + 589824;        rel = bid - 3648; }
  else if (bid < 4800) { src = vw;      dst = wqkv + 2 * 589824;    rel = bid - 4224; }
  else if (bid < 5376) { src = ow;      dst = wob;                  rel = bid - 4800; }
  else if (bid < 5568) { src = sp_w;    dst = spwb;                 rel = bid - 5376; }
  else if (bid < 5760) { src = sa_in_w; dst = sainb;                rel = bid - 5568; }
  else if (bid < 5824) { src = sa_out_w;dst = saoutb;               rel = bid - 5760; }
  else if (bid < 5856) { src = nw1;     dst = w1pack;               rel = bid - 5824; }
  else if (bid < 5888) { src = mw1;     dst = w1pack + 32768;       rel = bid - 5856; }
  else if (bid < 5920) { src = dw1;     dst = w1pack + 2 * 32768;   rel = bid - 5888; }
  else if (bid == 5920) {
    if (tid < 576) {
      int which = tid / 192, j = tid % 192;
      const float* s = which == 0 ? qb : (which == 1 ? kb : vb);
      reinterpret_cast<float4*>(bqkv)[tid] = reinterpret_cast<const float4*>(s)[j];
    }
    return;
  } else if (bid == 5921) {
    if (tid < 96) {
      int which = tid / 32, j = tid % 32;
      const float* s = which == 0 ? nb1 : (which == 1 ? mb1 : db1);
      reinterpret_cast<float4*>(b1pack)[tid] = reinterpret_cast<const float4*>(s)[j];
    }
    return;
  } else {
    int idx = (bid - 5922) * 256 + tid;
    int4 m = reinterpret_cast<const int4*>(mask)[idx];
    float4 o;
    o.x = m.x > 0 ? 0.f : -1e9f;
    o.y = m.y > 0 ? 0.f : -1e9f;
    o.z = m.z > 0 ? 0.f : -1e9f;
    o.w = m.w > 0 ? 0.f : -1e9f;
    reinterpret_cast<float4*>(maskBias)[idx] = o;
    return;
  }
  int i = rel * 256 + tid;
  float4 v = reinterpret_cast<const float4*>(src)[i];
  bf4 o;
  o[0] = (bf16)v.x; o[1] = (bf16)v.y; o[2] = (bf16)v.z; o[3] = (bf16)v.w;
  reinterpret_cast<bf4*>(dst)[i] = o;
}

// ---------------- GEMM 64x64 tile: C[M,N] = act(A[M,K] @ W[N,K]^T + bias) ----------------
template<int OUTF32, int RELU>
__global__ __launch_bounds__(256) void gemm_nt(
    const bf16* __restrict__ A, int lda,
    const bf16* __restrict__ W, int ldw,
    const float* __restrict__ bias,
    void* __restrict__ C, int ldc,
    int N64, int K) {
  int lane = threadIdx.x & 63;
  int w = threadIdx.x >> 6;
  int lrow = lane & 15, lgrp = lane >> 4;
  int tn = blockIdx.x % N64, tm = blockIdx.x / N64;
  int m0 = tm * 64 + (w >> 1) * 32;
  int n0 = tn * 64 + (w & 1) * 32;
  const bf16* Ab = A + (size_t)m0 * lda + lgrp * 8;
  const bf16* Wb = W + (size_t)n0 * ldw + lgrp * 8;
  f4 acc[2][2] = {};
  for (int k0 = 0; k0 < K; k0 += 32) {
    bfrag a0 = *(const bfrag*)(Ab + (size_t)lrow * lda + k0);
    bfrag a1 = *(const bfrag*)(Ab + (size_t)(lrow + 16) * lda + k0);
    bfrag b0 = *(const bfrag*)(Wb + (size_t)lrow * ldw + k0);
    bfrag b1 = *(const bfrag*)(Wb + (size_t)(lrow + 16) * ldw + k0);
    acc[0][0] = MFMA(a0, b0, acc[0][0]);
    acc[0][1] = MFMA(a0, b1, acc[0][1]);
    acc[1][0] = MFMA(a1, b0, acc[1][0]);
    acc[1][1] = MFMA(a1, b1, acc[1][1]);
  }
#pragma unroll
  for (int mi = 0; mi < 2; mi++)
#pragma unroll
    for (int nj = 0; nj < 2; nj++) {
      int col = n0 + nj * 16 + lrow;
      float bv = bias[col];
      int rowb = m0 + mi * 16 + lgrp * 4;
#pragma unroll
      for (int i = 0; i < 4; i++) {
        float v = acc[mi][nj][i] + bv;
        if (RELU) v = fmaxf(v, 0.f);
        if (OUTF32)
          ((float*)C)[(size_t)(rowb + i) * ldc + col] = v;
        else
          ((bf16*)C)[(size_t)(rowb + i) * ldc + col] = (bf16)v;
      }
    }
}

// ---------------- GEMM 128x128 tile (for the big QKV projection) ----------------
__global__ __launch_bounds__(256) void gemm_nt128(
    const bf16* __restrict__ A, int lda,
    const bf16* __restrict__ W, int ldw,
    const float* __restrict__ bias,
    bf16* __restrict__ C, int ldc,
    int N128, int K) {
  int lane = threadIdx.x & 63;
  int w = threadIdx.x >> 6;
  int lrow = lane & 15, lgrp = lane >> 4;
  int tn = blockIdx.x % N128, tm = blockIdx.x / N128;
  int m0 = tm * 128 + (w >> 1) * 64;
  int n0 = tn * 128 + (w & 1) * 64;
  const bf16* Ab = A + (size_t)m0 * lda + lgrp * 8;
  const bf16* Wb = W + (size_t)n0 * ldw + lgrp * 8;
  f4 acc[4][4] = {};
  for (int k0 = 0; k0 < K; k0 += 32) {
    bfrag a[4], bb[4];
#pragma unroll
    for (int i = 0; i < 4; i++) {
      a[i] = *(const bfrag*)(Ab + (size_t)(lrow + 16 * i) * lda + k0);
      bb[i] = *(const bfrag*)(Wb + (size_t)(lrow + 16 * i) * ldw + k0);
    }
#pragma unroll
    for (int mi = 0; mi < 4; mi++)
#pragma unroll
      for (int nj = 0; nj < 4; nj++)
        acc[mi][nj] = MFMA(a[mi], bb[nj], acc[mi][nj]);
  }
#pragma unroll
  for (int mi = 0; mi < 4; mi++)
#pragma unroll
    for (int nj = 0; nj < 4; nj++) {
      int col = n0 + nj * 16 + lrow;
      float bv = bias[col];
      int rowb = m0 + mi * 16 + lgrp * 4;
#pragma unroll
      for (int i = 0; i < 4; i++)
        C[(size_t)(rowb + i) * ldc + col] = (bf16)(acc[mi][nj][i] + bv);
    }
}

// ---------------- V transpose: Vt[b][h][d][s] = V[b][s][coff + h*64 + d] ----------------
__global__ __launch_bounds__(256) void vtrans(const bf16* __restrict__ V, int rs, int coff,
                                              bf16* __restrict__ Vt, int H, int S) {
  int nst = S / 64;
  int st = blockIdx.x % nst;
  int h = (blockIdx.x / nst) % H;
  int b = blockIdx.x / (nst * H);
  __shared__ bf16 tile[64][72];
  int t = threadIdx.x;
  int r = t >> 2, c = t & 3;
  const bf16* src = V + ((size_t)b * S + st * 64 + r) * rs + coff + h * 64 + c * 16;
  bfrag v0 = *(const bfrag*)(src);
  bfrag v1 = *(const bfrag*)(src + 8);
  *(bfrag*)&tile[r][c * 16] = v0;
  *(bfrag*)&tile[r][c * 16 + 8] = v1;
  __syncthreads();
  bf16* dst = Vt + (((size_t)b * H + h) * 64 + r) * S + st * 64 + c * 16;
  bfrag o0, o1;
#pragma unroll
  for (int j = 0; j < 8; j++) {
    o0[j] = tile[c * 16 + j][r];
    o1[j] = tile[c * 16 + 8 + j][r];
  }
  *(bfrag*)dst = o0;
  *(bfrag*)(dst + 8) = o1;
}

// ---------------- flash attention v4: 32x32 MFMA, fully LDS-free ----------------
// QK^T as mfma(K,Q): C col=lane&31 = q; row=(reg&3)+8*(reg>>2)+4*(lane>>5) = key.
// Softmax lane-local over 16 regs + one shfl_xor(32).
// PV as mfma(Vt,P): P B-operand built in-register (bf16 pack + shfl_xor(32)).
template<int SPLIT, int PARTIAL>
__global__ __launch_bounds__(256) void flash4_k(
    const bf16* __restrict__ Q, const bf16* __restrict__ Kp, int rs,
    const bf16* __restrict__ Vt, const float* __restrict__ bias,
    bf16* __restrict__ O, int ors,
    float* __restrict__ Opart, float2* __restrict__ MLpart,
    int H, int S, float scale, int Bc) {
  int nqt = S / 128;
  int bid = blockIdx.x;
  int qt = bid % nqt;
  int hh = (bid / nqt) % H;
  int b = (bid / (nqt * H)) % Bc;
  int sp = bid / (nqt * H * Bc);
  int lane = threadIdx.x & 63, w = threadIdx.x >> 6;
  int l31 = lane & 31, hf = lane >> 5;
  int q0 = qt * 128 + w * 32;
  const int kchunk = S / SPLIT;
  int k_beg = sp * kchunk;

  // Q B-operand frags: col=q=l31, k(d-dim) = 16c + 8*hf + i
  const bf16* Qb = Q + ((size_t)b * S + q0 + l31) * rs + hh * 64 + hf * 8;
  bfrag qf[4];
#pragma unroll
  for (int c = 0; c < 4; c++) qf[c] = *(const bfrag*)(Qb + 16 * c);

  const bf16* Kb = Kp + (size_t)b * S * rs + hh * 64 + hf * 8;
  const bf16* Vb = Vt + ((size_t)b * H + hh) * 64 * (size_t)S + hf * 8;
  const float* biasb = bias + (size_t)b * S;

  f16v acc0, acc1;
#pragma unroll
  for (int r = 0; r < 16; r++) { acc0[r] = 0.f; acc1[r] = 0.f; }
  float mrun = -3.0e38f, lrun = 0.f;

  for (int kt = k_beg; kt < k_beg + kchunk; kt += 32) {
    // ---- QK^T: A=K rows=keys kt..kt+31, k = 16c+8hf+i ----
    const bf16* Kr = Kb + (size_t)(kt + l31) * rs;
    f16v s;
#pragma unroll
    for (int r = 0; r < 16; r++) s[r] = 0.f;
#pragma unroll
    for (int c = 0; c < 4; c++) {
      bfrag kfr = *(const bfrag*)(Kr + 16 * c);
      s = MFMA32(kfr, qf[c], s);
    }
    // ---- bias: key = kt + (r&3) + 8*(r>>2) + 4*hf ----
    f4 bv[4];
#pragma unroll
    for (int g = 0; g < 4; g++)
      bv[g] = *(const f4*)(biasb + kt + g * 8 + hf * 4);
#pragma unroll
    for (int r = 0; r < 16; r++) s[r] = s[r] * scale + bv[r >> 2][r & 3];

    // ---- softmax (16 local + 1 shfl) ----
    float m01 = fmaxf(fmaxf(s[0], s[1]), fmaxf(s[2], s[3]));
    float m23 = fmaxf(fmaxf(s[4], s[5]), fmaxf(s[6], s[7]));
    float m45 = fmaxf(fmaxf(s[8], s[9]), fmaxf(s[10], s[11]));
    float m67 = fmaxf(fmaxf(s[12], s[13]), fmaxf(s[14], s[15]));
    float mx = fmaxf(fmaxf(m01, m23), fmaxf(m45, m67));
    mx = fmaxf(mx, __shfl_xor(mx, 32));
    if (!__all(mx <= mrun + 8.f)) {
      float mn = fmaxf(mrun, mx);
      float sc0 = __expf(mrun - mn);
      mrun = mn;
      lrun *= sc0;
#pragma unroll
      for (int r = 0; r < 16; r++) { acc0[r] *= sc0; acc1[r] *= sc0; }
    }
#pragma unroll
    for (int r = 0; r < 16; r++) s[r] = __expf(s[r] - mrun);
    float s0a = (s[0] + s[1]) + (s[2] + s[3]);
    float s0b = (s[4] + s[5]) + (s[6] + s[7]);
    float s0c = (s[8] + s[9]) + (s[10] + s[11]);
    float s0d = (s[12] + s[13]) + (s[14] + s[15]);
    float rsum = (s0a + s0b) + (s0c + s0d);
    rsum += __shfl_xor(rsum, 32);
    lrun += rsum;

    // ---- build P B-operand frags in-register ----
    // chain c covers mfma-k 0..15 <-> keys kt+16c..kt+16c+15.
    // lane needs keys 16c + 8*hf + (0..7); holds (regs 8c..8c+7) keys 16c+4hf+{0..3,8..11? no:}
    //   own regs 8c+j   = keys 16c + 4hf + j       (j=0..3)
    //   own regs 8c+4+j = keys 16c + 8 + 4hf + j
    bfrag pb[2];
#pragma unroll
    for (int c = 0; c < 2; c++) {
      unsigned lo0 = pkbf(s[8 * c + 0], s[8 * c + 1]);
      unsigned lo1 = pkbf(s[8 * c + 2], s[8 * c + 3]);
      unsigned hi0 = pkbf(s[8 * c + 4], s[8 * c + 5]);
      unsigned hi1 = pkbf(s[8 * c + 6], s[8 * c + 7]);
      // hf=0 sends keys 16c+8..11 (hi), needs partner's 16c+4..7 (its lo)
      // hf=1 sends keys 16c+4..7 (lo),  needs partner's 16c+8..11 (its hi)
      unsigned t0 = hf ? lo0 : hi0;
      unsigned t1 = hf ? lo1 : hi1;
      unsigned r0 = (unsigned)__shfl_xor((int)t0, 32);
      unsigned r1 = (unsigned)__shfl_xor((int)t1, 32);
      union { bfrag v; unsigned u[4]; } pu;
      pu.u[0] = hf ? r0 : lo0;
      pu.u[1] = hf ? r1 : lo1;
      pu.u[2] = hf ? hi0 : r0;
      pu.u[3] = hf ? hi1 : r1;
      pb[c] = pu.v;
    }

    // ---- PV: A = Vt rows d = 32*dt + l31, k = 16c + 8hf + i (keys) ----
    const bf16* Vr0 = Vb + (size_t)l31 * S + kt;
    const bf16* Vr1 = Vb + (size_t)(32 + l31) * S + kt;
#pragma unroll
    for (int c = 0; c < 2; c++) {
      acc0 = MFMA32(*(const bfrag*)(Vr0 + 16 * c), pb[c], acc0);
      acc1 = MFMA32(*(const bfrag*)(Vr1 + 16 * c), pb[c], acc1);
    }
  }

  int q = q0 + l31;
  if (PARTIAL) {
    float* op = Opart + ((((size_t)sp * Bc + b) * H + hh) * S + q) * 64 + hf * 4;
#pragma unroll
    for (int g = 0; g < 4; g++) {
      f4 v0, v1;
#pragma unroll
      for (int i = 0; i < 4; i++) { v0[i] = acc0[4 * g + i]; v1[i] = acc1[4 * g + i]; }
      *(f4*)(op + g * 8) = v0;
      *(f4*)(op + 32 + g * 8) = v1;
    }
    if (hf == 0) {
      float2 ml; ml.x = mrun; ml.y = lrun;
      MLpart[(((size_t)sp * Bc + b) * H + hh) * S + q] = ml;
    }
  } else {
    float inv = 1.f / lrun;
    bf16* Ob = O + ((size_t)b * S + q) * ors + hh * 64 + hf * 4;
#pragma unroll
    for (int g = 0; g < 4; g++) {
      bf4 o0, o1;
#pragma unroll
      for (int i = 0; i < 4; i++) {
        o0[i] = (bf16)(acc0[4 * g + i] * inv);
        o1[i] = (bf16)(acc1[4 * g + i] * inv);
      }
      *(bf4*)(Ob + g * 8) = o0;
      *(bf4*)(Ob + 32 + g * 8) = o1;
    }
  }
}

// ---------------- combine split-K flash partials ----------------
__global__ __launch_bounds__(256) void flash_comb(
    const float* __restrict__ Opart, const float2* __restrict__ ML,
    bf16* __restrict__ O, int ors, int Hh, int S, int Bc, int nsplit) {
  int idx = blockIdx.x * 256 + threadIdx.x;
  int d4 = idx & 15;
  int q = (idx >> 4) % S;
  int hh = ((idx >> 4) / S) % Hh;
  int b = (idx >> 4) / (S * Hh);
  size_t rowstride = (size_t)Bc * Hh * S;
  size_t rbase = ((size_t)b * Hh + hh) * S + q;
  float m = -3.0e38f;
  for (int sp = 0; sp < nsplit; sp++) m = fmaxf(m, ML[sp * rowstride + rbase].x);
  float lsum = 0.f;
  f4 o = {0.f, 0.f, 0.f, 0.f};
  for (int sp = 0; sp < nsplit; sp++) {
    float2 ml = ML[sp * rowstride + rbase];
    float wgt = __expf(ml.x - m);
    lsum += ml.y * wgt;
    f4 a = *(const f4*)(Opart + (sp * rowstride + rbase) * 64 + d4 * 4);
#pragma unroll
    for (int i = 0; i < 4; i++) o[i] += a[i] * wgt;
  }
  float inv = 1.f / lsum;
  bf4 obv;
#pragma unroll
  for (int i = 0; i < 4; i++) obv[i] = (bf16)(o[i] * inv);
  *(bf4*)(O + ((size_t)b * S + q) * ors + hh * 64 + d4 * 4) = obv;
}

// ---------------- survival epilogue ----------------
__global__ __launch_bounds__(256) void surv_k(
    const bf16* __restrict__ hid,
    const float* __restrict__ nw2, const float* __restrict__ nb2,
    const float* __restrict__ mw2, const float* __restrict__ mb2,
    const float* __restrict__ dw2, const float* __restrict__ db2,
    const float* __restrict__ maskBias, float* __restrict__ biasMain) {
  int w = threadIdx.x >> 6, lane = threadIdx.x & 63;
  int row = blockIdx.x * 4 + w;
  const bf16* hr = hid + (size_t)row * 384;
  const float* W2[3] = {nw2, mw2, dw2};
  float outs[3];
#pragma unroll
  for (int t = 0; t < 3; t++) {
    float acc = (float)hr[t * 128 + lane] * W2[t][lane] +
                (float)hr[t * 128 + 64 + lane] * W2[t][64 + lane];
    for (int msk = 1; msk < 64; msk <<= 1) acc += __shfl_xor(acc, msk);
    outs[t] = acc;
  }
  if (lane == 0) {
    float xn = outs[0] + nb2[0];
    float n = (xn > 20.f) ? xn : log1pf(__expf(xn));
    float mu = 1.f / (1.f + __expf(-(outs[1] + mb2[0])));
    float delta = fmaxf(outs[2] + db2[0], 0.f);
    float surv = logf(n + 1e-8f) + logf(mu + 1e-8f) - delta;
    biasMain[row] = 0.1f * surv + maskBias[row];
  }
}

extern "C" void kernel_launch(void* const* d_in, const int* in_sizes, int n_in,
                              void* d_out, int out_size, void* d_ws, size_t ws_size,
                              hipStream_t stream) {
  const int B = 2, S = 2048, H = 768, I = 256;
  const int NH = 12, SNH = 4;
  const int M = B * S;  // 4096

  const float* x = (const float*)d_in[0];
  const int* mask = (const int*)d_in[1];
  const float* qw = (const float*)d_in[2];
  const float* qb = (const float*)d_in[3];
  const float* kw = (const float*)d_in[4];
  const float* kb = (const float*)d_in[5];
  const float* vw = (const float*)d_in[6];
  const float* vb = (const float*)d_in[7];
  const float* ow = (const float*)d_in[8];
  const float* ob = (const float*)d_in[9];
  const float* sp_w = (const float*)d_in[10];
  const float* sp_b = (const float*)d_in[11];
  const float* sa_in_w = (const float*)d_in[12];
  const float* sa_in_b = (const float*)d_in[13];
  const float* sa_out_w = (const float*)d_in[14];
  const float* sa_out_b = (const float*)d_in[15];
  const float* nw1 = (const float*)d_in[16];
  const float* nb1 = (const float*)d_in[17];
  const float* nw2 = (const float*)d_in[18];
  const float* nb2 = (const float*)d_in[19];
  const float* mw1 = (const float*)d_in[20];
  const float* mb1 = (const float*)d_in[21];
  const float* mw2 = (const float*)d_in[22];
  const float* mb2 = (const float*)d_in[23];
  const float* dw1 = (const float*)d_in[24];
  const float* db1 = (const float*)d_in[25];
  const float* dw2 = (const float*)d_in[26];
  const float* db2 = (const float*)d_in[27];

  char* ws = (char*)d_ws;
  size_t off = 0;
  auto alloc = [&](size_t bytes) -> void* {
    void* p = ws + off;
    off += (bytes + 255) & ~(size_t)255;
    return p;
  };

  // persistent
  bf16* xb = (bf16*)alloc((size_t)M * H * 2);
  bf16* wqkv = (bf16*)alloc((size_t)3 * H * H * 2);
  float* bqkv = (float*)alloc((size_t)3 * H * 4);
  bf16* wob = (bf16*)alloc((size_t)H * H * 2);
  bf16* spwb = (bf16*)alloc((size_t)I * H * 2);
  bf16* sainb = (bf16*)alloc((size_t)(3 * I) * I * 2);
  bf16* saoutb = (bf16*)alloc((size_t)I * I * 2);
  bf16* w1pack = (bf16*)alloc((size_t)384 * 256 * 2);
  float* b1pack = (float*)alloc((size_t)384 * 4);
  float* maskBias = (float*)alloc((size_t)M * 4);
  float* biasMain = (float*)alloc((size_t)M * 4);

  const int SPM = 4, SPS = 8;
  size_t offMark = off;
  // phase A (scorer)
  bf16* h0 = (bf16*)alloc((size_t)M * I * 2);
  bf16* qkv_s = (bf16*)alloc((size_t)M * (3 * I) * 2);
  bf16* vt_s = (bf16*)alloc((size_t)B * SNH * 64 * S * 2);
  bf16* attn_s = (bf16*)alloc((size_t)M * I * 2);
  bf16* h1 = (bf16*)alloc((size_t)M * I * 2);
  bf16* hid = (bf16*)alloc((size_t)M * 384 * 2);
  float* Opart_s = (float*)alloc((size_t)SPS * B * SNH * S * 64 * 4);
  float2* ML_s = (float2*)alloc((size_t)SPS * B * SNH * S * 8);
  size_t endA = off;
  // phase B (main) overlays phase A
  off = offMark;
  bf16* QKVm = (bf16*)alloc((size_t)M * 3 * H * 2);
  bf16* vt_m = (bf16*)alloc((size_t)B * NH * 64 * S * 2);
  bf16* attn_m = (bf16*)alloc((size_t)M * H * 2);
  float* Opart_m = (float*)alloc((size_t)SPM * B * NH * S * 64 * 4);
  float2* ML_m = (float2*)alloc((size_t)SPM * B * NH * S * 8);
  size_t endB = off;
  size_t need = endA > endB ? endA : endB;
  bool split_ok = ws_size >= need;
  (void)in_sizes; (void)n_in; (void)out_size;

  pack_all<<<5926, 256, 0, stream>>>(x, qw, kw, vw, ow, sp_w, sa_in_w, sa_out_w, nw1, mw1, dw1,
                                     qb, kb, vb, nb1, mb1, db1, mask,
                                     xb, wqkv, wob, spwb, sainb, saoutb, w1pack, bqkv, b1pack,
                                     maskBias);

  // ---- scorer branch ----
  gemm_nt<0, 0><<<(M / 64) * (I / 64), 256, 0, stream>>>(xb, H, spwb, H, sp_b, h0, I, I / 64, H);
  gemm_nt<0, 0><<<(M / 64) * ((3 * I) / 64), 256, 0, stream>>>(h0, I, sainb, I, sa_in_b, qkv_s,
                                                               3 * I, (3 * I) / 64, I);
  vtrans<<<B * SNH * (S / 64), 256, 0, stream>>>(qkv_s, 3 * I, 2 * I, vt_s, SNH, S);
  if (split_ok) {
    flash4_k<SPS, 1><<<SPS * B * SNH * (S / 128), 256, 0, stream>>>(
        qkv_s, qkv_s + I, 3 * I, vt_s, maskBias, nullptr, 0, Opart_s, ML_s, SNH, S, 0.125f, B);
    flash_comb<<<(B * SNH * S * 16) / 256, 256, 0, stream>>>(Opart_s, ML_s, attn_s, I, SNH, S,
                                                             B, SPS);
  } else {
    flash4_k<1, 0><<<B * SNH * (S / 128), 256, 0, stream>>>(
        qkv_s, qkv_s + I, 3 * I, vt_s, maskBias, attn_s, I, nullptr, nullptr, SNH, S, 0.125f, B);
  }
  gemm_nt<0, 0><<<(M / 64) * (I / 64), 256, 0, stream>>>(attn_s, I, saoutb, I, sa_out_b, h1, I,
                                                         I / 64, I);
  gemm_nt<0, 1><<<(M / 64) * (384 / 64), 256, 0, stream>>>(h1, I, w1pack, I, b1pack, hid, 384,
                                                           384 / 64, I);
  surv_k<<<M / 4, 256, 0, stream>>>(hid, nw2, nb2, mw2, mb2, dw2, db2, maskBias, biasMain);

  // ---- main branch ----
  gemm_nt128<<<(M / 128) * (3 * H / 128), 256, 0, stream>>>(xb, H, wqkv, H, bqkv, QKVm, 3 * H,
                                                            3 * H / 128, H);
  vtrans<<<B * NH * (S / 64), 256, 0, stream>>>(QKVm, 3 * H, 2 * H, vt_m, NH, S);
  if (split_ok) {
    flash4_k<SPM, 1><<<SPM * B * NH * (S / 128), 256, 0, stream>>>(
        QKVm, QKVm + H, 3 * H, vt_m, biasMain, nullptr, 0, Opart_m, ML_m, NH, S, 0.125f, B);
    flash_comb<<<(B * NH * S * 16) / 256, 256, 0, stream>>>(Opart_m, ML_m, attn_m, H, NH, S, B,
                                                            SPM);
  } else {
    flash4_k<1, 0><<<B * NH * (S / 128), 256, 0, stream>>>(
        QKVm, QKVm + H, 3 * H, vt_m, biasMain, attn_m, H, nullptr, nullptr, NH, S, 0.125f, B);
  }
  gemm_nt<1, 0><<<(M / 64) * (H / 64), 256, 0, stream>>>(attn_m, H, wob, H, ob, d_out, H,
                                                         H / 64, H);
}

// Round 6
// 273.862 us; speedup vs baseline: 1.8822x; 1.2360x over previous
//
#include <hip/hip_runtime.h>
#include <math.h>

typedef __bf16 bf16;
typedef __bf16 bfrag __attribute__((ext_vector_type(8)));
typedef __bf16 bf4 __attribute__((ext_vector_type(4)));
typedef float f4 __attribute__((ext_vector_type(4)));
typedef float f16v __attribute__((ext_vector_type(16)));

#define DEV static __device__ __forceinline__

DEV f4 MFMA(bfrag a, bfrag b, f4 c) {
  return __builtin_amdgcn_mfma_f32_16x16x32_bf16(a, b, c, 0, 0, 0);
}
DEV f16v MFMA32(bfrag a, bfrag b, f16v c) {
  return __builtin_amdgcn_mfma_f32_32x32x16_bf16(a, b, c, 0, 0, 0);
}
DEV unsigned pkbf(float a, float b) {
  bf16 ha = (bf16)a, hb = (bf16)b;
  unsigned short ua = __builtin_bit_cast(unsigned short, ha);
  unsigned short ub = __builtin_bit_cast(unsigned short, hb);
  return (unsigned)ua | ((unsigned)ub << 16);
}

// ---------------- fused setup: all fp32->bf16 converts + bias packs + maskbias ----------------
__global__ __launch_bounds__(256) void pack_all(
    const float* __restrict__ x, const float* __restrict__ qw, const float* __restrict__ kw,
    const float* __restrict__ vw, const float* __restrict__ ow, const float* __restrict__ sp_w,
    const float* __restrict__ sa_in_w, const float* __restrict__ sa_out_w,
    const float* __restrict__ nw1, const float* __restrict__ mw1, const float* __restrict__ dw1,
    const float* __restrict__ qb, const float* __restrict__ kb, const float* __restrict__ vb,
    const float* __restrict__ nb1, const float* __restrict__ mb1, const float* __restrict__ db1,
    const int* __restrict__ mask,
    bf16* __restrict__ xb, bf16* __restrict__ wqkv, bf16* __restrict__ wob,
    bf16* __restrict__ spwb, bf16* __restrict__ sainb, bf16* __restrict__ saoutb,
    bf16* __restrict__ w1pack, float* __restrict__ bqkv, float* __restrict__ b1pack,
    float* __restrict__ maskBias) {
  int bid = blockIdx.x;
  int tid = threadIdx.x;
  const float* src = nullptr;
  bf16* dst = nullptr;
  int rel = 0;
  if (bid < 3072)      { src = x;       dst = xb;                   rel = bid; }
  else if (bid < 3648) { src = qw;      dst = wqkv;                 rel = bid - 3072; }
  else if (bid < 4224) { src = kw;      dst = wqkv + 589824;        rel = bid - 3648; }
  else if (bid < 4800) { src = vw;      dst = wqkv + 2 * 589824;    rel = bid - 4224; }
  else if (bid < 5376) { src = ow;      dst = wob;                  rel = bid - 4800; }
  else if (bid < 5568) { src = sp_w;    dst = spwb;                 rel = bid - 5376; }
  else if (bid < 5760) { src = sa_in_w; dst = sainb;                rel = bid - 5568; }
  else if (bid < 5824) { src = sa_out_w;dst = saoutb;               rel = bid - 5760; }
  else if (bid < 5856) { src = nw1;     dst = w1pack;               rel = bid - 5824; }
  else if (bid < 5888) { src = mw1;     dst = w1pack + 32768;       rel = bid - 5856; }
  else if (bid < 5920) { src = dw1;     dst = w1pack + 2 * 32768;   rel = bid - 5888; }
  else if (bid == 5920) {
    if (tid < 576) {
      int which = tid / 192, j = tid % 192;
      const float* s = which == 0 ? qb : (which == 1 ? kb : vb);
      reinterpret_cast<float4*>(bqkv)[tid] = reinterpret_cast<const float4*>(s)[j];
    }
    return;
  } else if (bid == 5921) {
    if (tid < 96) {
      int which = tid / 32, j = tid % 32;
      const float* s = which == 0 ? nb1 : (which == 1 ? mb1 : db1);
      reinterpret_cast<float4*>(b1pack)[tid] = reinterpret_cast<const float4*>(s)[j];
    }
    return;
  } else {
    int idx = (bid - 5922) * 256 + tid;
    int4 m = reinterpret_cast<const int4*>(mask)[idx];
    float4 o;
    o.x = m.x > 0 ? 0.f : -1e9f;
    o.y = m.y > 0 ? 0.f : -1e9f;
    o.z = m.z > 0 ? 0.f : -1e9f;
    o.w = m.w > 0 ? 0.f : -1e9f;
    reinterpret_cast<float4*>(maskBias)[idx] = o;
    return;
  }
  int i = rel * 256 + tid;
  float4 v = reinterpret_cast<const float4*>(src)[i];
  bf4 o;
  o[0] = (bf16)v.x; o[1] = (bf16)v.y; o[2] = (bf16)v.z; o[3] = (bf16)v.w;
  reinterpret_cast<bf4*>(dst)[i] = o;
}

// ---------------- GEMM 64x64 tile: C[M,N] = act(A[M,K] @ W[N,K]^T + bias) ----------------
template<int OUTF32, int RELU>
__global__ __launch_bounds__(256) void gemm_nt(
    const bf16* __restrict__ A, int lda,
    const bf16* __restrict__ W, int ldw,
    const float* __restrict__ bias,
    void* __restrict__ C, int ldc,
    int N64, int K) {
  int lane = threadIdx.x & 63;
  int w = threadIdx.x >> 6;
  int lrow = lane & 15, lgrp = lane >> 4;
  int tn = blockIdx.x % N64, tm = blockIdx.x / N64;
  int m0 = tm * 64 + (w >> 1) * 32;
  int n0 = tn * 64 + (w & 1) * 32;
  const bf16* Ab = A + (size_t)m0 * lda + lgrp * 8;
  const bf16* Wb = W + (size_t)n0 * ldw + lgrp * 8;
  f4 acc[2][2] = {};
  for (int k0 = 0; k0 < K; k0 += 32) {
    bfrag a0 = *(const bfrag*)(Ab + (size_t)lrow * lda + k0);
    bfrag a1 = *(const bfrag*)(Ab + (size_t)(lrow + 16) * lda + k0);
    bfrag b0 = *(const bfrag*)(Wb + (size_t)lrow * ldw + k0);
    bfrag b1 = *(const bfrag*)(Wb + (size_t)(lrow + 16) * ldw + k0);
    acc[0][0] = MFMA(a0, b0, acc[0][0]);
    acc[0][1] = MFMA(a0, b1, acc[0][1]);
    acc[1][0] = MFMA(a1, b0, acc[1][0]);
    acc[1][1] = MFMA(a1, b1, acc[1][1]);
  }
#pragma unroll
  for (int mi = 0; mi < 2; mi++)
#pragma unroll
    for (int nj = 0; nj < 2; nj++) {
      int col = n0 + nj * 16 + lrow;
      float bv = bias[col];
      int rowb = m0 + mi * 16 + lgrp * 4;
#pragma unroll
      for (int i = 0; i < 4; i++) {
        float v = acc[mi][nj][i] + bv;
        if (RELU) v = fmaxf(v, 0.f);
        if (OUTF32)
          ((float*)C)[(size_t)(rowb + i) * ldc + col] = v;
        else
          ((bf16*)C)[(size_t)(rowb + i) * ldc + col] = (bf16)v;
      }
    }
}

// ---------------- GEMM 128x128 tile (for the big QKV projection) ----------------
__global__ __launch_bounds__(256) void gemm_nt128(
    const bf16* __restrict__ A, int lda,
    const bf16* __restrict__ W, int ldw,
    const float* __restrict__ bias,
    bf16* __restrict__ C, int ldc,
    int N128, int K) {
  int lane = threadIdx.x & 63;
  int w = threadIdx.x >> 6;
  int lrow = lane & 15, lgrp = lane >> 4;
  int tn = blockIdx.x % N128, tm = blockIdx.x / N128;
  int m0 = tm * 128 + (w >> 1) * 64;
  int n0 = tn * 128 + (w & 1) * 64;
  const bf16* Ab = A + (size_t)m0 * lda + lgrp * 8;
  const bf16* Wb = W + (size_t)n0 * ldw + lgrp * 8;
  f4 acc[4][4] = {};
  for (int k0 = 0; k0 < K; k0 += 32) {
    bfrag a[4], bb[4];
#pragma unroll
    for (int i = 0; i < 4; i++) {
      a[i] = *(const bfrag*)(Ab + (size_t)(lrow + 16 * i) * lda + k0);
      bb[i] = *(const bfrag*)(Wb + (size_t)(lrow + 16 * i) * ldw + k0);
    }
#pragma unroll
    for (int mi = 0; mi < 4; mi++)
#pragma unroll
      for (int nj = 0; nj < 4; nj++)
        acc[mi][nj] = MFMA(a[mi], bb[nj], acc[mi][nj]);
  }
#pragma unroll
  for (int mi = 0; mi < 4; mi++)
#pragma unroll
    for (int nj = 0; nj < 4; nj++) {
      int col = n0 + nj * 16 + lrow;
      float bv = bias[col];
      int rowb = m0 + mi * 16 + lgrp * 4;
#pragma unroll
      for (int i = 0; i < 4; i++)
        C[(size_t)(rowb + i) * ldc + col] = (bf16)(acc[mi][nj][i] + bv);
    }
}

// ---------------- V transpose: Vt[b][h][d][s] = V[b][s][coff + h*64 + d] ----------------
__global__ __launch_bounds__(256) void vtrans(const bf16* __restrict__ V, int rs, int coff,
                                              bf16* __restrict__ Vt, int H, int S) {
  int nst = S / 64;
  int st = blockIdx.x % nst;
  int h = (blockIdx.x / nst) % H;
  int b = blockIdx.x / (nst * H);
  __shared__ bf16 tile[64][72];
  int t = threadIdx.x;
  int r = t >> 2, c = t & 3;
  const bf16* src = V + ((size_t)b * S + st * 64 + r) * rs + coff + h * 64 + c * 16;
  bfrag v0 = *(const bfrag*)(src);
  bfrag v1 = *(const bfrag*)(src + 8);
  *(bfrag*)&tile[r][c * 16] = v0;
  *(bfrag*)&tile[r][c * 16 + 8] = v1;
  __syncthreads();
  bf16* dst = Vt + (((size_t)b * H + h) * 64 + r) * S + st * 64 + c * 16;
  bfrag o0, o1;
#pragma unroll
  for (int j = 0; j < 8; j++) {
    o0[j] = tile[c * 16 + j][r];
    o1[j] = tile[c * 16 + 8 + j][r];
  }
  *(bfrag*)dst = o0;
  *(bfrag*)(dst + 8) = o1;
}

// ---------------- flash attention v5: LDS-staged K/V, 32x32 MFMA, 64-key tiles ----------------
// Block = 4 waves, 128 queries; all waves share one (b,h). Per 64-key tile the block
// cooperatively stages K[64][64] and Vt[64][64] into XOR-swizzled LDS (coalesced
// global reads), 2-phase pipelined (stage t+1 issued before compute t, 1 barrier/tile).
// QK^T as mfma32(K,Q): q = lane&31 lane-local softmax; PV via in-register P frags.
template<int SPLIT, int PARTIAL>
__global__ __launch_bounds__(256) void flash5_k(
    const bf16* __restrict__ Q, const bf16* __restrict__ Kp, int rs,
    const bf16* __restrict__ Vt, const float* __restrict__ bias,
    bf16* __restrict__ O, int ors,
    float* __restrict__ Opart, float2* __restrict__ MLpart,
    int H, int S, float scale, int Bc) {
  int nqt = S / 128;
  int bid = blockIdx.x;
  int qt = bid % nqt;
  int hh = (bid / nqt) % H;
  int b = (bid / (nqt * H)) % Bc;
  int sp = bid / (nqt * H * Bc);
  int lane = threadIdx.x & 63, w = threadIdx.x >> 6;
  int l31 = lane & 31, hf = lane >> 5;
  int q0 = qt * 128 + w * 32;
  const int kchunk = S / SPLIT;
  int k_beg = sp * kchunk;
  int swzl = (l31 & 7) << 4;

  // Q B-operand frags: col=q=l31, k(d-dim) = 16c + 8*hf + i
  const bf16* Qb = Q + ((size_t)b * S + q0 + l31) * rs + hh * 64 + hf * 8;
  bfrag qf[4];
#pragma unroll
  for (int c = 0; c < 4; c++) qf[c] = *(const bfrag*)(Qb + 16 * c);

  const bf16* gK0 = Kp + ((size_t)b * S + k_beg) * rs + hh * 64;
  const bf16* gV0 = Vt + (((size_t)b * H + hh) * 64) * (size_t)S + k_beg;
  const float* biasb = bias + (size_t)b * S;

  __shared__ bf16 KT[2][4096];
  __shared__ bf16 VT[2][4096];

  f16v acc0, acc1;
#pragma unroll
  for (int r = 0; r < 16; r++) { acc0[r] = 0.f; acc1[r] = 0.f; }
  float mrun = -3.0e38f, lrun = 0.f;

  // staging lane geometry: idx = (w*2+j)*64+lane; row=idx>>3 (key or d), c16=idx&7 (16B slot)
  int sidx0 = (w * 2) * 64 + lane;
  int sidx1 = (w * 2 + 1) * 64 + lane;
  int srow0 = sidx0 >> 3, sc0 = sidx0 & 7;
  int srow1 = sidx1 >> 3, sc1 = sidx1 & 7;
  int soff0 = srow0 * 128 + ((sc0 * 16) ^ ((srow0 & 7) << 4));
  int soff1 = srow1 * 128 + ((sc1 * 16) ^ ((srow1 & 7) << 4));

  bfrag kr0, kr1, vr0, vr1;
  // prologue stage tile 0
  kr0 = *(const bfrag*)(gK0 + (size_t)srow0 * rs + sc0 * 8);
  kr1 = *(const bfrag*)(gK0 + (size_t)srow1 * rs + sc1 * 8);
  vr0 = *(const bfrag*)(gV0 + (size_t)srow0 * S + sc0 * 8);
  vr1 = *(const bfrag*)(gV0 + (size_t)srow1 * S + sc1 * 8);
  *(bfrag*)((char*)KT[0] + soff0) = kr0;
  *(bfrag*)((char*)KT[0] + soff1) = kr1;
  *(bfrag*)((char*)VT[0] + soff0) = vr0;
  *(bfrag*)((char*)VT[0] + soff1) = vr1;
  __syncthreads();

  const int nt = kchunk / 64;
  for (int t = 0; t < nt; t++) {
    int kt = k_beg + t * 64;
    // issue next-tile global loads (land under compute)
    if (t + 1 < nt) {
      const bf16* gK = gK0 + (size_t)(t + 1) * 64 * rs;
      const bf16* gV = gV0 + (t + 1) * 64;
      kr0 = *(const bfrag*)(gK + (size_t)srow0 * rs + sc0 * 8);
      kr1 = *(const bfrag*)(gK + (size_t)srow1 * rs + sc1 * 8);
      vr0 = *(const bfrag*)(gV + (size_t)srow0 * S + sc0 * 8);
      vr1 = *(const bfrag*)(gV + (size_t)srow1 * S + sc1 * 8);
    }

    const char* KTb = (const char*)KT[t & 1];
    const char* VTb = (const char*)VT[t & 1];

    // ---- QK^T: keys kt+0..31 (rows l31) and kt+32..63 (rows 32+l31) ----
    f16v s_lo, s_hi;
#pragma unroll
    for (int r = 0; r < 16; r++) { s_lo[r] = 0.f; s_hi[r] = 0.f; }
#pragma unroll
    for (int c = 0; c < 4; c++) {
      int colb = 32 * c + 16 * hf;
      bfrag klo = *(const bfrag*)(KTb + l31 * 128 + (colb ^ swzl));
      bfrag khi = *(const bfrag*)(KTb + (32 + l31) * 128 + (colb ^ swzl));
      s_lo = MFMA32(klo, qf[c], s_lo);
      s_hi = MFMA32(khi, qf[c], s_hi);
    }

    // ---- bias: key = kt + (r&3) + 8*(r>>2) + 4*hf (+32 for hi) ----
    f4 blo[4], bhi[4];
#pragma unroll
    for (int g = 0; g < 4; g++) {
      blo[g] = *(const f4*)(biasb + kt + g * 8 + hf * 4);
      bhi[g] = *(const f4*)(biasb + kt + 32 + g * 8 + hf * 4);
    }
#pragma unroll
    for (int r = 0; r < 16; r++) {
      s_lo[r] = s_lo[r] * scale + blo[r >> 2][r & 3];
      s_hi[r] = s_hi[r] * scale + bhi[r >> 2][r & 3];
    }

    // ---- softmax over 32 local scores + partner half ----
    float mx = fmaxf(s_lo[0], s_hi[0]);
#pragma unroll
    for (int r = 1; r < 16; r++) mx = fmaxf(mx, fmaxf(s_lo[r], s_hi[r]));
    mx = fmaxf(mx, __shfl_xor(mx, 32));
    if (!__all(mx <= mrun + 8.f)) {
      float mn = fmaxf(mrun, mx);
      float sc0f = __expf(mrun - mn);
      mrun = mn;
      lrun *= sc0f;
#pragma unroll
      for (int r = 0; r < 16; r++) { acc0[r] *= sc0f; acc1[r] *= sc0f; }
    }
#pragma unroll
    for (int r = 0; r < 16; r++) {
      s_lo[r] = __expf(s_lo[r] - mrun);
      s_hi[r] = __expf(s_hi[r] - mrun);
    }
    float rsum = s_lo[0] + s_hi[0];
#pragma unroll
    for (int r = 1; r < 16; r++) rsum += s_lo[r] + s_hi[r];
    rsum += __shfl_xor(rsum, 32);
    lrun += rsum;

    // ---- build P B-operand frags (4 chains of 16 keys), verified flash4 mapping ----
    bfrag pb[4];
#pragma unroll
    for (int cc = 0; cc < 4; cc++) {
      const f16v& sv = (cc < 2) ? s_lo : s_hi;
      int rb = (cc & 1) * 8;
      unsigned lo0 = pkbf(sv[rb + 0], sv[rb + 1]);
      unsigned lo1 = pkbf(sv[rb + 2], sv[rb + 3]);
      unsigned hi0 = pkbf(sv[rb + 4], sv[rb + 5]);
      unsigned hi1 = pkbf(sv[rb + 6], sv[rb + 7]);
      unsigned t0 = hf ? lo0 : hi0;
      unsigned t1 = hf ? lo1 : hi1;
      unsigned r0 = (unsigned)__shfl_xor((int)t0, 32);
      unsigned r1 = (unsigned)__shfl_xor((int)t1, 32);
      union { bfrag v; unsigned u[4]; } pu;
      pu.u[0] = hf ? r0 : lo0;
      pu.u[1] = hf ? r1 : lo1;
      pu.u[2] = hf ? hi0 : r0;
      pu.u[3] = hf ? hi1 : r1;
      pb[cc] = pu.v;
    }

    // ---- PV: A = Vt d-rows (l31, 32+l31), k-chains = key slices ----
#pragma unroll
    for (int c = 0; c < 4; c++) {
      int colb = 32 * c + 16 * hf;
      bfrag v0 = *(const bfrag*)(VTb + l31 * 128 + (colb ^ swzl));
      bfrag v1 = *(const bfrag*)(VTb + (32 + l31) * 128 + (colb ^ swzl));
      acc0 = MFMA32(v0, pb[c], acc0);
      acc1 = MFMA32(v1, pb[c], acc1);
    }

    // write next tile to the other LDS buffer, then one barrier
    if (t + 1 < nt) {
      char* KTn = (char*)KT[(t + 1) & 1];
      char* VTn = (char*)VT[(t + 1) & 1];
      *(bfrag*)(KTn + soff0) = kr0;
      *(bfrag*)(KTn + soff1) = kr1;
      *(bfrag*)(VTn + soff0) = vr0;
      *(bfrag*)(VTn + soff1) = vr1;
    }
    __syncthreads();
  }

  int q = q0 + l31;
  if (PARTIAL) {
    float* op = Opart + ((((size_t)sp * Bc + b) * H + hh) * S + q) * 64 + hf * 4;
#pragma unroll
    for (int g = 0; g < 4; g++) {
      f4 v0, v1;
#pragma unroll
      for (int i = 0; i < 4; i++) { v0[i] = acc0[4 * g + i]; v1[i] = acc1[4 * g + i]; }
      *(f4*)(op + g * 8) = v0;
      *(f4*)(op + 32 + g * 8) = v1;
    }
    if (hf == 0) {
      float2 ml; ml.x = mrun; ml.y = lrun;
      MLpart[(((size_t)sp * Bc + b) * H + hh) * S + q] = ml;
    }
  } else {
    float inv = 1.f / lrun;
    bf16* Ob = O + ((size_t)b * S + q) * ors + hh * 64 + hf * 4;
#pragma unroll
    for (int g = 0; g < 4; g++) {
      bf4 o0, o1;
#pragma unroll
      for (int i = 0; i < 4; i++) {
        o0[i] = (bf16)(acc0[4 * g + i] * inv);
        o1[i] = (bf16)(acc1[4 * g + i] * inv);
      }
      *(bf4*)(Ob + g * 8) = o0;
      *(bf4*)(Ob + 32 + g * 8) = o1;
    }
  }
}

// ---------------- combine split-K flash partials ----------------
__global__ __launch_bounds__(256) void flash_comb(
    const float* __restrict__ Opart, const float2* __restrict__ ML,
    bf16* __restrict__ O, int ors, int Hh, int S, int Bc, int nsplit) {
  int idx = blockIdx.x * 256 + threadIdx.x;
  int d4 = idx & 15;
  int q = (idx >> 4) % S;
  int hh = ((idx >> 4) / S) % Hh;
  int b = (idx >> 4) / (S * Hh);
  size_t rowstride = (size_t)Bc * Hh * S;
  size_t rbase = ((size_t)b * Hh + hh) * S + q;
  float m = -3.0e38f;
  for (int sp = 0; sp < nsplit; sp++) m = fmaxf(m, ML[sp * rowstride + rbase].x);
  float lsum = 0.f;
  f4 o = {0.f, 0.f, 0.f, 0.f};
  for (int sp = 0; sp < nsplit; sp++) {
    float2 ml = ML[sp * rowstride + rbase];
    float wgt = __expf(ml.x - m);
    lsum += ml.y * wgt;
    f4 a = *(const f4*)(Opart + (sp * rowstride + rbase) * 64 + d4 * 4);
#pragma unroll
    for (int i = 0; i < 4; i++) o[i] += a[i] * wgt;
  }
  float inv = 1.f / lsum;
  bf4 obv;
#pragma unroll
  for (int i = 0; i < 4; i++) obv[i] = (bf16)(o[i] * inv);
  *(bf4*)(O + ((size_t)b * S + q) * ors + hh * 64 + d4 * 4) = obv;
}

// ---------------- survival epilogue ----------------
__global__ __launch_bounds__(256) void surv_k(
    const bf16* __restrict__ hid,
    const float* __restrict__ nw2, const float* __restrict__ nb2,
    const float* __restrict__ mw2, const float* __restrict__ mb2,
    const float* __restrict__ dw2, const float* __restrict__ db2,
    const float* __restrict__ maskBias, float* __restrict__ biasMain) {
  int w = threadIdx.x >> 6, lane = threadIdx.x & 63;
  int row = blockIdx.x * 4 + w;
  const bf16* hr = hid + (size_t)row * 384;
  const float* W2[3] = {nw2, mw2, dw2};
  float outs[3];
#pragma unroll
  for (int t = 0; t < 3; t++) {
    float acc = (float)hr[t * 128 + lane] * W2[t][lane] +
                (float)hr[t * 128 + 64 + lane] * W2[t][64 + lane];
    for (int msk = 1; msk < 64; msk <<= 1) acc += __shfl_xor(acc, msk);
    outs[t] = acc;
  }
  if (lane == 0) {
    float xn = outs[0] + nb2[0];
    float n = (xn > 20.f) ? xn : log1pf(__expf(xn));
    float mu = 1.f / (1.f + __expf(-(outs[1] + mb2[0])));
    float delta = fmaxf(outs[2] + db2[0], 0.f);
    float surv = logf(n + 1e-8f) + logf(mu + 1e-8f) - delta;
    biasMain[row] = 0.1f * surv + maskBias[row];
  }
}

extern "C" void kernel_launch(void* const* d_in, const int* in_sizes, int n_in,
                              void* d_out, int out_size, void* d_ws, size_t ws_size,
                              hipStream_t stream) {
  const int B = 2, S = 2048, H = 768, I = 256;
  const int NH = 12, SNH = 4;
  const int M = B * S;  // 4096

  const float* x = (const float*)d_in[0];
  const int* mask = (const int*)d_in[1];
  const float* qw = (const float*)d_in[2];
  const float* qb = (const float*)d_in[3];
  const float* kw = (const float*)d_in[4];
  const float* kb = (const float*)d_in[5];
  const float* vw = (const float*)d_in[6];
  const float* vb = (const float*)d_in[7];
  const float* ow = (const float*)d_in[8];
  const float* ob = (const float*)d_in[9];
  const float* sp_w = (const float*)d_in[10];
  const float* sp_b = (const float*)d_in[11];
  const float* sa_in_w = (const float*)d_in[12];
  const float* sa_in_b = (const float*)d_in[13];
  const float* sa_out_w = (const float*)d_in[14];
  const float* sa_out_b = (const float*)d_in[15];
  const float* nw1 = (const float*)d_in[16];
  const float* nb1 = (const float*)d_in[17];
  const float* nw2 = (const float*)d_in[18];
  const float* nb2 = (const float*)d_in[19];
  const float* mw1 = (const float*)d_in[20];
  const float* mb1 = (const float*)d_in[21];
  const float* mw2 = (const float*)d_in[22];
  const float* mb2 = (const float*)d_in[23];
  const float* dw1 = (const float*)d_in[24];
  const float* db1 = (const float*)d_in[25];
  const float* dw2 = (const float*)d_in[26];
  const float* db2 = (const float*)d_in[27];

  char* ws = (char*)d_ws;
  size_t off = 0;
  auto alloc = [&](size_t bytes) -> void* {
    void* p = ws + off;
    off += (bytes + 255) & ~(size_t)255;
    return p;
  };

  // persistent
  bf16* xb = (bf16*)alloc((size_t)M * H * 2);
  bf16* wqkv = (bf16*)alloc((size_t)3 * H * H * 2);
  float* bqkv = (float*)alloc((size_t)3 * H * 4);
  bf16* wob = (bf16*)alloc((size_t)H * H * 2);
  bf16* spwb = (bf16*)alloc((size_t)I * H * 2);
  bf16* sainb = (bf16*)alloc((size_t)(3 * I) * I * 2);
  bf16* saoutb = (bf16*)alloc((size_t)I * I * 2);
  bf16* w1pack = (bf16*)alloc((size_t)384 * 256 * 2);
  float* b1pack = (float*)alloc((size_t)384 * 4);
  float* maskBias = (float*)alloc((size_t)M * 4);
  float* biasMain = (float*)alloc((size_t)M * 4);

  const int SPM = 4, SPS = 8;
  size_t offMark = off;
  // phase A (scorer)
  bf16* h0 = (bf16*)alloc((size_t)M * I * 2);
  bf16* qkv_s = (bf16*)alloc((size_t)M * (3 * I) * 2);
  bf16* vt_s = (bf16*)alloc((size_t)B * SNH * 64 * S * 2);
  bf16* attn_s = (bf16*)alloc((size_t)M * I * 2);
  bf16* h1 = (bf16*)alloc((size_t)M * I * 2);
  bf16* hid = (bf16*)alloc((size_t)M * 384 * 2);
  float* Opart_s = (float*)alloc((size_t)SPS * B * SNH * S * 64 * 4);
  float2* ML_s = (float2*)alloc((size_t)SPS * B * SNH * S * 8);
  size_t endA = off;
  // phase B (main) overlays phase A
  off = offMark;
  bf16* QKVm = (bf16*)alloc((size_t)M * 3 * H * 2);
  bf16* vt_m = (bf16*)alloc((size_t)B * NH * 64 * S * 2);
  bf16* attn_m = (bf16*)alloc((size_t)M * H * 2);
  float* Opart_m = (float*)alloc((size_t)SPM * B * NH * S * 64 * 4);
  float2* ML_m = (float2*)alloc((size_t)SPM * B * NH * S * 8);
  size_t endB = off;
  size_t need = endA > endB ? endA : endB;
  bool split_ok = ws_size >= need;
  (void)in_sizes; (void)n_in; (void)out_size;

  pack_all<<<5926, 256, 0, stream>>>(x, qw, kw, vw, ow, sp_w, sa_in_w, sa_out_w, nw1, mw1, dw1,
                                     qb, kb, vb, nb1, mb1, db1, mask,
                                     xb, wqkv, wob, spwb, sainb, saoutb, w1pack, bqkv, b1pack,
                                     maskBias);

  // ---- scorer branch ----
  gemm_nt<0, 0><<<(M / 64) * (I / 64), 256, 0, stream>>>(xb, H, spwb, H, sp_b, h0, I, I / 64, H);
  gemm_nt<0, 0><<<(M / 64) * ((3 * I) / 64), 256, 0, stream>>>(h0, I, sainb, I, sa_in_b, qkv_s,
                                                               3 * I, (3 * I) / 64, I);
  vtrans<<<B * SNH * (S / 64), 256, 0, stream>>>(qkv_s, 3 * I, 2 * I, vt_s, SNH, S);
  if (split_ok) {
    flash5_k<SPS, 1><<<SPS * B * SNH * (S / 128), 256, 0, stream>>>(
        qkv_s, qkv_s + I, 3 * I, vt_s, maskBias, nullptr, 0, Opart_s, ML_s, SNH, S, 0.125f, B);
    flash_comb<<<(B * SNH * S * 16) / 256, 256, 0, stream>>>(Opart_s, ML_s, attn_s, I, SNH, S,
                                                             B, SPS);
  } else {
    flash5_k<1, 0><<<B * SNH * (S / 128), 256, 0, stream>>>(
        qkv_s, qkv_s + I, 3 * I, vt_s, maskBias, attn_s, I, nullptr, nullptr, SNH, S, 0.125f, B);
  }
  gemm_nt<0, 0><<<(M / 64) * (I / 64), 256, 0, stream>>>(attn_s, I, saoutb, I, sa_out_b, h1, I,
                                                         I / 64, I);
  gemm_nt<0, 1><<<(M / 64) * (384 / 64), 256, 0, stream>>>(h1, I, w1pack, I, b1pack, hid, 384,
                                                           384 / 64, I);
  surv_k<<<M / 4, 256, 0, stream>>>(hid, nw2, nb2, mw2, mb2, dw2, db2, maskBias, biasMain);

  // ---- main branch ----
  gemm_nt128<<<(M / 128) * (3 * H / 128), 256, 0, stream>>>(xb, H, wqkv, H, bqkv, QKVm, 3 * H,
                                                            3 * H / 128, H);
  vtrans<<<B * NH * (S / 64), 256, 0, stream>>>(QKVm, 3 * H, 2 * H, vt_m, NH, S);
  if (split_ok) {
    flash5_k<SPM, 1><<<SPM * B * NH * (S / 128), 256, 0, stream>>>(
        QKVm, QKVm + H, 3 * H, vt_m, biasMain, nullptr, 0, Opart_m, ML_m, NH, S, 0.125f, B);
    flash_comb<<<(B * NH * S * 16) / 256, 256, 0, stream>>>(Opart_m, ML_m, attn_m, H, NH, S, B,
                                                            SPM);
  } else {
    flash5_k<1, 0><<<B * NH * (S / 128), 256, 0, stream>>>(
        QKVm, QKVm + H, 3 * H, vt_m, biasMain, attn_m, H, nullptr, nullptr, NH, S, 0.125f, B);
  }
  gemm_nt<1, 0><<<(M / 64) * (H / 64), 256, 0, stream>>>(attn_m, H, wob, H, ob, d_out, H,
                                                         H / 64, H);
}

// Round 7
// 219.994 us; speedup vs baseline: 2.3431x; 1.2449x over previous
//
#include <hip/hip_runtime.h>
#include <math.h>

typedef __bf16 bf16;
typedef __bf16 bfrag __attribute__((ext_vector_type(8)));
typedef __bf16 bf4 __attribute__((ext_vector_type(4)));
typedef float f4 __attribute__((ext_vector_type(4)));
typedef float f16v __attribute__((ext_vector_type(16)));

#define DEV static __device__ __forceinline__

DEV f4 MFMA(bfrag a, bfrag b, f4 c) {
  return __builtin_amdgcn_mfma_f32_16x16x32_bf16(a, b, c, 0, 0, 0);
}
DEV f16v MFMA32(bfrag a, bfrag b, f16v c) {
  return __builtin_amdgcn_mfma_f32_32x32x16_bf16(a, b, c, 0, 0, 0);
}
DEV unsigned pkbf(float a, float b) {
  bf16 ha = (bf16)a, hb = (bf16)b;
  unsigned short ua = __builtin_bit_cast(unsigned short, ha);
  unsigned short ub = __builtin_bit_cast(unsigned short, hb);
  return (unsigned)ua | ((unsigned)ub << 16);
}
DEV void gload_lds16(const bf16* g, bf16* l) {
  __builtin_amdgcn_global_load_lds(
      (const __attribute__((address_space(1))) void*)g,
      (__attribute__((address_space(3))) void*)l, 16, 0, 0);
}

// ---------------- fused setup: all fp32->bf16 converts + bias packs + maskbias ----------------
__global__ __launch_bounds__(256) void pack_all(
    const float* __restrict__ x, const float* __restrict__ qw, const float* __restrict__ kw,
    const float* __restrict__ vw, const float* __restrict__ ow, const float* __restrict__ sp_w,
    const float* __restrict__ sa_in_w, const float* __restrict__ sa_out_w,
    const float* __restrict__ nw1, const float* __restrict__ mw1, const float* __restrict__ dw1,
    const float* __restrict__ qb, const float* __restrict__ kb, const float* __restrict__ vb,
    const float* __restrict__ nb1, const float* __restrict__ mb1, const float* __restrict__ db1,
    const int* __restrict__ mask,
    bf16* __restrict__ xb, bf16* __restrict__ wqkv, bf16* __restrict__ wob,
    bf16* __restrict__ spwb, bf16* __restrict__ sainb, bf16* __restrict__ saoutb,
    bf16* __restrict__ w1pack, float* __restrict__ bqkv, float* __restrict__ b1pack,
    float* __restrict__ maskBias) {
  int bid = blockIdx.x;
  int tid = threadIdx.x;
  const float* src = nullptr;
  bf16* dst = nullptr;
  int rel = 0;
  if (bid < 3072)      { src = x;       dst = xb;                   rel = bid; }
  else if (bid < 3648) { src = qw;      dst = wqkv;                 rel = bid - 3072; }
  else if (bid < 4224) { src = kw;      dst = wqkv + 589824;        rel = bid - 3648; }
  else if (bid < 4800) { src = vw;      dst = wqkv + 2 * 589824;    rel = bid - 4224; }
  else if (bid < 5376) { src = ow;      dst = wob;                  rel = bid - 4800; }
  else if (bid < 5568) { src = sp_w;    dst = spwb;                 rel = bid - 5376; }
  else if (bid < 5760) { src = sa_in_w; dst = sainb;                rel = bid - 5568; }
  else if (bid < 5824) { src = sa_out_w;dst = saoutb;               rel = bid - 5760; }
  else if (bid < 5856) { src = nw1;     dst = w1pack;               rel = bid - 5824; }
  else if (bid < 5888) { src = mw1;     dst = w1pack + 32768;       rel = bid - 5856; }
  else if (bid < 5920) { src = dw1;     dst = w1pack + 2 * 32768;   rel = bid - 5888; }
  else if (bid == 5920) {
    if (tid < 576) {
      int which = tid / 192, j = tid % 192;
      const float* s = which == 0 ? qb : (which == 1 ? kb : vb);
      reinterpret_cast<float4*>(bqkv)[tid] = reinterpret_cast<const float4*>(s)[j];
    }
    return;
  } else if (bid == 5921) {
    if (tid < 96) {
      int which = tid / 32, j = tid % 32;
      const float* s = which == 0 ? nb1 : (which == 1 ? mb1 : db1);
      reinterpret_cast<float4*>(b1pack)[tid] = reinterpret_cast<const float4*>(s)[j];
    }
    return;
  } else {
    int idx = (bid - 5922) * 256 + tid;
    int4 m = reinterpret_cast<const int4*>(mask)[idx];
    float4 o;
    o.x = m.x > 0 ? 0.f : -1e9f;
    o.y = m.y > 0 ? 0.f : -1e9f;
    o.z = m.z > 0 ? 0.f : -1e9f;
    o.w = m.w > 0 ? 0.f : -1e9f;
    reinterpret_cast<float4*>(maskBias)[idx] = o;
    return;
  }
  int i = rel * 256 + tid;
  float4 v = reinterpret_cast<const float4*>(src)[i];
  bf4 o;
  o[0] = (bf16)v.x; o[1] = (bf16)v.y; o[2] = (bf16)v.z; o[3] = (bf16)v.w;
  reinterpret_cast<bf4*>(dst)[i] = o;
}

// ---------------- GEMM 64x64 tile: C[M,N] = act(A[M,K] @ W[N,K]^T + bias) ----------------
template<int OUTF32, int RELU>
__global__ __launch_bounds__(256) void gemm_nt(
    const bf16* __restrict__ A, int lda,
    const bf16* __restrict__ W, int ldw,
    const float* __restrict__ bias,
    void* __restrict__ C, int ldc,
    int N64, int K) {
  int lane = threadIdx.x & 63;
  int w = threadIdx.x >> 6;
  int lrow = lane & 15, lgrp = lane >> 4;
  int tn = blockIdx.x % N64, tm = blockIdx.x / N64;
  int m0 = tm * 64 + (w >> 1) * 32;
  int n0 = tn * 64 + (w & 1) * 32;
  const bf16* Ab = A + (size_t)m0 * lda + lgrp * 8;
  const bf16* Wb = W + (size_t)n0 * ldw + lgrp * 8;
  f4 acc[2][2] = {};
  for (int k0 = 0; k0 < K; k0 += 32) {
    bfrag a0 = *(const bfrag*)(Ab + (size_t)lrow * lda + k0);
    bfrag a1 = *(const bfrag*)(Ab + (size_t)(lrow + 16) * lda + k0);
    bfrag b0 = *(const bfrag*)(Wb + (size_t)lrow * ldw + k0);
    bfrag b1 = *(const bfrag*)(Wb + (size_t)(lrow + 16) * ldw + k0);
    acc[0][0] = MFMA(a0, b0, acc[0][0]);
    acc[0][1] = MFMA(a0, b1, acc[0][1]);
    acc[1][0] = MFMA(a1, b0, acc[1][0]);
    acc[1][1] = MFMA(a1, b1, acc[1][1]);
  }
#pragma unroll
  for (int mi = 0; mi < 2; mi++)
#pragma unroll
    for (int nj = 0; nj < 2; nj++) {
      int col = n0 + nj * 16 + lrow;
      float bv = bias[col];
      int rowb = m0 + mi * 16 + lgrp * 4;
#pragma unroll
      for (int i = 0; i < 4; i++) {
        float v = acc[mi][nj][i] + bv;
        if (RELU) v = fmaxf(v, 0.f);
        if (OUTF32)
          ((float*)C)[(size_t)(rowb + i) * ldc + col] = v;
        else
          ((bf16*)C)[(size_t)(rowb + i) * ldc + col] = (bf16)v;
      }
    }
}

// ---------------- GEMM 128x128 tile, global_load_lds + swizzled LDS, 2-phase dbuf ----------
// A[M,K] row-major (lda=K), W[N,K] row-major (ldw=K). BK=64. LDS 64KB (2 bufs x (A16K+W16K)).
// LDS image: lds[row][s*16B] = G[row][(s^(row&7))*16B]; ds_read applies the same XOR.
template<int OUTF32>
__global__ __launch_bounds__(256, 2) void gemm_big(
    const bf16* __restrict__ A,
    const bf16* __restrict__ W,
    const float* __restrict__ bias,
    void* __restrict__ C, int ldc,
    int N128, int K) {
  __shared__ char smem[65536];
  int lane = threadIdx.x & 63;
  int w = threadIdx.x >> 6;
  int lrow = lane & 15, lgrp = lane >> 4;
  int tn = blockIdx.x % N128, tm = blockIdx.x / N128;
  int m0 = tm * 128, n0 = tn * 128;

  // staging geometry: wave-inst j covers LDS rows (w*4+j)*8..+8 linearly;
  // lane: row += lane>>3, slot = (lane&7) ^ (lane>>3) (pre-swizzled source).
  int srow = lane >> 3;
  int sslot = (lane & 7) ^ srow;

  auto stage = [&](int bufb, int k0) {
#pragma unroll
    for (int j = 0; j < 4; j++) {
      int rb = (w * 4 + j) * 8 + srow;
      gload_lds16(A + (size_t)(m0 + rb) * K + k0 + sslot * 8,
                  (bf16*)(smem + bufb + (w * 4 + j) * 1024));
      gload_lds16(W + (size_t)(n0 + rb) * K + k0 + sslot * 8,
                  (bf16*)(smem + bufb + 16384 + (w * 4 + j) * 1024));
    }
  };

  f4 acc[4][4] = {};
  int swz = (lrow & 7) << 4;
  int mbase = (w >> 1) * 64, nbase = (w & 1) * 64;

  stage(0, 0);
  __syncthreads();
  int buf = 0;
  int nt = K / 64;
  for (int t = 0; t < nt; t++) {
    int nbuf = buf ^ 32768;
    if (t + 1 < nt) stage(nbuf, (t + 1) * 64);
    const char* As = smem + buf;
    const char* Ws = smem + buf + 16384;
#pragma unroll
    for (int kb = 0; kb < 128; kb += 64) {
      bfrag a[4], b[4];
#pragma unroll
      for (int i = 0; i < 4; i++) {
        a[i] = *(const bfrag*)(As + (mbase + i * 16 + lrow) * 128 + ((kb + lgrp * 16) ^ swz));
        b[i] = *(const bfrag*)(Ws + (nbase + i * 16 + lrow) * 128 + ((kb + lgrp * 16) ^ swz));
      }
#pragma unroll
      for (int mi = 0; mi < 4; mi++)
#pragma unroll
        for (int nj = 0; nj < 4; nj++)
          acc[mi][nj] = MFMA(a[mi], b[nj], acc[mi][nj]);
    }
    __syncthreads();
    buf = nbuf;
  }

#pragma unroll
  for (int mi = 0; mi < 4; mi++)
#pragma unroll
    for (int nj = 0; nj < 4; nj++) {
      int col = n0 + nbase + nj * 16 + lrow;
      float bv = bias[col];
      int rowb = m0 + mbase + mi * 16 + lgrp * 4;
#pragma unroll
      for (int i = 0; i < 4; i++) {
        float v = acc[mi][nj][i] + bv;
        if (OUTF32)
          ((float*)C)[(size_t)(rowb + i) * ldc + col] = v;
        else
          ((bf16*)C)[(size_t)(rowb + i) * ldc + col] = (bf16)v;
      }
    }
}

// ---------------- V transpose: Vt[b][h][d][s] = V[b][s][coff + h*64 + d] ----------------
__global__ __launch_bounds__(256) void vtrans(const bf16* __restrict__ V, int rs, int coff,
                                              bf16* __restrict__ Vt, int H, int S) {
  int nst = S / 64;
  int st = blockIdx.x % nst;
  int h = (blockIdx.x / nst) % H;
  int b = blockIdx.x / (nst * H);
  __shared__ bf16 tile[64][72];
  int t = threadIdx.x;
  int r = t >> 2, c = t & 3;
  const bf16* src = V + ((size_t)b * S + st * 64 + r) * rs + coff + h * 64 + c * 16;
  bfrag v0 = *(const bfrag*)(src);
  bfrag v1 = *(const bfrag*)(src + 8);
  *(bfrag*)&tile[r][c * 16] = v0;
  *(bfrag*)&tile[r][c * 16 + 8] = v1;
  __syncthreads();
  bf16* dst = Vt + (((size_t)b * H + h) * 64 + r) * S + st * 64 + c * 16;
  bfrag o0, o1;
#pragma unroll
  for (int j = 0; j < 8; j++) {
    o0[j] = tile[c * 16 + j][r];
    o1[j] = tile[c * 16 + 8 + j][r];
  }
  *(bfrag*)dst = o0;
  *(bfrag*)(dst + 8) = o1;
}

// ---------------- flash attention v5: LDS-staged K/V, 32x32 MFMA, 64-key tiles ----------------
template<int SPLIT, int PARTIAL>
__global__ __launch_bounds__(256) void flash5_k(
    const bf16* __restrict__ Q, const bf16* __restrict__ Kp, int rs,
    const bf16* __restrict__ Vt, const float* __restrict__ bias,
    bf16* __restrict__ O, int ors,
    float* __restrict__ Opart, float2* __restrict__ MLpart,
    int H, int S, float scale, int Bc) {
  int nqt = S / 128;
  int bid = blockIdx.x;
  int qt = bid % nqt;
  int hh = (bid / nqt) % H;
  int b = (bid / (nqt * H)) % Bc;
  int sp = bid / (nqt * H * Bc);
  int lane = threadIdx.x & 63, w = threadIdx.x >> 6;
  int l31 = lane & 31, hf = lane >> 5;
  int q0 = qt * 128 + w * 32;
  const int kchunk = S / SPLIT;
  int k_beg = sp * kchunk;
  int swzl = (l31 & 7) << 4;

  const bf16* Qb = Q + ((size_t)b * S + q0 + l31) * rs + hh * 64 + hf * 8;
  bfrag qf[4];
#pragma unroll
  for (int c = 0; c < 4; c++) qf[c] = *(const bfrag*)(Qb + 16 * c);

  const bf16* gK0 = Kp + ((size_t)b * S + k_beg) * rs + hh * 64;
  const bf16* gV0 = Vt + (((size_t)b * H + hh) * 64) * (size_t)S + k_beg;
  const float* biasb = bias + (size_t)b * S;

  __shared__ bf16 KT[2][4096];
  __shared__ bf16 VT[2][4096];

  f16v acc0, acc1;
#pragma unroll
  for (int r = 0; r < 16; r++) { acc0[r] = 0.f; acc1[r] = 0.f; }
  float mrun = -3.0e38f, lrun = 0.f;

  int sidx0 = (w * 2) * 64 + lane;
  int sidx1 = (w * 2 + 1) * 64 + lane;
  int srow0 = sidx0 >> 3, sc0 = sidx0 & 7;
  int srow1 = sidx1 >> 3, sc1 = sidx1 & 7;
  int soff0 = srow0 * 128 + ((sc0 * 16) ^ ((srow0 & 7) << 4));
  int soff1 = srow1 * 128 + ((sc1 * 16) ^ ((srow1 & 7) << 4));

  bfrag kr0, kr1, vr0, vr1;
  kr0 = *(const bfrag*)(gK0 + (size_t)srow0 * rs + sc0 * 8);
  kr1 = *(const bfrag*)(gK0 + (size_t)srow1 * rs + sc1 * 8);
  vr0 = *(const bfrag*)(gV0 + (size_t)srow0 * S + sc0 * 8);
  vr1 = *(const bfrag*)(gV0 + (size_t)srow1 * S + sc1 * 8);
  *(bfrag*)((char*)KT[0] + soff0) = kr0;
  *(bfrag*)((char*)KT[0] + soff1) = kr1;
  *(bfrag*)((char*)VT[0] + soff0) = vr0;
  *(bfrag*)((char*)VT[0] + soff1) = vr1;
  __syncthreads();

  const int nt = kchunk / 64;
  for (int t = 0; t < nt; t++) {
    int kt = k_beg + t * 64;
    if (t + 1 < nt) {
      const bf16* gK = gK0 + (size_t)(t + 1) * 64 * rs;
      const bf16* gV = gV0 + (t + 1) * 64;
      kr0 = *(const bfrag*)(gK + (size_t)srow0 * rs + sc0 * 8);
      kr1 = *(const bfrag*)(gK + (size_t)srow1 * rs + sc1 * 8);
      vr0 = *(const bfrag*)(gV + (size_t)srow0 * S + sc0 * 8);
      vr1 = *(const bfrag*)(gV + (size_t)srow1 * S + sc1 * 8);
    }

    const char* KTb = (const char*)KT[t & 1];
    const char* VTb = (const char*)VT[t & 1];

    f16v s_lo, s_hi;
#pragma unroll
    for (int r = 0; r < 16; r++) { s_lo[r] = 0.f; s_hi[r] = 0.f; }
#pragma unroll
    for (int c = 0; c < 4; c++) {
      int colb = 32 * c + 16 * hf;
      bfrag klo = *(const bfrag*)(KTb + l31 * 128 + (colb ^ swzl));
      bfrag khi = *(const bfrag*)(KTb + (32 + l31) * 128 + (colb ^ swzl));
      s_lo = MFMA32(klo, qf[c], s_lo);
      s_hi = MFMA32(khi, qf[c], s_hi);
    }

    f4 blo[4], bhi[4];
#pragma unroll
    for (int g = 0; g < 4; g++) {
      blo[g] = *(const f4*)(biasb + kt + g * 8 + hf * 4);
      bhi[g] = *(const f4*)(biasb + kt + 32 + g * 8 + hf * 4);
    }
#pragma unroll
    for (int r = 0; r < 16; r++) {
      s_lo[r] = s_lo[r] * scale + blo[r >> 2][r & 3];
      s_hi[r] = s_hi[r] * scale + bhi[r >> 2][r & 3];
    }

    float mx = fmaxf(s_lo[0], s_hi[0]);
#pragma unroll
    for (int r = 1; r < 16; r++) mx = fmaxf(mx, fmaxf(s_lo[r], s_hi[r]));
    mx = fmaxf(mx, __shfl_xor(mx, 32));
    if (!__all(mx <= mrun + 8.f)) {
      float mn = fmaxf(mrun, mx);
      float sc0f = __expf(mrun - mn);
      mrun = mn;
      lrun *= sc0f;
#pragma unroll
      for (int r = 0; r < 16; r++) { acc0[r] *= sc0f; acc1[r] *= sc0f; }
    }
#pragma unroll
    for (int r = 0; r < 16; r++) {
      s_lo[r] = __expf(s_lo[r] - mrun);
      s_hi[r] = __expf(s_hi[r] - mrun);
    }
    float rsum = s_lo[0] + s_hi[0];
#pragma unroll
    for (int r = 1; r < 16; r++) rsum += s_lo[r] + s_hi[r];
    rsum += __shfl_xor(rsum, 32);
    lrun += rsum;

    bfrag pb[4];
#pragma unroll
    for (int cc = 0; cc < 4; cc++) {
      const f16v& sv = (cc < 2) ? s_lo : s_hi;
      int rb = (cc & 1) * 8;
      unsigned lo0 = pkbf(sv[rb + 0], sv[rb + 1]);
      unsigned lo1 = pkbf(sv[rb + 2], sv[rb + 3]);
      unsigned hi0 = pkbf(sv[rb + 4], sv[rb + 5]);
      unsigned hi1 = pkbf(sv[rb + 6], sv[rb + 7]);
      unsigned t0 = hf ? lo0 : hi0;
      unsigned t1 = hf ? lo1 : hi1;
      unsigned r0 = (unsigned)__shfl_xor((int)t0, 32);
      unsigned r1 = (unsigned)__shfl_xor((int)t1, 32);
      union { bfrag v; unsigned u[4]; } pu;
      pu.u[0] = hf ? r0 : lo0;
      pu.u[1] = hf ? r1 : lo1;
      pu.u[2] = hf ? hi0 : r0;
      pu.u[3] = hf ? hi1 : r1;
      pb[cc] = pu.v;
    }

#pragma unroll
    for (int c = 0; c < 4; c++) {
      int colb = 32 * c + 16 * hf;
      bfrag v0 = *(const bfrag*)(VTb + l31 * 128 + (colb ^ swzl));
      bfrag v1 = *(const bfrag*)(VTb + (32 + l31) * 128 + (colb ^ swzl));
      acc0 = MFMA32(v0, pb[c], acc0);
      acc1 = MFMA32(v1, pb[c], acc1);
    }

    if (t + 1 < nt) {
      char* KTn = (char*)KT[(t + 1) & 1];
      char* VTn = (char*)VT[(t + 1) & 1];
      *(bfrag*)(KTn + soff0) = kr0;
      *(bfrag*)(KTn + soff1) = kr1;
      *(bfrag*)(VTn + soff0) = vr0;
      *(bfrag*)(VTn + soff1) = vr1;
    }
    __syncthreads();
  }

  int q = q0 + l31;
  if (PARTIAL) {
    float* op = Opart + ((((size_t)sp * Bc + b) * H + hh) * S + q) * 64 + hf * 4;
#pragma unroll
    for (int g = 0; g < 4; g++) {
      f4 v0, v1;
#pragma unroll
      for (int i = 0; i < 4; i++) { v0[i] = acc0[4 * g + i]; v1[i] = acc1[4 * g + i]; }
      *(f4*)(op + g * 8) = v0;
      *(f4*)(op + 32 + g * 8) = v1;
    }
    if (hf == 0) {
      float2 ml; ml.x = mrun; ml.y = lrun;
      MLpart[(((size_t)sp * Bc + b) * H + hh) * S + q] = ml;
    }
  } else {
    float inv = 1.f / lrun;
    bf16* Ob = O + ((size_t)b * S + q) * ors + hh * 64 + hf * 4;
#pragma unroll
    for (int g = 0; g < 4; g++) {
      bf4 o0, o1;
#pragma unroll
      for (int i = 0; i < 4; i++) {
        o0[i] = (bf16)(acc0[4 * g + i] * inv);
        o1[i] = (bf16)(acc1[4 * g + i] * inv);
      }
      *(bf4*)(Ob + g * 8) = o0;
      *(bf4*)(Ob + 32 + g * 8) = o1;
    }
  }
}

// ---------------- combine split-K flash partials ----------------
__global__ __launch_bounds__(256) void flash_comb(
    const float* __restrict__ Opart, const float2* __restrict__ ML,
    bf16* __restrict__ O, int ors, int Hh, int S, int Bc, int nsplit) {
  int idx = blockIdx.x * 256 + threadIdx.x;
  int d4 = idx & 15;
  int q = (idx >> 4) % S;
  int hh = ((idx >> 4) / S) % Hh;
  int b = (idx >> 4) / (S * Hh);
  size_t rowstride = (size_t)Bc * Hh * S;
  size_t rbase = ((size_t)b * Hh + hh) * S + q;
  float m = -3.0e38f;
  for (int sp = 0; sp < nsplit; sp++) m = fmaxf(m, ML[sp * rowstride + rbase].x);
  float lsum = 0.f;
  f4 o = {0.f, 0.f, 0.f, 0.f};
  for (int sp = 0; sp < nsplit; sp++) {
    float2 ml = ML[sp * rowstride + rbase];
    float wgt = __expf(ml.x - m);
    lsum += ml.y * wgt;
    f4 a = *(const f4*)(Opart + (sp * rowstride + rbase) * 64 + d4 * 4);
#pragma unroll
    for (int i = 0; i < 4; i++) o[i] += a[i] * wgt;
  }
  float inv = 1.f / lsum;
  bf4 obv;
#pragma unroll
  for (int i = 0; i < 4; i++) obv[i] = (bf16)(o[i] * inv);
  *(bf4*)(O + ((size_t)b * S + q) * ors + hh * 64 + d4 * 4) = obv;
}

// ---------------- survival epilogue ----------------
__global__ __launch_bounds__(256) void surv_k(
    const bf16* __restrict__ hid,
    const float* __restrict__ nw2, const float* __restrict__ nb2,
    const float* __restrict__ mw2, const float* __restrict__ mb2,
    const float* __restrict__ dw2, const float* __restrict__ db2,
    const float* __restrict__ maskBias, float* __restrict__ biasMain) {
  int w = threadIdx.x >> 6, lane = threadIdx.x & 63;
  int row = blockIdx.x * 4 + w;
  const bf16* hr = hid + (size_t)row * 384;
  const float* W2[3] = {nw2, mw2, dw2};
  float outs[3];
#pragma unroll
  for (int t = 0; t < 3; t++) {
    float acc = (float)hr[t * 128 + lane] * W2[t][lane] +
                (float)hr[t * 128 + 64 + lane] * W2[t][64 + lane];
    for (int msk = 1; msk < 64; msk <<= 1) acc += __shfl_xor(acc, msk);
    outs[t] = acc;
  }
  if (lane == 0) {
    float xn = outs[0] + nb2[0];
    float n = (xn > 20.f) ? xn : log1pf(__expf(xn));
    float mu = 1.f / (1.f + __expf(-(outs[1] + mb2[0])));
    float delta = fmaxf(outs[2] + db2[0], 0.f);
    float surv = logf(n + 1e-8f) + logf(mu + 1e-8f) - delta;
    biasMain[row] = 0.1f * surv + maskBias[row];
  }
}

extern "C" void kernel_launch(void* const* d_in, const int* in_sizes, int n_in,
                              void* d_out, int out_size, void* d_ws, size_t ws_size,
                              hipStream_t stream) {
  const int B = 2, S = 2048, H = 768, I = 256;
  const int NH = 12, SNH = 4;
  const int M = B * S;  // 4096

  const float* x = (const float*)d_in[0];
  const int* mask = (const int*)d_in[1];
  const float* qw = (const float*)d_in[2];
  const float* qb = (const float*)d_in[3];
  const float* kw = (const float*)d_in[4];
  const float* kb = (const float*)d_in[5];
  const float* vw = (const float*)d_in[6];
  const float* vb = (const float*)d_in[7];
  const float* ow = (const float*)d_in[8];
  const float* ob = (const float*)d_in[9];
  const float* sp_w = (const float*)d_in[10];
  const float* sp_b = (const float*)d_in[11];
  const float* sa_in_w = (const float*)d_in[12];
  const float* sa_in_b = (const float*)d_in[13];
  const float* sa_out_w = (const float*)d_in[14];
  const float* sa_out_b = (const float*)d_in[15];
  const float* nw1 = (const float*)d_in[16];
  const float* nb1 = (const float*)d_in[17];
  const float* nw2 = (const float*)d_in[18];
  const float* nb2 = (const float*)d_in[19];
  const float* mw1 = (const float*)d_in[20];
  const float* mb1 = (const float*)d_in[21];
  const float* mw2 = (const float*)d_in[22];
  const float* mb2 = (const float*)d_in[23];
  const float* dw1 = (const float*)d_in[24];
  const float* db1 = (const float*)d_in[25];
  const float* dw2 = (const float*)d_in[26];
  const float* db2 = (const float*)d_in[27];

  char* ws = (char*)d_ws;
  size_t off = 0;
  auto alloc = [&](size_t bytes) -> void* {
    void* p = ws + off;
    off += (bytes + 255) & ~(size_t)255;
    return p;
  };

  // persistent
  bf16* xb = (bf16*)alloc((size_t)M * H * 2);
  bf16* wqkv = (bf16*)alloc((size_t)3 * H * H * 2);
  float* bqkv = (float*)alloc((size_t)3 * H * 4);
  bf16* wob = (bf16*)alloc((size_t)H * H * 2);
  bf16* spwb = (bf16*)alloc((size_t)I * H * 2);
  bf16* sainb = (bf16*)alloc((size_t)(3 * I) * I * 2);
  bf16* saoutb = (bf16*)alloc((size_t)I * I * 2);
  bf16* w1pack = (bf16*)alloc((size_t)384 * 256 * 2);
  float* b1pack = (float*)alloc((size_t)384 * 4);
  float* maskBias = (float*)alloc((size_t)M * 4);
  float* biasMain = (float*)alloc((size_t)M * 4);

  const int SPM = 4, SPS = 8;
  size_t offMark = off;
  // phase A (scorer)
  bf16* h0 = (bf16*)alloc((size_t)M * I * 2);
  bf16* qkv_s = (bf16*)alloc((size_t)M * (3 * I) * 2);
  bf16* vt_s = (bf16*)alloc((size_t)B * SNH * 64 * S * 2);
  bf16* attn_s = (bf16*)alloc((size_t)M * I * 2);
  bf16* h1 = (bf16*)alloc((size_t)M * I * 2);
  bf16* hid = (bf16*)alloc((size_t)M * 384 * 2);
  float* Opart_s = (float*)alloc((size_t)SPS * B * SNH * S * 64 * 4);
  float2* ML_s = (float2*)alloc((size_t)SPS * B * SNH * S * 8);
  size_t endA = off;
  // phase B (main) overlays phase A
  off = offMark;
  bf16* QKVm = (bf16*)alloc((size_t)M * 3 * H * 2);
  bf16* vt_m = (bf16*)alloc((size_t)B * NH * 64 * S * 2);
  bf16* attn_m = (bf16*)alloc((size_t)M * H * 2);
  float* Opart_m = (float*)alloc((size_t)SPM * B * NH * S * 64 * 4);
  float2* ML_m = (float2*)alloc((size_t)SPM * B * NH * S * 8);
  size_t endB = off;
  size_t need = endA > endB ? endA : endB;
  bool split_ok = ws_size >= need;
  (void)in_sizes; (void)n_in; (void)out_size;

  pack_all<<<5926, 256, 0, stream>>>(x, qw, kw, vw, ow, sp_w, sa_in_w, sa_out_w, nw1, mw1, dw1,
                                     qb, kb, vb, nb1, mb1, db1, mask,
                                     xb, wqkv, wob, spwb, sainb, saoutb, w1pack, bqkv, b1pack,
                                     maskBias);

  // ---- scorer branch ----
  gemm_nt<0, 0><<<(M / 64) * (I / 64), 256, 0, stream>>>(xb, H, spwb, H, sp_b, h0, I, I / 64, H);
  gemm_nt<0, 0><<<(M / 64) * ((3 * I) / 64), 256, 0, stream>>>(h0, I, sainb, I, sa_in_b, qkv_s,
                                                               3 * I, (3 * I) / 64, I);
  vtrans<<<B * SNH * (S / 64), 256, 0, stream>>>(qkv_s, 3 * I, 2 * I, vt_s, SNH, S);
  if (split_ok) {
    flash5_k<SPS, 1><<<SPS * B * SNH * (S / 128), 256, 0, stream>>>(
        qkv_s, qkv_s + I, 3 * I, vt_s, maskBias, nullptr, 0, Opart_s, ML_s, SNH, S, 0.125f, B);
    flash_comb<<<(B * SNH * S * 16) / 256, 256, 0, stream>>>(Opart_s, ML_s, attn_s, I, SNH, S,
                                                             B, SPS);
  } else {
    flash5_k<1, 0><<<B * SNH * (S / 128), 256, 0, stream>>>(
        qkv_s, qkv_s + I, 3 * I, vt_s, maskBias, attn_s, I, nullptr, nullptr, SNH, S, 0.125f, B);
  }
  gemm_nt<0, 0><<<(M / 64) * (I / 64), 256, 0, stream>>>(attn_s, I, saoutb, I, sa_out_b, h1, I,
                                                         I / 64, I);
  gemm_nt<0, 1><<<(M / 64) * (384 / 64), 256, 0, stream>>>(h1, I, w1pack, I, b1pack, hid, 384,
                                                           384 / 64, I);
  surv_k<<<M / 4, 256, 0, stream>>>(hid, nw2, nb2, mw2, mb2, dw2, db2, maskBias, biasMain);

  // ---- main branch ----
  gemm_big<0><<<(M / 128) * (3 * H / 128), 256, 0, stream>>>(xb, wqkv, bqkv, QKVm, 3 * H,
                                                             3 * H / 128, H);
  vtrans<<<B * NH * (S / 64), 256, 0, stream>>>(QKVm, 3 * H, 2 * H, vt_m, NH, S);
  if (split_ok) {
    flash5_k<SPM, 1><<<SPM * B * NH * (S / 128), 256, 0, stream>>>(
        QKVm, QKVm + H, 3 * H, vt_m, biasMain, nullptr, 0, Opart_m, ML_m, NH, S, 0.125f, B);
    flash_comb<<<(B * NH * S * 16) / 256, 256, 0, stream>>>(Opart_m, ML_m, attn_m, H, NH, S, B,
                                                            SPM);
  } else {
    flash5_k<1, 0><<<B * NH * (S / 128), 256, 0, stream>>>(
        QKVm, QKVm + H, 3 * H, vt_m, biasMain, attn_m, H, nullptr, nullptr, NH, S, 0.125f, B);
  }
  gemm_big<1><<<(M / 128) * (H / 128), 256, 0, stream>>>(attn_m, wob, ob, d_out, H,
                                                         H / 128, H);
}

// Round 8
// 211.579 us; speedup vs baseline: 2.4363x; 1.0398x over previous
//
#include <hip/hip_runtime.h>
#include <math.h>

typedef __bf16 bf16;
typedef __bf16 bfrag __attribute__((ext_vector_type(8)));
typedef __bf16 bf4 __attribute__((ext_vector_type(4)));
typedef float f4 __attribute__((ext_vector_type(4)));
typedef float f16v __attribute__((ext_vector_type(16)));

#define LOG2E 1.4426950408889634f

#define DEV static __device__ __forceinline__

DEV f4 MFMA(bfrag a, bfrag b, f4 c) {
  return __builtin_amdgcn_mfma_f32_16x16x32_bf16(a, b, c, 0, 0, 0);
}
DEV f16v MFMA32(bfrag a, bfrag b, f16v c) {
  return __builtin_amdgcn_mfma_f32_32x32x16_bf16(a, b, c, 0, 0, 0);
}
DEV float ex2(float x) { return __builtin_amdgcn_exp2f(x); }
DEV unsigned pkbf(float a, float b) {
  bf16 ha = (bf16)a, hb = (bf16)b;
  unsigned short ua = __builtin_bit_cast(unsigned short, ha);
  unsigned short ub = __builtin_bit_cast(unsigned short, hb);
  return (unsigned)ua | ((unsigned)ub << 16);
}
DEV void gload_lds16(const bf16* g, bf16* l) {
  __builtin_amdgcn_global_load_lds(
      (const __attribute__((address_space(1))) void*)g,
      (__attribute__((address_space(3))) void*)l, 16, 0, 0);
}

// ---------------- fused setup: all fp32->bf16 converts + bias packs + maskbias ----------------
// maskBias is stored PRE-SCALED by LOG2E (exp2 domain).
__global__ __launch_bounds__(256) void pack_all(
    const float* __restrict__ x, const float* __restrict__ qw, const float* __restrict__ kw,
    const float* __restrict__ vw, const float* __restrict__ ow, const float* __restrict__ sp_w,
    const float* __restrict__ sa_in_w, const float* __restrict__ sa_out_w,
    const float* __restrict__ nw1, const float* __restrict__ mw1, const float* __restrict__ dw1,
    const float* __restrict__ qb, const float* __restrict__ kb, const float* __restrict__ vb,
    const float* __restrict__ nb1, const float* __restrict__ mb1, const float* __restrict__ db1,
    const int* __restrict__ mask,
    bf16* __restrict__ xb, bf16* __restrict__ wqkv, bf16* __restrict__ wob,
    bf16* __restrict__ spwb, bf16* __restrict__ sainb, bf16* __restrict__ saoutb,
    bf16* __restrict__ w1pack, float* __restrict__ bqkv, float* __restrict__ b1pack,
    float* __restrict__ maskBias) {
  int bid = blockIdx.x;
  int tid = threadIdx.x;
  const float* src = nullptr;
  bf16* dst = nullptr;
  int rel = 0;
  if (bid < 3072)      { src = x;       dst = xb;                   rel = bid; }
  else if (bid < 3648) { src = qw;      dst = wqkv;                 rel = bid - 3072; }
  else if (bid < 4224) { src = kw;      dst = wqkv + 589824;        rel = bid - 3648; }
  else if (bid < 4800) { src = vw;      dst = wqkv + 2 * 589824;    rel = bid - 4224; }
  else if (bid < 5376) { src = ow;      dst = wob;                  rel = bid - 4800; }
  else if (bid < 5568) { src = sp_w;    dst = spwb;                 rel = bid - 5376; }
  else if (bid < 5760) { src = sa_in_w; dst = sainb;                rel = bid - 5568; }
  else if (bid < 5824) { src = sa_out_w;dst = saoutb;               rel = bid - 5760; }
  else if (bid < 5856) { src = nw1;     dst = w1pack;               rel = bid - 5824; }
  else if (bid < 5888) { src = mw1;     dst = w1pack + 32768;       rel = bid - 5856; }
  else if (bid < 5920) { src = dw1;     dst = w1pack + 2 * 32768;   rel = bid - 5888; }
  else if (bid == 5920) {
    if (tid < 576) {
      int which = tid / 192, j = tid % 192;
      const float* s = which == 0 ? qb : (which == 1 ? kb : vb);
      reinterpret_cast<float4*>(bqkv)[tid] = reinterpret_cast<const float4*>(s)[j];
    }
    return;
  } else if (bid == 5921) {
    if (tid < 96) {
      int which = tid / 32, j = tid % 32;
      const float* s = which == 0 ? nb1 : (which == 1 ? mb1 : db1);
      reinterpret_cast<float4*>(b1pack)[tid] = reinterpret_cast<const float4*>(s)[j];
    }
    return;
  } else {
    int idx = (bid - 5922) * 256 + tid;
    int4 m = reinterpret_cast<const int4*>(mask)[idx];
    float4 o;
    o.x = m.x > 0 ? 0.f : -1e9f * LOG2E;
    o.y = m.y > 0 ? 0.f : -1e9f * LOG2E;
    o.z = m.z > 0 ? 0.f : -1e9f * LOG2E;
    o.w = m.w > 0 ? 0.f : -1e9f * LOG2E;
    reinterpret_cast<float4*>(maskBias)[idx] = o;
    return;
  }
  int i = rel * 256 + tid;
  float4 v = reinterpret_cast<const float4*>(src)[i];
  bf4 o;
  o[0] = (bf16)v.x; o[1] = (bf16)v.y; o[2] = (bf16)v.z; o[3] = (bf16)v.w;
  reinterpret_cast<bf4*>(dst)[i] = o;
}

// ---------------- GEMM 64x64 tile: C[M,N] = act(A[M,K] @ W[N,K]^T + bias) ----------------
template<int OUTF32, int RELU>
__global__ __launch_bounds__(256) void gemm_nt(
    const bf16* __restrict__ A, int lda,
    const bf16* __restrict__ W, int ldw,
    const float* __restrict__ bias,
    void* __restrict__ C, int ldc,
    int N64, int K) {
  int lane = threadIdx.x & 63;
  int w = threadIdx.x >> 6;
  int lrow = lane & 15, lgrp = lane >> 4;
  int tn = blockIdx.x % N64, tm = blockIdx.x / N64;
  int m0 = tm * 64 + (w >> 1) * 32;
  int n0 = tn * 64 + (w & 1) * 32;
  const bf16* Ab = A + (size_t)m0 * lda + lgrp * 8;
  const bf16* Wb = W + (size_t)n0 * ldw + lgrp * 8;
  f4 acc[2][2] = {};
  for (int k0 = 0; k0 < K; k0 += 32) {
    bfrag a0 = *(const bfrag*)(Ab + (size_t)lrow * lda + k0);
    bfrag a1 = *(const bfrag*)(Ab + (size_t)(lrow + 16) * lda + k0);
    bfrag b0 = *(const bfrag*)(Wb + (size_t)lrow * ldw + k0);
    bfrag b1 = *(const bfrag*)(Wb + (size_t)(lrow + 16) * ldw + k0);
    acc[0][0] = MFMA(a0, b0, acc[0][0]);
    acc[0][1] = MFMA(a0, b1, acc[0][1]);
    acc[1][0] = MFMA(a1, b0, acc[1][0]);
    acc[1][1] = MFMA(a1, b1, acc[1][1]);
  }
#pragma unroll
  for (int mi = 0; mi < 2; mi++)
#pragma unroll
    for (int nj = 0; nj < 2; nj++) {
      int col = n0 + nj * 16 + lrow;
      float bv = bias[col];
      int rowb = m0 + mi * 16 + lgrp * 4;
#pragma unroll
      for (int i = 0; i < 4; i++) {
        float v = acc[mi][nj][i] + bv;
        if (RELU) v = fmaxf(v, 0.f);
        if (OUTF32)
          ((float*)C)[(size_t)(rowb + i) * ldc + col] = v;
        else
          ((bf16*)C)[(size_t)(rowb + i) * ldc + col] = (bf16)v;
      }
    }
}

// ---------------- GEMM 128x128 tile, global_load_lds + swizzled LDS, 2-phase dbuf ----------
template<int OUTF32>
__global__ __launch_bounds__(256, 2) void gemm_big(
    const bf16* __restrict__ A,
    const bf16* __restrict__ W,
    const float* __restrict__ bias,
    void* __restrict__ C, int ldc,
    int N128, int K) {
  __shared__ char smem[65536];
  int lane = threadIdx.x & 63;
  int w = threadIdx.x >> 6;
  int lrow = lane & 15, lgrp = lane >> 4;
  int tn = blockIdx.x % N128, tm = blockIdx.x / N128;
  int m0 = tm * 128, n0 = tn * 128;

  int srow = lane >> 3;
  int sslot = (lane & 7) ^ srow;

  auto stage = [&](int bufb, int k0) {
#pragma unroll
    for (int j = 0; j < 4; j++) {
      int rb = (w * 4 + j) * 8 + srow;
      gload_lds16(A + (size_t)(m0 + rb) * K + k0 + sslot * 8,
                  (bf16*)(smem + bufb + (w * 4 + j) * 1024));
      gload_lds16(W + (size_t)(n0 + rb) * K + k0 + sslot * 8,
                  (bf16*)(smem + bufb + 16384 + (w * 4 + j) * 1024));
    }
  };

  f4 acc[4][4] = {};
  int swz = (lrow & 7) << 4;
  int mbase = (w >> 1) * 64, nbase = (w & 1) * 64;

  stage(0, 0);
  __syncthreads();
  int buf = 0;
  int nt = K / 64;
  for (int t = 0; t < nt; t++) {
    int nbuf = buf ^ 32768;
    if (t + 1 < nt) stage(nbuf, (t + 1) * 64);
    const char* As = smem + buf;
    const char* Ws = smem + buf + 16384;
#pragma unroll
    for (int kb = 0; kb < 128; kb += 64) {
      bfrag a[4], b[4];
#pragma unroll
      for (int i = 0; i < 4; i++) {
        a[i] = *(const bfrag*)(As + (mbase + i * 16 + lrow) * 128 + ((kb + lgrp * 16) ^ swz));
        b[i] = *(const bfrag*)(Ws + (nbase + i * 16 + lrow) * 128 + ((kb + lgrp * 16) ^ swz));
      }
#pragma unroll
      for (int mi = 0; mi < 4; mi++)
#pragma unroll
        for (int nj = 0; nj < 4; nj++)
          acc[mi][nj] = MFMA(a[mi], b[nj], acc[mi][nj]);
    }
    __syncthreads();
    buf = nbuf;
  }

#pragma unroll
  for (int mi = 0; mi < 4; mi++)
#pragma unroll
    for (int nj = 0; nj < 4; nj++) {
      int col = n0 + nbase + nj * 16 + lrow;
      float bv = bias[col];
      int rowb = m0 + mbase + mi * 16 + lgrp * 4;
#pragma unroll
      for (int i = 0; i < 4; i++) {
        float v = acc[mi][nj][i] + bv;
        if (OUTF32)
          ((float*)C)[(size_t)(rowb + i) * ldc + col] = v;
        else
          ((bf16*)C)[(size_t)(rowb + i) * ldc + col] = (bf16)v;
      }
    }
}

// ---------------- V transpose: Vt[b][h][d][s] = V[b][s][coff + h*64 + d] ----------------
__global__ __launch_bounds__(256) void vtrans(const bf16* __restrict__ V, int rs, int coff,
                                              bf16* __restrict__ Vt, int H, int S) {
  int nst = S / 64;
  int st = blockIdx.x % nst;
  int h = (blockIdx.x / nst) % H;
  int b = blockIdx.x / (nst * H);
  __shared__ bf16 tile[64][72];
  int t = threadIdx.x;
  int r = t >> 2, c = t & 3;
  const bf16* src = V + ((size_t)b * S + st * 64 + r) * rs + coff + h * 64 + c * 16;
  bfrag v0 = *(const bfrag*)(src);
  bfrag v1 = *(const bfrag*)(src + 8);
  *(bfrag*)&tile[r][c * 16] = v0;
  *(bfrag*)&tile[r][c * 16 + 8] = v1;
  __syncthreads();
  bf16* dst = Vt + (((size_t)b * H + h) * 64 + r) * S + st * 64 + c * 16;
  bfrag o0, o1;
#pragma unroll
  for (int j = 0; j < 8; j++) {
    o0[j] = tile[c * 16 + j][r];
    o1[j] = tile[c * 16 + 8 + j][r];
  }
  *(bfrag*)dst = o0;
  *(bfrag*)(dst + 8) = o1;
}

// ---------------- flash attention v6: no-max exp2 softmax, LDS-staged K/V ----------------
// Scores are small (|s|<~12) and masked keys carry -1.44e9 bias -> exp2 underflows to 0,
// so fixed m=0 is numerically safe in f32 (l <= S * 2^18). scale/bias are exp2-domain.
template<int SPLIT, int PARTIAL>
__global__ __launch_bounds__(256) void flash6_k(
    const bf16* __restrict__ Q, const bf16* __restrict__ Kp, int rs,
    const bf16* __restrict__ Vt, const float* __restrict__ bias,
    bf16* __restrict__ O, int ors,
    float* __restrict__ Opart, float* __restrict__ Lpart,
    int H, int S, float scale, int Bc) {
  int nqt = S / 128;
  int bid = blockIdx.x;
  int qt = bid % nqt;
  int hh = (bid / nqt) % H;
  int b = (bid / (nqt * H)) % Bc;
  int sp = bid / (nqt * H * Bc);
  int lane = threadIdx.x & 63, w = threadIdx.x >> 6;
  int l31 = lane & 31, hf = lane >> 5;
  int q0 = qt * 128 + w * 32;
  const int kchunk = S / SPLIT;
  int k_beg = sp * kchunk;
  int swzl = (l31 & 7) << 4;

  const bf16* Qb = Q + ((size_t)b * S + q0 + l31) * rs + hh * 64 + hf * 8;
  bfrag qf[4];
#pragma unroll
  for (int c = 0; c < 4; c++) qf[c] = *(const bfrag*)(Qb + 16 * c);

  const bf16* gK0 = Kp + ((size_t)b * S + k_beg) * rs + hh * 64;
  const bf16* gV0 = Vt + (((size_t)b * H + hh) * 64) * (size_t)S + k_beg;
  const float* biasb = bias + (size_t)b * S;

  __shared__ bf16 KT[2][4096];
  __shared__ bf16 VT[2][4096];

  f16v acc0, acc1;
#pragma unroll
  for (int r = 0; r < 16; r++) { acc0[r] = 0.f; acc1[r] = 0.f; }
  float lrun = 0.f;

  int sidx0 = (w * 2) * 64 + lane;
  int sidx1 = (w * 2 + 1) * 64 + lane;
  int srow0 = sidx0 >> 3, sc0 = sidx0 & 7;
  int srow1 = sidx1 >> 3, sc1 = sidx1 & 7;
  int soff0 = srow0 * 128 + ((sc0 * 16) ^ ((srow0 & 7) << 4));
  int soff1 = srow1 * 128 + ((sc1 * 16) ^ ((srow1 & 7) << 4));

  bfrag kr0, kr1, vr0, vr1;
  kr0 = *(const bfrag*)(gK0 + (size_t)srow0 * rs + sc0 * 8);
  kr1 = *(const bfrag*)(gK0 + (size_t)srow1 * rs + sc1 * 8);
  vr0 = *(const bfrag*)(gV0 + (size_t)srow0 * S + sc0 * 8);
  vr1 = *(const bfrag*)(gV0 + (size_t)srow1 * S + sc1 * 8);
  *(bfrag*)((char*)KT[0] + soff0) = kr0;
  *(bfrag*)((char*)KT[0] + soff1) = kr1;
  *(bfrag*)((char*)VT[0] + soff0) = vr0;
  *(bfrag*)((char*)VT[0] + soff1) = vr1;
  __syncthreads();

  const int nt = kchunk / 64;
  for (int t = 0; t < nt; t++) {
    int kt = k_beg + t * 64;
    if (t + 1 < nt) {
      const bf16* gK = gK0 + (size_t)(t + 1) * 64 * rs;
      const bf16* gV = gV0 + (t + 1) * 64;
      kr0 = *(const bfrag*)(gK + (size_t)srow0 * rs + sc0 * 8);
      kr1 = *(const bfrag*)(gK + (size_t)srow1 * rs + sc1 * 8);
      vr0 = *(const bfrag*)(gV + (size_t)srow0 * S + sc0 * 8);
      vr1 = *(const bfrag*)(gV + (size_t)srow1 * S + sc1 * 8);
    }

    const char* KTb = (const char*)KT[t & 1];
    const char* VTb = (const char*)VT[t & 1];

    f16v s_lo, s_hi;
#pragma unroll
    for (int r = 0; r < 16; r++) { s_lo[r] = 0.f; s_hi[r] = 0.f; }
#pragma unroll
    for (int c = 0; c < 4; c++) {
      int colb = 32 * c + 16 * hf;
      bfrag klo = *(const bfrag*)(KTb + l31 * 128 + (colb ^ swzl));
      bfrag khi = *(const bfrag*)(KTb + (32 + l31) * 128 + (colb ^ swzl));
      s_lo = MFMA32(klo, qf[c], s_lo);
      s_hi = MFMA32(khi, qf[c], s_hi);
    }

    f4 blo[4], bhi[4];
#pragma unroll
    for (int g = 0; g < 4; g++) {
      blo[g] = *(const f4*)(biasb + kt + g * 8 + hf * 4);
      bhi[g] = *(const f4*)(biasb + kt + 32 + g * 8 + hf * 4);
    }
    // p = exp2(s * scale + bias)  (no max tracking)
#pragma unroll
    for (int r = 0; r < 16; r++) {
      s_lo[r] = ex2(s_lo[r] * scale + blo[r >> 2][r & 3]);
      s_hi[r] = ex2(s_hi[r] * scale + bhi[r >> 2][r & 3]);
    }
    float rsum = s_lo[0] + s_hi[0];
#pragma unroll
    for (int r = 1; r < 16; r++) rsum += s_lo[r] + s_hi[r];
    rsum += __shfl_xor(rsum, 32);
    lrun += rsum;

    bfrag pb[4];
#pragma unroll
    for (int cc = 0; cc < 4; cc++) {
      const f16v& sv = (cc < 2) ? s_lo : s_hi;
      int rb = (cc & 1) * 8;
      unsigned lo0 = pkbf(sv[rb + 0], sv[rb + 1]);
      unsigned lo1 = pkbf(sv[rb + 2], sv[rb + 3]);
      unsigned hi0 = pkbf(sv[rb + 4], sv[rb + 5]);
      unsigned hi1 = pkbf(sv[rb + 6], sv[rb + 7]);
      unsigned t0 = hf ? lo0 : hi0;
      unsigned t1 = hf ? lo1 : hi1;
      unsigned r0 = (unsigned)__shfl_xor((int)t0, 32);
      unsigned r1 = (unsigned)__shfl_xor((int)t1, 32);
      union { bfrag v; unsigned u[4]; } pu;
      pu.u[0] = hf ? r0 : lo0;
      pu.u[1] = hf ? r1 : lo1;
      pu.u[2] = hf ? hi0 : r0;
      pu.u[3] = hf ? hi1 : r1;
      pb[cc] = pu.v;
    }

#pragma unroll
    for (int c = 0; c < 4; c++) {
      int colb = 32 * c + 16 * hf;
      bfrag v0 = *(const bfrag*)(VTb + l31 * 128 + (colb ^ swzl));
      bfrag v1 = *(const bfrag*)(VTb + (32 + l31) * 128 + (colb ^ swzl));
      acc0 = MFMA32(v0, pb[c], acc0);
      acc1 = MFMA32(v1, pb[c], acc1);
    }

    if (t + 1 < nt) {
      char* KTn = (char*)KT[(t + 1) & 1];
      char* VTn = (char*)VT[(t + 1) & 1];
      *(bfrag*)(KTn + soff0) = kr0;
      *(bfrag*)(KTn + soff1) = kr1;
      *(bfrag*)(VTn + soff0) = vr0;
      *(bfrag*)(VTn + soff1) = vr1;
    }
    __syncthreads();
  }

  int q = q0 + l31;
  if (PARTIAL) {
    float* op = Opart + ((((size_t)sp * Bc + b) * H + hh) * S + q) * 64 + hf * 4;
#pragma unroll
    for (int g = 0; g < 4; g++) {
      f4 v0, v1;
#pragma unroll
      for (int i = 0; i < 4; i++) { v0[i] = acc0[4 * g + i]; v1[i] = acc1[4 * g + i]; }
      *(f4*)(op + g * 8) = v0;
      *(f4*)(op + 32 + g * 8) = v1;
    }
    if (hf == 0)
      Lpart[(((size_t)sp * Bc + b) * H + hh) * S + q] = lrun;
  } else {
    float inv = 1.f / lrun;
    bf16* Ob = O + ((size_t)b * S + q) * ors + hh * 64 + hf * 4;
#pragma unroll
    for (int g = 0; g < 4; g++) {
      bf4 o0, o1;
#pragma unroll
      for (int i = 0; i < 4; i++) {
        o0[i] = (bf16)(acc0[4 * g + i] * inv);
        o1[i] = (bf16)(acc1[4 * g + i] * inv);
      }
      *(bf4*)(Ob + g * 8) = o0;
      *(bf4*)(Ob + 32 + g * 8) = o1;
    }
  }
}

// ---------------- combine split-K flash partials (fixed m: plain sums) ----------------
__global__ __launch_bounds__(256) void flash_comb(
    const float* __restrict__ Opart, const float* __restrict__ L,
    bf16* __restrict__ O, int ors, int Hh, int S, int Bc, int nsplit) {
  int idx = blockIdx.x * 256 + threadIdx.x;
  int d4 = idx & 15;
  int q = (idx >> 4) % S;
  int hh = ((idx >> 4) / S) % Hh;
  int b = (idx >> 4) / (S * Hh);
  size_t rowstride = (size_t)Bc * Hh * S;
  size_t rbase = ((size_t)b * Hh + hh) * S + q;
  float lsum = 0.f;
  f4 o = {0.f, 0.f, 0.f, 0.f};
  for (int sp = 0; sp < nsplit; sp++) {
    lsum += L[sp * rowstride + rbase];
    f4 a = *(const f4*)(Opart + (sp * rowstride + rbase) * 64 + d4 * 4);
#pragma unroll
    for (int i = 0; i < 4; i++) o[i] += a[i];
  }
  float inv = 1.f / lsum;
  bf4 obv;
#pragma unroll
  for (int i = 0; i < 4; i++) obv[i] = (bf16)(o[i] * inv);
  *(bf4*)(O + ((size_t)b * S + q) * ors + hh * 64 + d4 * 4) = obv;
}

// ---------------- survival epilogue (writes exp2-domain bias) ----------------
__global__ __launch_bounds__(256) void surv_k(
    const bf16* __restrict__ hid,
    const float* __restrict__ nw2, const float* __restrict__ nb2,
    const float* __restrict__ mw2, const float* __restrict__ mb2,
    const float* __restrict__ dw2, const float* __restrict__ db2,
    const float* __restrict__ maskBias, float* __restrict__ biasMain) {
  int w = threadIdx.x >> 6, lane = threadIdx.x & 63;
  int row = blockIdx.x * 4 + w;
  const bf16* hr = hid + (size_t)row * 384;
  const float* W2[3] = {nw2, mw2, dw2};
  float outs[3];
#pragma unroll
  for (int t = 0; t < 3; t++) {
    float acc = (float)hr[t * 128 + lane] * W2[t][lane] +
                (float)hr[t * 128 + 64 + lane] * W2[t][64 + lane];
    for (int msk = 1; msk < 64; msk <<= 1) acc += __shfl_xor(acc, msk);
    outs[t] = acc;
  }
  if (lane == 0) {
    float xn = outs[0] + nb2[0];
    float n = (xn > 20.f) ? xn : log1pf(__expf(xn));
    float mu = 1.f / (1.f + __expf(-(outs[1] + mb2[0])));
    float delta = fmaxf(outs[2] + db2[0], 0.f);
    float surv = logf(n + 1e-8f) + logf(mu + 1e-8f) - delta;
    // maskBias already in exp2 domain; scale the surv term too
    biasMain[row] = 0.1f * LOG2E * surv + maskBias[row];
  }
}

extern "C" void kernel_launch(void* const* d_in, const int* in_sizes, int n_in,
                              void* d_out, int out_size, void* d_ws, size_t ws_size,
                              hipStream_t stream) {
  const int B = 2, S = 2048, H = 768, I = 256;
  const int NH = 12, SNH = 4;
  const int M = B * S;  // 4096
  const float SC = 0.125f * LOG2E;

  const float* x = (const float*)d_in[0];
  const int* mask = (const int*)d_in[1];
  const float* qw = (const float*)d_in[2];
  const float* qb = (const float*)d_in[3];
  const float* kw = (const float*)d_in[4];
  const float* kb = (const float*)d_in[5];
  const float* vw = (const float*)d_in[6];
  const float* vb = (const float*)d_in[7];
  const float* ow = (const float*)d_in[8];
  const float* ob = (const float*)d_in[9];
  const float* sp_w = (const float*)d_in[10];
  const float* sp_b = (const float*)d_in[11];
  const float* sa_in_w = (const float*)d_in[12];
  const float* sa_in_b = (const float*)d_in[13];
  const float* sa_out_w = (const float*)d_in[14];
  const float* sa_out_b = (const float*)d_in[15];
  const float* nw1 = (const float*)d_in[16];
  const float* nb1 = (const float*)d_in[17];
  const float* nw2 = (const float*)d_in[18];
  const float* nb2 = (const float*)d_in[19];
  const float* mw1 = (const float*)d_in[20];
  const float* mb1 = (const float*)d_in[21];
  const float* mw2 = (const float*)d_in[22];
  const float* mb2 = (const float*)d_in[23];
  const float* dw1 = (const float*)d_in[24];
  const float* db1 = (const float*)d_in[25];
  const float* dw2 = (const float*)d_in[26];
  const float* db2 = (const float*)d_in[27];

  char* ws = (char*)d_ws;
  size_t off = 0;
  auto alloc = [&](size_t bytes) -> void* {
    void* p = ws + off;
    off += (bytes + 255) & ~(size_t)255;
    return p;
  };

  // persistent
  bf16* xb = (bf16*)alloc((size_t)M * H * 2);
  bf16* wqkv = (bf16*)alloc((size_t)3 * H * H * 2);
  float* bqkv = (float*)alloc((size_t)3 * H * 4);
  bf16* wob = (bf16*)alloc((size_t)H * H * 2);
  bf16* spwb = (bf16*)alloc((size_t)I * H * 2);
  bf16* sainb = (bf16*)alloc((size_t)(3 * I) * I * 2);
  bf16* saoutb = (bf16*)alloc((size_t)I * I * 2);
  bf16* w1pack = (bf16*)alloc((size_t)384 * 256 * 2);
  float* b1pack = (float*)alloc((size_t)384 * 4);
  float* maskBias = (float*)alloc((size_t)M * 4);
  float* biasMain = (float*)alloc((size_t)M * 4);

  const int SPM = 4, SPS = 8;
  size_t offMark = off;
  // phase A (scorer)
  bf16* h0 = (bf16*)alloc((size_t)M * I * 2);
  bf16* qkv_s = (bf16*)alloc((size_t)M * (3 * I) * 2);
  bf16* vt_s = (bf16*)alloc((size_t)B * SNH * 64 * S * 2);
  bf16* attn_s = (bf16*)alloc((size_t)M * I * 2);
  bf16* h1 = (bf16*)alloc((size_t)M * I * 2);
  bf16* hid = (bf16*)alloc((size_t)M * 384 * 2);
  float* Opart_s = (float*)alloc((size_t)SPS * B * SNH * S * 64 * 4);
  float* L_s = (float*)alloc((size_t)SPS * B * SNH * S * 4);
  size_t endA = off;
  // phase B (main) overlays phase A
  off = offMark;
  bf16* QKVm = (bf16*)alloc((size_t)M * 3 * H * 2);
  bf16* vt_m = (bf16*)alloc((size_t)B * NH * 64 * S * 2);
  bf16* attn_m = (bf16*)alloc((size_t)M * H * 2);
  float* Opart_m = (float*)alloc((size_t)SPM * B * NH * S * 64 * 4);
  float* L_m = (float*)alloc((size_t)SPM * B * NH * S * 4);
  size_t endB = off;
  size_t need = endA > endB ? endA : endB;
  bool split_ok = ws_size >= need;
  (void)in_sizes; (void)n_in; (void)out_size;

  pack_all<<<5926, 256, 0, stream>>>(x, qw, kw, vw, ow, sp_w, sa_in_w, sa_out_w, nw1, mw1, dw1,
                                     qb, kb, vb, nb1, mb1, db1, mask,
                                     xb, wqkv, wob, spwb, sainb, saoutb, w1pack, bqkv, b1pack,
                                     maskBias);

  // ---- scorer branch ----
  gemm_nt<0, 0><<<(M / 64) * (I / 64), 256, 0, stream>>>(xb, H, spwb, H, sp_b, h0, I, I / 64, H);
  gemm_nt<0, 0><<<(M / 64) * ((3 * I) / 64), 256, 0, stream>>>(h0, I, sainb, I, sa_in_b, qkv_s,
                                                               3 * I, (3 * I) / 64, I);
  vtrans<<<B * SNH * (S / 64), 256, 0, stream>>>(qkv_s, 3 * I, 2 * I, vt_s, SNH, S);
  if (split_ok) {
    flash6_k<SPS, 1><<<SPS * B * SNH * (S / 128), 256, 0, stream>>>(
        qkv_s, qkv_s + I, 3 * I, vt_s, maskBias, nullptr, 0, Opart_s, L_s, SNH, S, SC, B);
    flash_comb<<<(B * SNH * S * 16) / 256, 256, 0, stream>>>(Opart_s, L_s, attn_s, I, SNH, S,
                                                             B, SPS);
  } else {
    flash6_k<1, 0><<<B * SNH * (S / 128), 256, 0, stream>>>(
        qkv_s, qkv_s + I, 3 * I, vt_s, maskBias, attn_s, I, nullptr, nullptr, SNH, S, SC, B);
  }
  gemm_nt<0, 0><<<(M / 64) * (I / 64), 256, 0, stream>>>(attn_s, I, saoutb, I, sa_out_b, h1, I,
                                                         I / 64, I);
  gemm_nt<0, 1><<<(M / 64) * (384 / 64), 256, 0, stream>>>(h1, I, w1pack, I, b1pack, hid, 384,
                                                           384 / 64, I);
  surv_k<<<M / 4, 256, 0, stream>>>(hid, nw2, nb2, mw2, mb2, dw2, db2, maskBias, biasMain);

  // ---- main branch ----
  gemm_big<0><<<(M / 128) * (3 * H / 128), 256, 0, stream>>>(xb, wqkv, bqkv, QKVm, 3 * H,
                                                             3 * H / 128, H);
  vtrans<<<B * NH * (S / 64), 256, 0, stream>>>(QKVm, 3 * H, 2 * H, vt_m, NH, S);
  if (split_ok) {
    flash6_k<SPM, 1><<<SPM * B * NH * (S / 128), 256, 0, stream>>>(
        QKVm, QKVm + H, 3 * H, vt_m, biasMain, nullptr, 0, Opart_m, L_m, NH, S, SC, B);
    flash_comb<<<(B * NH * S * 16) / 256, 256, 0, stream>>>(Opart_m, L_m, attn_m, H, NH, S, B,
                                                            SPM);
  } else {
    flash6_k<1, 0><<<B * NH * (S / 128), 256, 0, stream>>>(
        QKVm, QKVm + H, 3 * H, vt_m, biasMain, attn_m, H, nullptr, nullptr, NH, S, SC, B);
  }
  gemm_big<1><<<(M / 128) * (H / 128), 256, 0, stream>>>(attn_m, wob, ob, d_out, H,
                                                         H / 128, H);
}

// Round 9
// 196.828 us; speedup vs baseline: 2.6189x; 1.0749x over previous
//
#include <hip/hip_runtime.h>
#include <math.h>

typedef __bf16 bf16;
typedef __bf16 bfrag __attribute__((ext_vector_type(8)));
typedef __bf16 bf4 __attribute__((ext_vector_type(4)));
typedef float f4 __attribute__((ext_vector_type(4)));
typedef float f16v __attribute__((ext_vector_type(16)));

#define LOG2E 1.4426950408889634f

#define DEV static __device__ __forceinline__

DEV f4 MFMA(bfrag a, bfrag b, f4 c) {
  return __builtin_amdgcn_mfma_f32_16x16x32_bf16(a, b, c, 0, 0, 0);
}
DEV f16v MFMA32(bfrag a, bfrag b, f16v c) {
  return __builtin_amdgcn_mfma_f32_32x32x16_bf16(a, b, c, 0, 0, 0);
}
DEV float ex2(float x) { return __builtin_amdgcn_exp2f(x); }
DEV unsigned pkbf(float a, float b) {
  bf16 ha = (bf16)a, hb = (bf16)b;
  unsigned short ua = __builtin_bit_cast(unsigned short, ha);
  unsigned short ub = __builtin_bit_cast(unsigned short, hb);
  return (unsigned)ua | ((unsigned)ub << 16);
}
DEV void gload_lds16(const bf16* g, bf16* l) {
  __builtin_amdgcn_global_load_lds(
      (const __attribute__((address_space(1))) void*)g,
      (__attribute__((address_space(3))) void*)l, 16, 0, 0);
}

// ---------------- fused setup: all fp32->bf16 converts + bias packs + maskbias ----------------
// maskBias is stored PRE-SCALED by LOG2E (exp2 domain).
__global__ __launch_bounds__(256) void pack_all(
    const float* __restrict__ x, const float* __restrict__ qw, const float* __restrict__ kw,
    const float* __restrict__ vw, const float* __restrict__ ow, const float* __restrict__ sp_w,
    const float* __restrict__ sa_in_w, const float* __restrict__ sa_out_w,
    const float* __restrict__ nw1, const float* __restrict__ mw1, const float* __restrict__ dw1,
    const float* __restrict__ qb, const float* __restrict__ kb, const float* __restrict__ vb,
    const float* __restrict__ nb1, const float* __restrict__ mb1, const float* __restrict__ db1,
    const int* __restrict__ mask,
    bf16* __restrict__ xb, bf16* __restrict__ wqkv, bf16* __restrict__ wob,
    bf16* __restrict__ spwb, bf16* __restrict__ sainb, bf16* __restrict__ saoutb,
    bf16* __restrict__ w1pack, float* __restrict__ bqkv, float* __restrict__ b1pack,
    float* __restrict__ maskBias) {
  int bid = blockIdx.x;
  int tid = threadIdx.x;
  const float* src = nullptr;
  bf16* dst = nullptr;
  int rel = 0;
  if (bid < 3072)      { src = x;       dst = xb;                   rel = bid; }
  else if (bid < 3648) { src = qw;      dst = wqkv;                 rel = bid - 3072; }
  else if (bid < 4224) { src = kw;      dst = wqkv + 589824;        rel = bid - 3648; }
  else if (bid < 4800) { src = vw;      dst = wqkv + 2 * 589824;    rel = bid - 4224; }
  else if (bid < 5376) { src = ow;      dst = wob;                  rel = bid - 4800; }
  else if (bid < 5568) { src = sp_w;    dst = spwb;                 rel = bid - 5376; }
  else if (bid < 5760) { src = sa_in_w; dst = sainb;                rel = bid - 5568; }
  else if (bid < 5824) { src = sa_out_w;dst = saoutb;               rel = bid - 5760; }
  else if (bid < 5856) { src = nw1;     dst = w1pack;               rel = bid - 5824; }
  else if (bid < 5888) { src = mw1;     dst = w1pack + 32768;       rel = bid - 5856; }
  else if (bid < 5920) { src = dw1;     dst = w1pack + 2 * 32768;   rel = bid - 5888; }
  else if (bid == 5920) {
    if (tid < 576) {
      int which = tid / 192, j = tid % 192;
      const float* s = which == 0 ? qb : (which == 1 ? kb : vb);
      reinterpret_cast<float4*>(bqkv)[tid] = reinterpret_cast<const float4*>(s)[j];
    }
    return;
  } else if (bid == 5921) {
    if (tid < 96) {
      int which = tid / 32, j = tid % 32;
      const float* s = which == 0 ? nb1 : (which == 1 ? mb1 : db1);
      reinterpret_cast<float4*>(b1pack)[tid] = reinterpret_cast<const float4*>(s)[j];
    }
    return;
  } else {
    int idx = (bid - 5922) * 256 + tid;
    int4 m = reinterpret_cast<const int4*>(mask)[idx];
    float4 o;
    o.x = m.x > 0 ? 0.f : -1e9f * LOG2E;
    o.y = m.y > 0 ? 0.f : -1e9f * LOG2E;
    o.z = m.z > 0 ? 0.f : -1e9f * LOG2E;
    o.w = m.w > 0 ? 0.f : -1e9f * LOG2E;
    reinterpret_cast<float4*>(maskBias)[idx] = o;
    return;
  }
  int i = rel * 256 + tid;
  float4 v = reinterpret_cast<const float4*>(src)[i];
  bf4 o;
  o[0] = (bf16)v.x; o[1] = (bf16)v.y; o[2] = (bf16)v.z; o[3] = (bf16)v.w;
  reinterpret_cast<bf4*>(dst)[i] = o;
}

// ---------------- GEMM 64x64 tile: C[M,N] = act(A[M,K] @ W[N,K]^T + bias) ----------------
template<int OUTF32, int RELU>
__global__ __launch_bounds__(256) void gemm_nt(
    const bf16* __restrict__ A, int lda,
    const bf16* __restrict__ W, int ldw,
    const float* __restrict__ bias,
    void* __restrict__ C, int ldc,
    int N64, int K) {
  int lane = threadIdx.x & 63;
  int w = threadIdx.x >> 6;
  int lrow = lane & 15, lgrp = lane >> 4;
  int tn = blockIdx.x % N64, tm = blockIdx.x / N64;
  int m0 = tm * 64 + (w >> 1) * 32;
  int n0 = tn * 64 + (w & 1) * 32;
  const bf16* Ab = A + (size_t)m0 * lda + lgrp * 8;
  const bf16* Wb = W + (size_t)n0 * ldw + lgrp * 8;
  f4 acc[2][2] = {};
  for (int k0 = 0; k0 < K; k0 += 32) {
    bfrag a0 = *(const bfrag*)(Ab + (size_t)lrow * lda + k0);
    bfrag a1 = *(const bfrag*)(Ab + (size_t)(lrow + 16) * lda + k0);
    bfrag b0 = *(const bfrag*)(Wb + (size_t)lrow * ldw + k0);
    bfrag b1 = *(const bfrag*)(Wb + (size_t)(lrow + 16) * ldw + k0);
    acc[0][0] = MFMA(a0, b0, acc[0][0]);
    acc[0][1] = MFMA(a0, b1, acc[0][1]);
    acc[1][0] = MFMA(a1, b0, acc[1][0]);
    acc[1][1] = MFMA(a1, b1, acc[1][1]);
  }
#pragma unroll
  for (int mi = 0; mi < 2; mi++)
#pragma unroll
    for (int nj = 0; nj < 2; nj++) {
      int col = n0 + nj * 16 + lrow;
      float bv = bias[col];
      int rowb = m0 + mi * 16 + lgrp * 4;
#pragma unroll
      for (int i = 0; i < 4; i++) {
        float v = acc[mi][nj][i] + bv;
        if (RELU) v = fmaxf(v, 0.f);
        if (OUTF32)
          ((float*)C)[(size_t)(rowb + i) * ldc + col] = v;
        else
          ((bf16*)C)[(size_t)(rowb + i) * ldc + col] = (bf16)v;
      }
    }
}

// ---------------- GEMM 128x128 tile, global_load_lds + swizzled LDS, 2-phase dbuf ----------
template<int OUTF32>
__global__ __launch_bounds__(256, 2) void gemm_big(
    const bf16* __restrict__ A,
    const bf16* __restrict__ W,
    const float* __restrict__ bias,
    void* __restrict__ C, int ldc,
    int N128, int K) {
  __shared__ char smem[65536];
  int lane = threadIdx.x & 63;
  int w = threadIdx.x >> 6;
  int lrow = lane & 15, lgrp = lane >> 4;
  int tn = blockIdx.x % N128, tm = blockIdx.x / N128;
  int m0 = tm * 128, n0 = tn * 128;

  int srow = lane >> 3;
  int sslot = (lane & 7) ^ srow;

  auto stage = [&](int bufb, int k0) {
#pragma unroll
    for (int j = 0; j < 4; j++) {
      int rb = (w * 4 + j) * 8 + srow;
      gload_lds16(A + (size_t)(m0 + rb) * K + k0 + sslot * 8,
                  (bf16*)(smem + bufb + (w * 4 + j) * 1024));
      gload_lds16(W + (size_t)(n0 + rb) * K + k0 + sslot * 8,
                  (bf16*)(smem + bufb + 16384 + (w * 4 + j) * 1024));
    }
  };

  f4 acc[4][4] = {};
  int swz = (lrow & 7) << 4;
  int mbase = (w >> 1) * 64, nbase = (w & 1) * 64;

  stage(0, 0);
  __syncthreads();
  int buf = 0;
  int nt = K / 64;
  for (int t = 0; t < nt; t++) {
    int nbuf = buf ^ 32768;
    if (t + 1 < nt) stage(nbuf, (t + 1) * 64);
    const char* As = smem + buf;
    const char* Ws = smem + buf + 16384;
#pragma unroll
    for (int kb = 0; kb < 128; kb += 64) {
      bfrag a[4], b[4];
#pragma unroll
      for (int i = 0; i < 4; i++) {
        a[i] = *(const bfrag*)(As + (mbase + i * 16 + lrow) * 128 + ((kb + lgrp * 16) ^ swz));
        b[i] = *(const bfrag*)(Ws + (nbase + i * 16 + lrow) * 128 + ((kb + lgrp * 16) ^ swz));
      }
#pragma unroll
      for (int mi = 0; mi < 4; mi++)
#pragma unroll
        for (int nj = 0; nj < 4; nj++)
          acc[mi][nj] = MFMA(a[mi], b[nj], acc[mi][nj]);
    }
    __syncthreads();
    buf = nbuf;
  }

#pragma unroll
  for (int mi = 0; mi < 4; mi++)
#pragma unroll
    for (int nj = 0; nj < 4; nj++) {
      int col = n0 + nbase + nj * 16 + lrow;
      float bv = bias[col];
      int rowb = m0 + mbase + mi * 16 + lgrp * 4;
#pragma unroll
      for (int i = 0; i < 4; i++) {
        float v = acc[mi][nj][i] + bv;
        if (OUTF32)
          ((float*)C)[(size_t)(rowb + i) * ldc + col] = v;
        else
          ((bf16*)C)[(size_t)(rowb + i) * ldc + col] = (bf16)v;
      }
    }
}

// ---------------- V transpose: Vt[b][h][d][s] = V[b][s][coff + h*64 + d] ----------------
__global__ __launch_bounds__(256) void vtrans(const bf16* __restrict__ V, int rs, int coff,
                                              bf16* __restrict__ Vt, int H, int S) {
  int nst = S / 64;
  int st = blockIdx.x % nst;
  int h = (blockIdx.x / nst) % H;
  int b = blockIdx.x / (nst * H);
  __shared__ bf16 tile[64][72];
  int t = threadIdx.x;
  int r = t >> 2, c = t & 3;
  const bf16* src = V + ((size_t)b * S + st * 64 + r) * rs + coff + h * 64 + c * 16;
  bfrag v0 = *(const bfrag*)(src);
  bfrag v1 = *(const bfrag*)(src + 8);
  *(bfrag*)&tile[r][c * 16] = v0;
  *(bfrag*)&tile[r][c * 16 + 8] = v1;
  __syncthreads();
  bf16* dst = Vt + (((size_t)b * H + h) * 64 + r) * S + st * 64 + c * 16;
  bfrag o0, o1;
#pragma unroll
  for (int j = 0; j < 8; j++) {
    o0[j] = tile[c * 16 + j][r];
    o1[j] = tile[c * 16 + 8 + j][r];
  }
  *(bfrag*)dst = o0;
  *(bfrag*)(dst + 8) = o1;
}

// ---------------- flash attention v7: gload_lds staged K/V, no-max exp2 softmax ----------------
// LDS image lds[r][s'] = G[r][s'^(r&7)] achieved with LINEAR gload_lds dest + pre-swizzled
// per-lane GLOBAL source (rule #21); readers XOR the slot with (row&7).
template<int SPLIT, int PARTIAL>
__global__ __launch_bounds__(256) void flash7_k(
    const bf16* __restrict__ Q, const bf16* __restrict__ Kp, int rs,
    const bf16* __restrict__ Vt, const float* __restrict__ bias,
    bf16* __restrict__ O, int ors,
    float* __restrict__ Opart, float* __restrict__ Lpart,
    int H, int S, float scale, int Bc) {
  int nqt = S / 128;
  int bid = blockIdx.x;
  int qt = bid % nqt;
  int hh = (bid / nqt) % H;
  int b = (bid / (nqt * H)) % Bc;
  int sp = bid / (nqt * H * Bc);
  int lane = threadIdx.x & 63, w = threadIdx.x >> 6;
  int l31 = lane & 31, hf = lane >> 5;
  int q0 = qt * 128 + w * 32;
  const int kchunk = S / SPLIT;
  int k_beg = sp * kchunk;
  int swzl = (l31 & 7) << 4;

  const bf16* Qb = Q + ((size_t)b * S + q0 + l31) * rs + hh * 64 + hf * 8;
  bfrag qf[4];
#pragma unroll
  for (int c = 0; c < 4; c++) qf[c] = *(const bfrag*)(Qb + 16 * c);

  const bf16* gK0 = Kp + ((size_t)b * S + k_beg) * rs + hh * 64;
  const bf16* gV0 = Vt + (((size_t)b * H + hh) * 64) * (size_t)S + k_beg;
  const float* biasb = bias + (size_t)b * S;

  __shared__ bf16 KT[2][4096];
  __shared__ bf16 VT[2][4096];

  f16v acc0, acc1;
#pragma unroll
  for (int r = 0; r < 16; r++) { acc0[r] = 0.f; acc1[r] = 0.f; }
  float lrun = 0.f;

  // gload_lds staging: wave w, inst j in {0,1}: LDS rows (w*2+j)*8..+8 linear;
  // lane -> row offset lane>>3, slot lane&7; global slot pre-swizzled by row&7.
  int srow = lane >> 3;                      // also == row&7 for 8-row groups
  int sel = ((lane & 7) ^ srow) * 8;         // element offset within row
  int r0 = (w * 2) * 8 + srow;
  int r1 = (w * 2 + 1) * 8 + srow;

  auto stage = [&](int bb, int kt) {
    const bf16* gK = gK0 + (size_t)(kt - k_beg) * rs;
    const bf16* gV = gV0 + (kt - k_beg);
    gload_lds16(gK + (size_t)r0 * rs + sel, KT[bb] + (w * 2) * 512);
    gload_lds16(gK + (size_t)r1 * rs + sel, KT[bb] + (w * 2 + 1) * 512);
    gload_lds16(gV + (size_t)r0 * S + sel, VT[bb] + (w * 2) * 512);
    gload_lds16(gV + (size_t)r1 * S + sel, VT[bb] + (w * 2 + 1) * 512);
  };

  stage(0, k_beg);
  __syncthreads();

  const int nt = kchunk / 64;
  int buf = 0;
  for (int t = 0; t < nt; t++) {
    int kt = k_beg + t * 64;
    if (t + 1 < nt) stage(buf ^ 1, kt + 64);

    const char* KTb = (const char*)KT[buf];
    const char* VTb = (const char*)VT[buf];

    f16v s_lo, s_hi;
#pragma unroll
    for (int r = 0; r < 16; r++) { s_lo[r] = 0.f; s_hi[r] = 0.f; }
#pragma unroll
    for (int c = 0; c < 4; c++) {
      int colb = 32 * c + 16 * hf;
      bfrag klo = *(const bfrag*)(KTb + l31 * 128 + (colb ^ swzl));
      bfrag khi = *(const bfrag*)(KTb + (32 + l31) * 128 + (colb ^ swzl));
      s_lo = MFMA32(klo, qf[c], s_lo);
      s_hi = MFMA32(khi, qf[c], s_hi);
    }

    f4 blo[4], bhi[4];
#pragma unroll
    for (int g = 0; g < 4; g++) {
      blo[g] = *(const f4*)(biasb + kt + g * 8 + hf * 4);
      bhi[g] = *(const f4*)(biasb + kt + 32 + g * 8 + hf * 4);
    }
    // p = exp2(s * scale + bias)  (no max tracking)
#pragma unroll
    for (int r = 0; r < 16; r++) {
      s_lo[r] = ex2(s_lo[r] * scale + blo[r >> 2][r & 3]);
      s_hi[r] = ex2(s_hi[r] * scale + bhi[r >> 2][r & 3]);
    }
    float rsum = s_lo[0] + s_hi[0];
#pragma unroll
    for (int r = 1; r < 16; r++) rsum += s_lo[r] + s_hi[r];
    rsum += __shfl_xor(rsum, 32);
    lrun += rsum;

    bfrag pb[4];
#pragma unroll
    for (int cc = 0; cc < 4; cc++) {
      const f16v& sv = (cc < 2) ? s_lo : s_hi;
      int rb = (cc & 1) * 8;
      unsigned lo0 = pkbf(sv[rb + 0], sv[rb + 1]);
      unsigned lo1 = pkbf(sv[rb + 2], sv[rb + 3]);
      unsigned hi0 = pkbf(sv[rb + 4], sv[rb + 5]);
      unsigned hi1 = pkbf(sv[rb + 6], sv[rb + 7]);
      unsigned t0 = hf ? lo0 : hi0;
      unsigned t1 = hf ? lo1 : hi1;
      unsigned r0s = (unsigned)__shfl_xor((int)t0, 32);
      unsigned r1s = (unsigned)__shfl_xor((int)t1, 32);
      union { bfrag v; unsigned u[4]; } pu;
      pu.u[0] = hf ? r0s : lo0;
      pu.u[1] = hf ? r1s : lo1;
      pu.u[2] = hf ? hi0 : r0s;
      pu.u[3] = hf ? hi1 : r1s;
      pb[cc] = pu.v;
    }

#pragma unroll
    for (int c = 0; c < 4; c++) {
      int colb = 32 * c + 16 * hf;
      bfrag v0 = *(const bfrag*)(VTb + l31 * 128 + (colb ^ swzl));
      bfrag v1 = *(const bfrag*)(VTb + (32 + l31) * 128 + (colb ^ swzl));
      acc0 = MFMA32(v0, pb[c], acc0);
      acc1 = MFMA32(v1, pb[c], acc1);
    }

    __syncthreads();
    buf ^= 1;
  }

  int q = q0 + l31;
  if (PARTIAL) {
    float* op = Opart + ((((size_t)sp * Bc + b) * H + hh) * S + q) * 64 + hf * 4;
#pragma unroll
    for (int g = 0; g < 4; g++) {
      f4 v0, v1;
#pragma unroll
      for (int i = 0; i < 4; i++) { v0[i] = acc0[4 * g + i]; v1[i] = acc1[4 * g + i]; }
      *(f4*)(op + g * 8) = v0;
      *(f4*)(op + 32 + g * 8) = v1;
    }
    if (hf == 0)
      Lpart[(((size_t)sp * Bc + b) * H + hh) * S + q] = lrun;
  } else {
    float inv = 1.f / lrun;
    bf16* Ob = O + ((size_t)b * S + q) * ors + hh * 64 + hf * 4;
#pragma unroll
    for (int g = 0; g < 4; g++) {
      bf4 o0, o1;
#pragma unroll
      for (int i = 0; i < 4; i++) {
        o0[i] = (bf16)(acc0[4 * g + i] * inv);
        o1[i] = (bf16)(acc1[4 * g + i] * inv);
      }
      *(bf4*)(Ob + g * 8) = o0;
      *(bf4*)(Ob + 32 + g * 8) = o1;
    }
  }
}

// ---------------- combine split-K flash partials (fixed m: plain sums) ----------------
__global__ __launch_bounds__(256) void flash_comb(
    const float* __restrict__ Opart, const float* __restrict__ L,
    bf16* __restrict__ O, int ors, int Hh, int S, int Bc, int nsplit) {
  int idx = blockIdx.x * 256 + threadIdx.x;
  int d4 = idx & 15;
  int q = (idx >> 4) % S;
  int hh = ((idx >> 4) / S) % Hh;
  int b = (idx >> 4) / (S * Hh);
  size_t rowstride = (size_t)Bc * Hh * S;
  size_t rbase = ((size_t)b * Hh + hh) * S + q;
  float lsum = 0.f;
  f4 o = {0.f, 0.f, 0.f, 0.f};
  for (int sp = 0; sp < nsplit; sp++) {
    lsum += L[sp * rowstride + rbase];
    f4 a = *(const f4*)(Opart + (sp * rowstride + rbase) * 64 + d4 * 4);
#pragma unroll
    for (int i = 0; i < 4; i++) o[i] += a[i];
  }
  float inv = 1.f / lsum;
  bf4 obv;
#pragma unroll
  for (int i = 0; i < 4; i++) obv[i] = (bf16)(o[i] * inv);
  *(bf4*)(O + ((size_t)b * S + q) * ors + hh * 64 + d4 * 4) = obv;
}

// ---------------- survival epilogue (writes exp2-domain bias) ----------------
__global__ __launch_bounds__(256) void surv_k(
    const bf16* __restrict__ hid,
    const float* __restrict__ nw2, const float* __restrict__ nb2,
    const float* __restrict__ mw2, const float* __restrict__ mb2,
    const float* __restrict__ dw2, const float* __restrict__ db2,
    const float* __restrict__ maskBias, float* __restrict__ biasMain) {
  int w = threadIdx.x >> 6, lane = threadIdx.x & 63;
  int row = blockIdx.x * 4 + w;
  const bf16* hr = hid + (size_t)row * 384;
  const float* W2[3] = {nw2, mw2, dw2};
  float outs[3];
#pragma unroll
  for (int t = 0; t < 3; t++) {
    float acc = (float)hr[t * 128 + lane] * W2[t][lane] +
                (float)hr[t * 128 + 64 + lane] * W2[t][64 + lane];
    for (int msk = 1; msk < 64; msk <<= 1) acc += __shfl_xor(acc, msk);
    outs[t] = acc;
  }
  if (lane == 0) {
    float xn = outs[0] + nb2[0];
    float n = (xn > 20.f) ? xn : log1pf(__expf(xn));
    float mu = 1.f / (1.f + __expf(-(outs[1] + mb2[0])));
    float delta = fmaxf(outs[2] + db2[0], 0.f);
    float surv = logf(n + 1e-8f) + logf(mu + 1e-8f) - delta;
    biasMain[row] = 0.1f * LOG2E * surv + maskBias[row];
  }
}

extern "C" void kernel_launch(void* const* d_in, const int* in_sizes, int n_in,
                              void* d_out, int out_size, void* d_ws, size_t ws_size,
                              hipStream_t stream) {
  const int B = 2, S = 2048, H = 768, I = 256;
  const int NH = 12, SNH = 4;
  const int M = B * S;  // 4096
  const float SC = 0.125f * LOG2E;

  const float* x = (const float*)d_in[0];
  const int* mask = (const int*)d_in[1];
  const float* qw = (const float*)d_in[2];
  const float* qb = (const float*)d_in[3];
  const float* kw = (const float*)d_in[4];
  const float* kb = (const float*)d_in[5];
  const float* vw = (const float*)d_in[6];
  const float* vb = (const float*)d_in[7];
  const float* ow = (const float*)d_in[8];
  const float* ob = (const float*)d_in[9];
  const float* sp_w = (const float*)d_in[10];
  const float* sp_b = (const float*)d_in[11];
  const float* sa_in_w = (const float*)d_in[12];
  const float* sa_in_b = (const float*)d_in[13];
  const float* sa_out_w = (const float*)d_in[14];
  const float* sa_out_b = (const float*)d_in[15];
  const float* nw1 = (const float*)d_in[16];
  const float* nb1 = (const float*)d_in[17];
  const float* nw2 = (const float*)d_in[18];
  const float* nb2 = (const float*)d_in[19];
  const float* mw1 = (const float*)d_in[20];
  const float* mb1 = (const float*)d_in[21];
  const float* mw2 = (const float*)d_in[22];
  const float* mb2 = (const float*)d_in[23];
  const float* dw1 = (const float*)d_in[24];
  const float* db1 = (const float*)d_in[25];
  const float* dw2 = (const float*)d_in[26];
  const float* db2 = (const float*)d_in[27];

  char* ws = (char*)d_ws;
  size_t off = 0;
  auto alloc = [&](size_t bytes) -> void* {
    void* p = ws + off;
    off += (bytes + 255) & ~(size_t)255;
    return p;
  };

  // persistent
  bf16* xb = (bf16*)alloc((size_t)M * H * 2);
  bf16* wqkv = (bf16*)alloc((size_t)3 * H * H * 2);
  float* bqkv = (float*)alloc((size_t)3 * H * 4);
  bf16* wob = (bf16*)alloc((size_t)H * H * 2);
  bf16* spwb = (bf16*)alloc((size_t)I * H * 2);
  bf16* sainb = (bf16*)alloc((size_t)(3 * I) * I * 2);
  bf16* saoutb = (bf16*)alloc((size_t)I * I * 2);
  bf16* w1pack = (bf16*)alloc((size_t)384 * 256 * 2);
  float* b1pack = (float*)alloc((size_t)384 * 4);
  float* maskBias = (float*)alloc((size_t)M * 4);
  float* biasMain = (float*)alloc((size_t)M * 4);

  const int SPM = 2, SPS = 4;
  size_t offMark = off;
  // phase A (scorer)
  bf16* h0 = (bf16*)alloc((size_t)M * I * 2);
  bf16* qkv_s = (bf16*)alloc((size_t)M * (3 * I) * 2);
  bf16* vt_s = (bf16*)alloc((size_t)B * SNH * 64 * S * 2);
  bf16* attn_s = (bf16*)alloc((size_t)M * I * 2);
  bf16* h1 = (bf16*)alloc((size_t)M * I * 2);
  bf16* hid = (bf16*)alloc((size_t)M * 384 * 2);
  float* Opart_s = (float*)alloc((size_t)SPS * B * SNH * S * 64 * 4);
  float* L_s = (float*)alloc((size_t)SPS * B * SNH * S * 4);
  size_t endA = off;
  // phase B (main) overlays phase A
  off = offMark;
  bf16* QKVm = (bf16*)alloc((size_t)M * 3 * H * 2);
  bf16* vt_m = (bf16*)alloc((size_t)B * NH * 64 * S * 2);
  bf16* attn_m = (bf16*)alloc((size_t)M * H * 2);
  float* Opart_m = (float*)alloc((size_t)SPM * B * NH * S * 64 * 4);
  float* L_m = (float*)alloc((size_t)SPM * B * NH * S * 4);
  size_t endB = off;
  size_t need = endA > endB ? endA : endB;
  bool split_ok = ws_size >= need;
  (void)in_sizes; (void)n_in; (void)out_size;

  pack_all<<<5926, 256, 0, stream>>>(x, qw, kw, vw, ow, sp_w, sa_in_w, sa_out_w, nw1, mw1, dw1,
                                     qb, kb, vb, nb1, mb1, db1, mask,
                                     xb, wqkv, wob, spwb, sainb, saoutb, w1pack, bqkv, b1pack,
                                     maskBias);

  // ---- scorer branch ----
  gemm_nt<0, 0><<<(M / 64) * (I / 64), 256, 0, stream>>>(xb, H, spwb, H, sp_b, h0, I, I / 64, H);
  gemm_nt<0, 0><<<(M / 64) * ((3 * I) / 64), 256, 0, stream>>>(h0, I, sainb, I, sa_in_b, qkv_s,
                                                               3 * I, (3 * I) / 64, I);
  vtrans<<<B * SNH * (S / 64), 256, 0, stream>>>(qkv_s, 3 * I, 2 * I, vt_s, SNH, S);
  if (split_ok) {
    flash7_k<SPS, 1><<<SPS * B * SNH * (S / 128), 256, 0, stream>>>(
        qkv_s, qkv_s + I, 3 * I, vt_s, maskBias, nullptr, 0, Opart_s, L_s, SNH, S, SC, B);
    flash_comb<<<(B * SNH * S * 16) / 256, 256, 0, stream>>>(Opart_s, L_s, attn_s, I, SNH, S,
                                                             B, SPS);
  } else {
    flash7_k<1, 0><<<B * SNH * (S / 128), 256, 0, stream>>>(
        qkv_s, qkv_s + I, 3 * I, vt_s, maskBias, attn_s, I, nullptr, nullptr, SNH, S, SC, B);
  }
  gemm_nt<0, 0><<<(M / 64) * (I / 64), 256, 0, stream>>>(attn_s, I, saoutb, I, sa_out_b, h1, I,
                                                         I / 64, I);
  gemm_nt<0, 1><<<(M / 64) * (384 / 64), 256, 0, stream>>>(h1, I, w1pack, I, b1pack, hid, 384,
                                                           384 / 64, I);
  surv_k<<<M / 4, 256, 0, stream>>>(hid, nw2, nb2, mw2, mb2, dw2, db2, maskBias, biasMain);

  // ---- main branch ----
  gemm_big<0><<<(M / 128) * (3 * H / 128), 256, 0, stream>>>(xb, wqkv, bqkv, QKVm, 3 * H,
                                                             3 * H / 128, H);
  vtrans<<<B * NH * (S / 64), 256, 0, stream>>>(QKVm, 3 * H, 2 * H, vt_m, NH, S);
  if (split_ok) {
    flash7_k<SPM, 1><<<SPM * B * NH * (S / 128), 256, 0, stream>>>(
        QKVm, QKVm + H, 3 * H, vt_m, biasMain, nullptr, 0, Opart_m, L_m, NH, S, SC, B);
    flash_comb<<<(B * NH * S * 16) / 256, 256, 0, stream>>>(Opart_m, L_m, attn_m, H, NH, S, B,
                                                            SPM);
  } else {
    flash7_k<1, 0><<<B * NH * (S / 128), 256, 0, stream>>>(
        QKVm, QKVm + H, 3 * H, vt_m, biasMain, attn_m, H, nullptr, nullptr, NH, S, SC, B);
  }
  gemm_big<1><<<(M / 128) * (H / 128), 256, 0, stream>>>(attn_m, wob, ob, d_out, H,
                                                         H / 128, H);
}